// Round 4
// baseline (6097.334 us; speedup 1.0000x reference)
//
#include <hip/hip_runtime.h>
#include <math.h>

#define NN    1000
#define KP    1024
#define BATCH 32
#define SEQ   48
#define HID   64
#define FEAT  40
#define AGW   3328                  // 1280 x-cols + 2048 h-cols
#define HCOLS 2048

typedef unsigned short u16;
typedef __attribute__((ext_vector_type(8))) short  short8v;
typedef __attribute__((ext_vector_type(8))) unsigned short ushort8v;
typedef __attribute__((ext_vector_type(4))) float  float4v;

__device__ __forceinline__ u16 f2bf(float x) {
    union { float f; unsigned u; } v; v.f = x;
    unsigned r = v.u + 0x7FFF + ((v.u >> 16) & 1);
    return (u16)(r >> 16);
}
__device__ __forceinline__ float bf2f(u16 h) {
    union { unsigned u; float f; } v; v.u = ((unsigned)h) << 16;
    return v.f;
}

// ---------------- Laplacian ----------------
__global__ void k_rowsum(const float* __restrict__ adj, float* __restrict__ dinv) {
    int m = blockIdx.x;
    float s = 0.f;
    for (int n = threadIdx.x; n < NN; n += blockDim.x)
        s += adj[(size_t)m*NN + n];
    __shared__ float red[256];
    red[threadIdx.x] = s; __syncthreads();
    for (int st = 128; st > 0; st >>= 1) {
        if (threadIdx.x < st) red[threadIdx.x] += red[threadIdx.x + st];
        __syncthreads();
    }
    if (threadIdx.x == 0) dinv[m] = rsqrtf(red[0] + 1.0f);
}

__global__ void k_buildL(const float* __restrict__ adj, const float* __restrict__ dinv,
                         u16* __restrict__ Lhi, u16* __restrict__ Llo) {
    int idx = blockIdx.x * 256 + threadIdx.x;
    if (idx >= KP*KP) return;
    int m = idx >> 10, k = idx & (KP-1);
    float v = 0.f;
    if (m < NN && k < NN)
        v = dinv[m] * (adj[(size_t)m*NN + k] + (m == k ? 1.f : 0.f)) * dinv[k];
    u16 h = f2bf(v);
    Lhi[idx] = h;
    Llo[idx] = f2bf(v - bf2f(h));
}

// ---------------- W conversion: W1bf[k 128][f 128], W2bf[c 64][f 128] hi/lo ----------------
__global__ void k_wconv(const float* __restrict__ W1, const float* __restrict__ W2,
                        u16* __restrict__ W1h, u16* __restrict__ W1l,
                        u16* __restrict__ W2h, u16* __restrict__ W2l) {
    int idx = blockIdx.x * 256 + threadIdx.x;
    if (idx < 128*128) {
        int k = idx >> 7, f = idx & 127;
        float v = (f < 104) ? W1[f*128 + k] : 0.f;
        u16 h = f2bf(v);
        W1h[idx] = h; W1l[idx] = f2bf(v - bf2f(h));
    } else if (idx < 128*128 + 64*128) {
        int i2 = idx - 128*128;
        int c = i2 >> 7, f = i2 & 127;
        float v = (f < 104) ? W2[f*64 + c] : 0.f;
        u16 h = f2bf(v);
        W2h[i2] = h; W2l[i2] = f2bf(v - bf2f(h));
    }
}

// ---------------- x projection -> xT[j=b*40+a][n] bf16 ----------------
__global__ __launch_bounds__(256)
void k_xproj(const float* __restrict__ inputs, int t,
             const float* __restrict__ Wo, const float* __restrict__ bo,
             const float* __restrict__ Wd, const float* __restrict__ bd,
             const float* __restrict__ We, const float* __restrict__ be,
             const float* __restrict__ Wi, const float* __restrict__ bi,
             u16* __restrict__ xT) {
    int b = blockIdx.x, nt = blockIdx.y;
    int n0 = nt * 64;
    __shared__ float raw[64][22];
    for (int i = threadIdx.x; i < 64*21; i += 256) {
        int nn = i / 21, f = i - nn*21;
        int n = n0 + nn;
        raw[nn][f] = (n < NN) ? inputs[(((size_t)b*SEQ + t)*NN + n)*21 + f] : 0.f;
    }
    __syncthreads();
    for (int o = threadIdx.x; o < 40*64; o += 256) {
        int a2 = o >> 6, nn = o & 63;
        int n = n0 + nn;
        if (n >= NN) continue;
        int a = a2 % 10, g = a2 / 10;
        const float* r = raw[nn];
        float v;
        if (g == 0)
            v = bo[a] + r[2]*Wo[0*10+a] + r[5]*Wo[1*10+a] + r[8]*Wo[2*10+a]
                      + r[9]*Wo[3*10+a] + r[12]*Wo[4*10+a];
        else if (g == 1)
            v = bd[a] + r[10]*Wd[0*10+a] + r[14]*Wd[1*10+a] + r[15]*Wd[2*10+a];
        else if (g == 2)
            v = be[a] + r[13]*We[0*10+a] + r[17]*We[1*10+a];
        else
            v = bi[a] + r[19]*Wi[0*10+a] + r[20]*Wi[1*10+a];
        xT[(size_t)(b*40 + a2)*KP + n] = f2bf(v);
    }
}

// ---------------- MFMA GEMM: C[m][n0+j] = sum_k A[m][k]*B[j][k] ----------------
// 512 thr, 8 waves, BM=128 BN=64 BK=32, no split-K, direct store.
// blocks [0,xblocks): B=Bx (2-pass, no B-lo); rest: B=Bh/Bhl (3-pass).
__global__ __launch_bounds__(512)
void k_gemm(const u16* __restrict__ Ahi, const u16* __restrict__ Alo,
            const u16* __restrict__ Bx,
            const u16* __restrict__ Bh, const u16* __restrict__ Bhl,
            int xblocks, float* __restrict__ C, int ncols) {
    __shared__ char sAh[128*64], sAl[128*64];
    __shared__ char sBh[64*64],  sBl[64*64];
    const int n0 = blockIdx.x * 64;
    const int m0 = blockIdx.y * 128;
    const bool isx = (int)blockIdx.x < xblocks;
    const u16* Bp  = isx ? Bx : Bh;
    const int brow0 = isx ? n0 : n0 - xblocks*64;
    const int tid = threadIdx.x;
    const int w = tid >> 6, lane = tid & 63;
    const int l15 = lane & 15, l4 = lane >> 4;

    float4v acc[4];
    #pragma unroll
    for (int i = 0; i < 4; ++i) acc[i] = (float4v){0.f,0.f,0.f,0.f};

    const int ar = w*16 + l15;
    const int aoff = (ar*64 + l4*16) ^ ((ar & 7) << 4);
    int boff[4];
    #pragma unroll
    for (int nf = 0; nf < 4; ++nf) {
        int br = nf*16 + l15;
        boff[nf] = (br*64 + l4*16) ^ ((br & 7) << 4);
    }
    // staging maps
    const int rA = tid >> 2, qA = tid & 3;          // 512 A-chunks
    const int dA = (rA*64 + qA*16) ^ ((rA & 7) << 4);
    const size_t gA = (size_t)(m0 + rA)*KP + qA*8;
    const int rB = (tid & 255) >> 2, qB = tid & 3;  // 256 B-chunks per team
    const int dB = (rB*64 + qB*16) ^ ((rB & 7) << 4);
    const size_t gB = (size_t)(brow0 + rB)*KP + qB*8;
    const bool team0 = tid < 256;

    for (int kt = 0; kt < 32; ++kt) {
        const int k0 = kt*32;
        __syncthreads();
        *(uint4*)(sAh + dA) = *(const uint4*)(Ahi + gA + k0);
        *(uint4*)(sAl + dA) = *(const uint4*)(Alo + gA + k0);
        if (team0)      *(uint4*)(sBh + dB) = *(const uint4*)(Bp  + gB + k0);
        else if (!isx)  *(uint4*)(sBl + dB) = *(const uint4*)(Bhl + gB + k0);
        __syncthreads();
        short8v ah = *(const short8v*)(sAh + aoff);
        short8v al = *(const short8v*)(sAl + aoff);
        #pragma unroll
        for (int nf = 0; nf < 4; ++nf) {
            short8v bh = *(const short8v*)(sBh + boff[nf]);
            acc[nf] = __builtin_amdgcn_mfma_f32_16x16x32_bf16(ah, bh, acc[nf], 0, 0, 0);
            acc[nf] = __builtin_amdgcn_mfma_f32_16x16x32_bf16(al, bh, acc[nf], 0, 0, 0);
            if (!isx) {
                short8v bl = *(const short8v*)(sBl + boff[nf]);
                acc[nf] = __builtin_amdgcn_mfma_f32_16x16x32_bf16(ah, bl, acc[nf], 0, 0, 0);
            }
        }
    }
    #pragma unroll
    for (int nf = 0; nf < 4; ++nf)
        #pragma unroll
        for (int i = 0; i < 4; ++i) {
            int m = m0 + w*16 + l4*4 + i;
            int j = n0 + nf*16 + l15;
            C[(size_t)m*ncols + j] = acc[nf][i];
        }
}

// ---------------- gate (MFMA) + fused rh / u demux ----------------
// ru(m,k) = sigmoid(ag_row(m) . W1[:,k] + b1[k]); m<500 -> rh for nodes 2m,2m+1;
// m>=500 -> u for nodes 2(m-500), +1.
__global__ __launch_bounds__(256)
void k_gate(const float* __restrict__ ag, const u16* __restrict__ W1h,
            const u16* __restrict__ W1l, const float* __restrict__ b1,
            const float* __restrict__ h_lin,
            u16* __restrict__ rhh, u16* __restrict__ rhl,
            float* __restrict__ u_lin) {
    const int b = blockIdx.x, mt = blockIdx.y;   // (32,16)
    const int tid = threadIdx.x;
    const int w = tid >> 6, lane = tid & 63, l15 = lane & 15, l4 = lane >> 4;
    __shared__ char sAh[64*64], sAl[64*64];      // [64 rows][32 f] bf16/kt, swizzled
    __shared__ float ru_s[64*129];

    float4v acc[8];
    #pragma unroll
    for (int i = 0; i < 8; ++i) acc[i] = (float4v){0.f,0.f,0.f,0.f};

    const int srow = tid >> 2, sfg = tid & 3;
    const int sdst = (srow*64 + sfg*16) ^ ((srow & 7) << 4);
    const float* agrow = ag + (size_t)(mt*64 + srow)*AGW;
    const int ar = w*16 + l15;
    const int aoff = (ar*64 + l4*16) ^ ((ar & 7) << 4);

    for (int kt = 0; kt < 4; ++kt) {
        __syncthreads();
        ushort8v hv, lv;
        #pragma unroll
        for (int e = 0; e < 8; ++e) {
            int f = kt*32 + sfg*8 + e;
            float v = 0.f;
            if (f < 40)        v = agrow[b*40 + f];
            else if (f < 104)  v = agrow[1280 + b*64 + (f - 40)];
            u16 hi = f2bf(v);
            hv[e] = hi; lv[e] = f2bf(v - bf2f(hi));
        }
        *(ushort8v*)(sAh + sdst) = hv;
        *(ushort8v*)(sAl + sdst) = lv;
        __syncthreads();
        short8v ah = *(const short8v*)(sAh + aoff);
        short8v al = *(const short8v*)(sAl + aoff);
        #pragma unroll
        for (int nf = 0; nf < 8; ++nf) {
            int j = nf*16 + l15;
            short8v bh = *(const short8v*)(W1h + j*128 + kt*32 + l4*8);
            short8v bl = *(const short8v*)(W1l + j*128 + kt*32 + l4*8);
            acc[nf] = __builtin_amdgcn_mfma_f32_16x16x32_bf16(ah, bh, acc[nf], 0, 0, 0);
            acc[nf] = __builtin_amdgcn_mfma_f32_16x16x32_bf16(al, bh, acc[nf], 0, 0, 0);
            acc[nf] = __builtin_amdgcn_mfma_f32_16x16x32_bf16(ah, bl, acc[nf], 0, 0, 0);
        }
    }
    // sigmoid + dump to LDS
    #pragma unroll
    for (int nf = 0; nf < 8; ++nf) {
        int col = nf*16 + l15;
        float bias = b1[col];
        #pragma unroll
        for (int i = 0; i < 4; ++i) {
            int row = w*16 + l4*4 + i;
            float v = acc[nf][i] + bias;
            ru_s[row*129 + col] = 1.f / (1.f + __expf(-v));
        }
    }
    __syncthreads();
    // epilogue: demux r/u
    const int c = tid & 63, ng = tid >> 6;
    for (int lc = 0; lc < 16; lc += 4) {
        int lr = ng*16 + lc;
        int m = mt*64 + lr;
        if (m + 3 < 500) {          // all-r chunk (500 % 4 == 0 -> no mixed chunk)
            unsigned hiw[4], low[4];
            #pragma unroll
            for (int d = 0; d < 4; ++d) {
                int mm = m + d;
                float r0 = ru_s[(lr+d)*129 + c];
                float r1 = ru_s[(lr+d)*129 + 64 + c];
                float h0 = h_lin[((size_t)b*NN + 2*mm)*64 + c];
                float h1 = h_lin[((size_t)b*NN + 2*mm + 1)*64 + c];
                float x0 = r0*h0, x1 = r1*h1;
                u16 a0 = f2bf(x0), a1 = f2bf(x1);
                hiw[d] = (unsigned)a0 | ((unsigned)a1 << 16);
                u16 c0 = f2bf(x0 - bf2f(a0)), c1 = f2bf(x1 - bf2f(a1));
                low[d] = (unsigned)c0 | ((unsigned)c1 << 16);
            }
            size_t base = (size_t)(b*64 + c)*KP + 2*m;
            uint4 vh; vh.x = hiw[0]; vh.y = hiw[1]; vh.z = hiw[2]; vh.w = hiw[3];
            uint4 vl; vl.x = low[0]; vl.y = low[1]; vl.z = low[2]; vl.w = low[3];
            *(uint4*)(rhh + base) = vh;
            *(uint4*)(rhl + base) = vl;
        } else if (m >= 500) {      // u chunk
            #pragma unroll
            for (int d = 0; d < 4; ++d) {
                int mm = m + d;
                if (mm < 1000) {
                    int n = 2*(mm - 500);
                    u_lin[((size_t)b*NN + n)*64 + c]     = ru_s[(lr+d)*129 + c];
                    u_lin[((size_t)b*NN + n + 1)*64 + c] = ru_s[(lr+d)*129 + 64 + c];
                }
            }
        }
    }
}

// ---------------- update (MFMA) + h' + hT transpose-write ----------------
__global__ __launch_bounds__(256)
void k_update(const float* __restrict__ ag, const float* __restrict__ agc,
              const u16* __restrict__ W2h, const u16* __restrict__ W2l,
              const float* __restrict__ b2, const float* __restrict__ u_lin,
              float* __restrict__ h_lin,
              u16* __restrict__ hTh, u16* __restrict__ hTl,
              float* __restrict__ out, int write_out) {
    const int b = blockIdx.x, mt = blockIdx.y;   // (32,16)
    const int tid = threadIdx.x;
    const int w = tid >> 6, lane = tid & 63, l15 = lane & 15, l4 = lane >> 4;
    __shared__ char sAh[64*64], sAl[64*64];
    __shared__ float cs[64*65];

    float4v acc[4];
    #pragma unroll
    for (int i = 0; i < 4; ++i) acc[i] = (float4v){0.f,0.f,0.f,0.f};

    const int srow = tid >> 2, sfg = tid & 3;
    const int sdst = (srow*64 + sfg*16) ^ ((srow & 7) << 4);
    const float* agrow  = ag  + (size_t)(mt*64 + srow)*AGW;
    const float* agcrow = agc + (size_t)(mt*64 + srow)*HCOLS;
    const int ar = w*16 + l15;
    const int aoff = (ar*64 + l4*16) ^ ((ar & 7) << 4);

    for (int kt = 0; kt < 4; ++kt) {
        __syncthreads();
        ushort8v hv, lv;
        #pragma unroll
        for (int e = 0; e < 8; ++e) {
            int f = kt*32 + sfg*8 + e;
            float v = 0.f;
            if (f < 40)        v = agrow[b*40 + f];
            else if (f < 104)  v = agcrow[b*64 + (f - 40)];
            u16 hi = f2bf(v);
            hv[e] = hi; lv[e] = f2bf(v - bf2f(hi));
        }
        *(ushort8v*)(sAh + sdst) = hv;
        *(ushort8v*)(sAl + sdst) = lv;
        __syncthreads();
        short8v ah = *(const short8v*)(sAh + aoff);
        short8v al = *(const short8v*)(sAl + aoff);
        #pragma unroll
        for (int nf = 0; nf < 4; ++nf) {
            int j = nf*16 + l15;
            short8v bh = *(const short8v*)(W2h + j*128 + kt*32 + l4*8);
            short8v bl = *(const short8v*)(W2l + j*128 + kt*32 + l4*8);
            acc[nf] = __builtin_amdgcn_mfma_f32_16x16x32_bf16(ah, bh, acc[nf], 0, 0, 0);
            acc[nf] = __builtin_amdgcn_mfma_f32_16x16x32_bf16(al, bh, acc[nf], 0, 0, 0);
            acc[nf] = __builtin_amdgcn_mfma_f32_16x16x32_bf16(ah, bl, acc[nf], 0, 0, 0);
        }
    }
    #pragma unroll
    for (int nf = 0; nf < 4; ++nf) {
        int col = nf*16 + l15;
        float bias = b2[col];
        #pragma unroll
        for (int i = 0; i < 4; ++i) {
            int row = w*16 + l4*4 + i;
            cs[row*65 + col] = acc[nf][i] + bias;
        }
    }
    __syncthreads();
    const int c = tid & 63, ng = tid >> 6;
    for (int lc = 0; lc < 16; lc += 8) {
        int lr = ng*16 + lc;
        int m = mt*64 + lr;
        ushort8v hiv, lov;
        #pragma unroll
        for (int d = 0; d < 8; ++d) {
            int mm = m + d;
            float hn = 0.f;
            if (mm < NN) {
                float x = cs[(lr+d)*65 + c];
                x = fminf(fmaxf(x, -15.f), 15.f);
                float e = __expf(2.f*x);
                float cand = (e - 1.f) / (e + 1.f);
                size_t idx = ((size_t)b*NN + mm)*64 + c;
                float u = u_lin[idx], h = h_lin[idx];
                hn = u*h + (1.f - u)*cand;
                h_lin[idx] = hn;
                if (write_out) out[idx] = hn;
            }
            u16 hb = f2bf(hn);
            hiv[d] = hb; lov[d] = f2bf(hn - bf2f(hb));
        }
        size_t base = (size_t)(b*64 + c)*KP + m;
        *(ushort8v*)(hTh + base) = hiv;
        *(ushort8v*)(hTl + base) = lov;
    }
}

// ---------------- workspace layout (byte offsets) ----------------
#define O_LHI   0ull
#define O_LLO   2097152ull
#define O_HTH   4194304ull
#define O_HTL   8388608ull
#define O_XT    12582912ull
#define O_RHH   15204352ull
#define O_RHL   19398656ull
#define O_AG    23592960ull
#define O_AGC   37224448ull
#define O_U     45613056ull
#define O_HL    53805056ull
#define O_W1H   61997056ull
#define O_W1L   62029824ull
#define O_W2H   62062592ull
#define O_W2L   62078976ull
#define O_DINV  62095360ull

extern "C" void kernel_launch(void* const* d_in, const int* in_sizes, int n_in,
                              void* d_out, int out_size, void* d_ws, size_t ws_size,
                              hipStream_t stream) {
    const float* inputs = (const float*)d_in[0];
    const float* adj    = (const float*)d_in[1];
    const float* Wo = (const float*)d_in[2];  const float* bo = (const float*)d_in[3];
    const float* Wd = (const float*)d_in[4];  const float* bd = (const float*)d_in[5];
    const float* We = (const float*)d_in[6];  const float* be = (const float*)d_in[7];
    const float* Wi = (const float*)d_in[8];  const float* bi = (const float*)d_in[9];
    const float* W1 = (const float*)d_in[10]; const float* b1 = (const float*)d_in[11];
    const float* W2 = (const float*)d_in[12]; const float* b2 = (const float*)d_in[13];
    float* out = (float*)d_out;

    char* ws = (char*)d_ws;
    u16* Lhi = (u16*)(ws + O_LHI);
    u16* Llo = (u16*)(ws + O_LLO);
    u16* hTh = (u16*)(ws + O_HTH);
    u16* hTl = (u16*)(ws + O_HTL);
    u16* xT  = (u16*)(ws + O_XT);
    u16* rhh = (u16*)(ws + O_RHH);
    u16* rhl = (u16*)(ws + O_RHL);
    float* ag    = (float*)(ws + O_AG);
    float* agc   = (float*)(ws + O_AGC);
    float* u_lin = (float*)(ws + O_U);
    float* h_lin = (float*)(ws + O_HL);
    u16* W1h = (u16*)(ws + O_W1H);
    u16* W1l = (u16*)(ws + O_W1L);
    u16* W2h = (u16*)(ws + O_W2H);
    u16* W2l = (u16*)(ws + O_W2L);
    float* dinv = (float*)(ws + O_DINV);

    // h0 = 0 (hT hi+lo contiguous, h_lin)
    hipMemsetAsync(ws + O_HTH, 0, 8388608ull, stream);
    hipMemsetAsync(ws + O_HL,  0, 8192000ull, stream);

    k_rowsum<<<NN, 256, 0, stream>>>(adj, dinv);
    k_buildL<<<(KP*KP)/256, 256, 0, stream>>>(adj, dinv, Lhi, Llo);
    k_wconv<<<96, 256, 0, stream>>>(W1, W2, W1h, W1l, W2h, W2l);

    for (int t = 0; t < SEQ; ++t) {
        k_xproj<<<dim3(32,16), 256, 0, stream>>>(inputs, t, Wo, bo, Wd, bd,
                                                 We, be, Wi, bi, xT);
        // ag = L @ [x | h]
        k_gemm<<<dim3(52,8), 512, 0, stream>>>(Lhi, Llo, xT, hTh, hTl, 20, ag, AGW);
        k_gate<<<dim3(32,16), 256, 0, stream>>>(ag, W1h, W1l, b1, h_lin, rhh, rhl, u_lin);
        // agc = L @ rh
        k_gemm<<<dim3(32,8), 512, 0, stream>>>(Lhi, Llo, (const u16*)0, rhh, rhl, 0, agc, HCOLS);
        k_update<<<dim3(32,16), 256, 0, stream>>>(ag, agc, W2h, W2l, b2, u_lin, h_lin,
                                                  hTh, hTl, out, t == SEQ-1);
    }
}

// Round 5
// 3967.799 us; speedup vs baseline: 1.5367x; 1.5367x over previous
//
#include <hip/hip_runtime.h>
#include <math.h>

#define NN    1000
#define KP    1024
#define BATCH 32
#define SEQ   48
#define HID   64
#define LCOLS 32256                 // 48*32*21 premultiplied input cols
#define HCOLS 2048

typedef unsigned short u16;
typedef __attribute__((ext_vector_type(8))) short  short8v;
typedef __attribute__((ext_vector_type(8))) unsigned short ushort8v;
typedef __attribute__((ext_vector_type(4))) float  float4v;

__device__ __forceinline__ u16 f2bf(float x) {
    union { float f; unsigned u; } v; v.f = x;
    unsigned r = v.u + 0x7FFF + ((v.u >> 16) & 1);
    return (u16)(r >> 16);
}

// ---------------- Laplacian ----------------
__global__ void k_rowsum(const float* __restrict__ adj, float* __restrict__ dinv) {
    int m = blockIdx.x;
    float s = 0.f;
    for (int n = threadIdx.x; n < NN; n += blockDim.x)
        s += adj[(size_t)m*NN + n];
    __shared__ float red[256];
    red[threadIdx.x] = s; __syncthreads();
    for (int st = 128; st > 0; st >>= 1) {
        if (threadIdx.x < st) red[threadIdx.x] += red[threadIdx.x + st];
        __syncthreads();
    }
    if (threadIdx.x == 0) dinv[m] = rsqrtf(red[0] + 1.0f);
}

__global__ void k_buildL(const float* __restrict__ adj, const float* __restrict__ dinv,
                         u16* __restrict__ Lhi) {
    int idx = blockIdx.x * 256 + threadIdx.x;
    if (idx >= KP*KP) return;
    int m = idx >> 10, k = idx & (KP-1);
    float v = 0.f;
    if (m < NN && k < NN)
        v = dinv[m] * (adj[(size_t)m*NN + k] + (m == k ? 1.f : 0.f)) * dinv[k];
    Lhi[idx] = f2bf(v);
}

__global__ void k_srow(const float* __restrict__ adj, const float* __restrict__ dinv,
                       float* __restrict__ srl) {
    int m = blockIdx.x;
    __shared__ float red[256];
    float s = 0.f;
    if (m < NN)
        for (int n = threadIdx.x; n < NN; n += blockDim.x)
            s += adj[(size_t)m*NN + n] * dinv[n];
    red[threadIdx.x] = s; __syncthreads();
    for (int st = 128; st > 0; st >>= 1) {
        if (threadIdx.x < st) red[threadIdx.x] += red[threadIdx.x + st];
        __syncthreads();
    }
    if (threadIdx.x == 0) srl[m] = (m < NN) ? dinv[m] * (red[0] + dinv[m]) : 0.f;
}

// ---------------- W conversion ----------------
__global__ void k_wconv(const float* __restrict__ W1, const float* __restrict__ W2,
                        u16* __restrict__ W1h, u16* __restrict__ W2h) {
    int idx = blockIdx.x * 256 + threadIdx.x;
    if (idx < 128*128) {
        int k = idx >> 7, f = idx & 127;
        W1h[idx] = f2bf((f < 104) ? W1[f*128 + k] : 0.f);
    } else if (idx < 128*128 + 64*128) {
        int i2 = idx - 128*128;
        int c = i2 >> 7, f = i2 & 127;
        W2h[i2] = f2bf((f < 104) ? W2[f*64 + c] : 0.f);
    }
}

// ---------------- pack aspect projections ----------------
__global__ void k_packW(const float* __restrict__ Wo, const float* __restrict__ bo,
                        const float* __restrict__ Wd, const float* __restrict__ bd,
                        const float* __restrict__ We, const float* __restrict__ be,
                        const float* __restrict__ Wi, const float* __restrict__ bi,
                        float* __restrict__ Wp, float* __restrict__ bp) {
    for (int o = threadIdx.x; o < 21*40; o += 256) {
        int f = o / 40, a = o - f*40;
        int g = a / 10, aa = a - 10*g;
        float v = 0.f;
        if (g == 0) {
            if (f == 2) v = Wo[0*10+aa]; else if (f == 5) v = Wo[1*10+aa];
            else if (f == 8) v = Wo[2*10+aa]; else if (f == 9) v = Wo[3*10+aa];
            else if (f == 12) v = Wo[4*10+aa];
        } else if (g == 1) {
            if (f == 10) v = Wd[aa]; else if (f == 14) v = Wd[10+aa];
            else if (f == 15) v = Wd[20+aa];
        } else if (g == 2) {
            if (f == 13) v = We[aa]; else if (f == 17) v = We[10+aa];
        } else {
            if (f == 19) v = Wi[aa]; else if (f == 20) v = Wi[10+aa];
        }
        Wp[o] = v;
    }
    if (threadIdx.x < 40) {
        int a = threadIdx.x, g = a / 10, aa = a - 10*g;
        bp[a] = (g == 0) ? bo[aa] : (g == 1) ? bd[aa] : (g == 2) ? be[aa] : bi[aa];
    }
}

// ---------------- transpose inputs -> inT[(t*32+b)*21+f][1024] bf16 ----------------
__global__ __launch_bounds__(256)
void k_transpose(const float* __restrict__ inputs, u16* __restrict__ inT) {
    int bt = blockIdx.x;                // b*48 + t
    int b = bt / SEQ, t = bt - b*SEQ;
    int nt = blockIdx.y;
    __shared__ float sm[128][22];
    const float* base = inputs + ((size_t)bt * NN + nt*128) * 21;
    for (int i = threadIdx.x; i < 128*21; i += 256) {
        int nn = i / 21, f = i - nn*21;
        int n = nt*128 + nn;
        sm[nn][f] = (n < NN) ? base[(size_t)nn*21 + f] : 0.f;
    }
    __syncthreads();
    for (int o = threadIdx.x; o < 21*128; o += 256) {
        int f = o >> 7, nn = o & 127;
        inT[(size_t)((t*32 + b)*21 + f)*KP + nt*128 + nn] = f2bf(sm[nn][f]);
    }
}

// ---------------- MFMA GEMM: C[m][j] = sum_k A[m][k]*B[j][k] ----------------
template<int OUTBF16>
__global__ __launch_bounds__(512)
void k_gemm(const u16* __restrict__ A, const u16* __restrict__ B,
            void* __restrict__ Cout, int ncols) {
    __shared__ char sA[128*64];
    __shared__ char sB[64*64];
    const int n0 = blockIdx.x * 64;
    const int m0 = blockIdx.y * 128;
    const int tid = threadIdx.x;
    const int w = tid >> 6, lane = tid & 63;
    const int l15 = lane & 15, l4 = lane >> 4;
    const int wm = w >> 1, wn = w & 1;

    float4v acc[2][2];
    #pragma unroll
    for (int i = 0; i < 2; ++i)
        #pragma unroll
        for (int j = 0; j < 2; ++j) acc[i][j] = (float4v){0.f,0.f,0.f,0.f};

    int aoff[2], boff[2];
    #pragma unroll
    for (int mf = 0; mf < 2; ++mf) {
        int r = wm*32 + mf*16 + l15;
        aoff[mf] = (r*64 + l4*16) ^ ((r & 7) << 4);
    }
    #pragma unroll
    for (int nf = 0; nf < 2; ++nf) {
        int r = wn*32 + nf*16 + l15;
        boff[nf] = (r*64 + l4*16) ^ ((r & 7) << 4);
    }
    const int rA = tid >> 2, qA = tid & 3;
    const int dA = (rA*64 + qA*16) ^ ((rA & 7) << 4);
    const size_t gA = (size_t)(m0 + rA)*KP + qA*8;
    const int rB = (tid & 255) >> 2, qB = tid & 3;
    const int dB = (rB*64 + qB*16) ^ ((rB & 7) << 4);
    const size_t gB = (size_t)(n0 + rB)*KP + qB*8;

    for (int kt = 0; kt < 32; ++kt) {
        const int k0 = kt*32;
        __syncthreads();
        *(uint4*)(sA + dA) = *(const uint4*)(A + gA + k0);
        if (tid < 256) *(uint4*)(sB + dB) = *(const uint4*)(B + gB + k0);
        __syncthreads();
        short8v a0 = *(const short8v*)(sA + aoff[0]);
        short8v a1 = *(const short8v*)(sA + aoff[1]);
        short8v b0 = *(const short8v*)(sB + boff[0]);
        short8v b1 = *(const short8v*)(sB + boff[1]);
        acc[0][0] = __builtin_amdgcn_mfma_f32_16x16x32_bf16(a0, b0, acc[0][0], 0, 0, 0);
        acc[0][1] = __builtin_amdgcn_mfma_f32_16x16x32_bf16(a0, b1, acc[0][1], 0, 0, 0);
        acc[1][0] = __builtin_amdgcn_mfma_f32_16x16x32_bf16(a1, b0, acc[1][0], 0, 0, 0);
        acc[1][1] = __builtin_amdgcn_mfma_f32_16x16x32_bf16(a1, b1, acc[1][1], 0, 0, 0);
    }
    #pragma unroll
    for (int mf = 0; mf < 2; ++mf)
        #pragma unroll
        for (int nf = 0; nf < 2; ++nf)
            #pragma unroll
            for (int i = 0; i < 4; ++i) {
                int m = m0 + wm*32 + mf*16 + l4*4 + i;
                int j = n0 + wn*32 + nf*16 + l15;
                if (OUTBF16)
                    ((u16*)Cout)[(size_t)m*ncols + j] = f2bf(acc[mf][nf][i]);
                else
                    ((float*)Cout)[(size_t)m*ncols + j] = acc[mf][nf][i];
            }
}

// ---------------- gate (MFMA) + fused r*h / u demux ----------------
__global__ __launch_bounds__(256)
void k_gate(const u16* __restrict__ agx, const u16* __restrict__ agh,
            const u16* __restrict__ W1h, const float* __restrict__ b1,
            const float* __restrict__ h_lin,
            u16* __restrict__ rhh, float* __restrict__ u_lin) {
    const int b = blockIdx.x, mt = blockIdx.y;
    const int tid = threadIdx.x;
    const int w = tid >> 6, lane = tid & 63, l15 = lane & 15, l4 = lane >> 4;
    __shared__ char sAh[64*64];
    __shared__ float ru_s[64*129];

    float4v acc[8];
    #pragma unroll
    for (int i = 0; i < 8; ++i) acc[i] = (float4v){0.f,0.f,0.f,0.f};

    const int srow = tid >> 2, sfg = tid & 3;
    const int sdst = (srow*64 + sfg*16) ^ ((srow & 7) << 4);
    const size_t mrow = (size_t)(mt*64 + srow);
    const int ar = w*16 + l15;
    const int aoff = (ar*64 + l4*16) ^ ((ar & 7) << 4);

    for (int kt = 0; kt < 4; ++kt) {
        __syncthreads();
        int f0 = kt*32 + sfg*8;
        uint4 v;
        if (f0 < 40)       v = *(const uint4*)(agx + mrow*1280 + b*40 + f0);
        else if (f0 < 104) v = *(const uint4*)(agh + mrow*2048 + b*64 + (f0 - 40));
        else               v = (uint4){0,0,0,0};
        *(uint4*)(sAh + sdst) = v;
        __syncthreads();
        short8v a = *(const short8v*)(sAh + aoff);
        #pragma unroll
        for (int nf = 0; nf < 8; ++nf) {
            short8v bh = *(const short8v*)(W1h + (nf*16 + l15)*128 + kt*32 + l4*8);
            acc[nf] = __builtin_amdgcn_mfma_f32_16x16x32_bf16(a, bh, acc[nf], 0, 0, 0);
        }
    }
    #pragma unroll
    for (int nf = 0; nf < 8; ++nf) {
        int col = nf*16 + l15;
        float bias = b1[col];
        #pragma unroll
        for (int i = 0; i < 4; ++i) {
            int row = w*16 + l4*4 + i;
            ru_s[row*129 + col] = 1.f / (1.f + __expf(-(acc[nf][i] + bias)));
        }
    }
    __syncthreads();
    const int c = tid & 63, ng = tid >> 6;
    for (int lc = 0; lc < 16; lc += 4) {
        int lr = ng*16 + lc;
        int m = mt*64 + lr;
        if (m + 3 < 500) {
            unsigned hiw[4];
            #pragma unroll
            for (int d = 0; d < 4; ++d) {
                int mm = m + d;
                float r0 = ru_s[(lr+d)*129 + c];
                float r1 = ru_s[(lr+d)*129 + 64 + c];
                float h0 = h_lin[((size_t)b*NN + 2*mm)*64 + c];
                float h1 = h_lin[((size_t)b*NN + 2*mm + 1)*64 + c];
                u16 a0 = f2bf(r0*h0), a1 = f2bf(r1*h1);
                hiw[d] = (unsigned)a0 | ((unsigned)a1 << 16);
            }
            uint4 vh; vh.x = hiw[0]; vh.y = hiw[1]; vh.z = hiw[2]; vh.w = hiw[3];
            *(uint4*)(rhh + (size_t)(b*64 + c)*KP + 2*m) = vh;
        } else if (m >= 500) {
            #pragma unroll
            for (int d = 0; d < 4; ++d) {
                int mm = m + d;
                if (mm < 1000) {
                    int n = 2*(mm - 500);
                    u_lin[((size_t)b*NN + n)*64 + c]     = ru_s[(lr+d)*129 + c];
                    u_lin[((size_t)b*NN + n + 1)*64 + c] = ru_s[(lr+d)*129 + 64 + c];
                }
            }
        }
    }
}

// ---------------- update (MFMA) + h' + hT write + next-step agx ----------------
__global__ __launch_bounds__(256)
void k_update(const u16* __restrict__ agx, const u16* __restrict__ agc,
              const u16* __restrict__ W2h, const float* __restrict__ b2,
              const float* __restrict__ u_lin, float* __restrict__ h_lin,
              u16* __restrict__ hTh,
              const float* __restrict__ Linp, const float* __restrict__ Wp,
              const float* __restrict__ bp, const float* __restrict__ srl,
              u16* __restrict__ agx_next, int tnext,
              float* __restrict__ out, int write_out) {
    const int b = blockIdx.x, mt = blockIdx.y;
    const int tid = threadIdx.x;
    const int w = tid >> 6, lane = tid & 63, l15 = lane & 15, l4 = lane >> 4;
    __shared__ char sAh[64*64];
    __shared__ float cs[64*65];
    __shared__ float sLp[64][22];
    __shared__ float sWp[21*40];
    __shared__ float sbp[40];
    __shared__ float ssr[64];

    float4v acc[4];
    #pragma unroll
    for (int i = 0; i < 4; ++i) acc[i] = (float4v){0.f,0.f,0.f,0.f};

    const int srow = tid >> 2, sfg = tid & 3;
    const int sdst = (srow*64 + sfg*16) ^ ((srow & 7) << 4);
    const size_t mrow = (size_t)(mt*64 + srow);
    const int ar = w*16 + l15;
    const int aoff = (ar*64 + l4*16) ^ ((ar & 7) << 4);

    for (int kt = 0; kt < 4; ++kt) {
        __syncthreads();
        int f0 = kt*32 + sfg*8;
        uint4 v;
        if (f0 < 40)       v = *(const uint4*)(agx + mrow*1280 + b*40 + f0);
        else if (f0 < 104) v = *(const uint4*)(agc + mrow*2048 + b*64 + (f0 - 40));
        else               v = (uint4){0,0,0,0};
        *(uint4*)(sAh + sdst) = v;
        __syncthreads();
        short8v a = *(const short8v*)(sAh + aoff);
        #pragma unroll
        for (int nf = 0; nf < 4; ++nf) {
            short8v bh = *(const short8v*)(W2h + (nf*16 + l15)*128 + kt*32 + l4*8);
            acc[nf] = __builtin_amdgcn_mfma_f32_16x16x32_bf16(a, bh, acc[nf], 0, 0, 0);
        }
    }
    #pragma unroll
    for (int nf = 0; nf < 4; ++nf) {
        int col = nf*16 + l15;
        float bias = b2[col];
        #pragma unroll
        for (int i = 0; i < 4; ++i) {
            int row = w*16 + l4*4 + i;
            cs[row*65 + col] = acc[nf][i] + bias;
        }
    }
    __syncthreads();
    const int c = tid & 63, ng = tid >> 6;
    for (int lc = 0; lc < 16; lc += 8) {
        int lr = ng*16 + lc;
        int m = mt*64 + lr;
        ushort8v hiv;
        #pragma unroll
        for (int d = 0; d < 8; ++d) {
            int mm = m + d;
            float hn = 0.f;
            if (mm < NN) {
                float x = cs[(lr+d)*65 + c];
                x = fminf(fmaxf(x, -15.f), 15.f);
                float e = __expf(2.f*x);
                float cand = (e - 1.f) / (e + 1.f);
                size_t idx = ((size_t)b*NN + mm)*64 + c;
                float u = u_lin[idx], h = h_lin[idx];
                hn = u*h + (1.f - u)*cand;
                h_lin[idx] = hn;
                if (write_out) out[idx] = hn;
            }
            hiv[d] = f2bf(hn);
        }
        *(ushort8v*)(hTh + (size_t)(b*64 + c)*KP + m) = hiv;
    }
    if (tnext < SEQ) {
        for (int i = tid; i < 64*21; i += 256) {
            int r = i / 21, f = i - r*21;
            sLp[r][f] = Linp[(size_t)(mt*64 + r)*LCOLS + tnext*672 + b*21 + f];
        }
        for (int i = tid; i < 21*40; i += 256) sWp[i] = Wp[i];
        if (tid < 40) sbp[tid] = bp[tid];
        if (tid < 64) ssr[tid] = srl[mt*64 + tid];
        __syncthreads();
        for (int o = tid; o < 64*40; o += 256) {
            int r = o / 40, a = o - r*40;
            float acc2 = ssr[r] * sbp[a];
            #pragma unroll
            for (int f = 0; f < 21; ++f) acc2 += sLp[r][f] * sWp[f*40 + a];
            agx_next[(size_t)(mt*64 + r)*1280 + b*40 + a] = f2bf(acc2);
        }
    }
}

// ---------------- standalone agx producer (t=0) ----------------
__global__ __launch_bounds__(256)
void k_xproj2(const float* __restrict__ Linp, const float* __restrict__ Wp,
              const float* __restrict__ bp, const float* __restrict__ srl,
              u16* __restrict__ agx, int t) {
    const int b = blockIdx.x, mt = blockIdx.y;
    const int tid = threadIdx.x;
    __shared__ float sLp[64][22];
    __shared__ float sWp[21*40];
    __shared__ float sbp[40];
    __shared__ float ssr[64];
    for (int i = tid; i < 64*21; i += 256) {
        int r = i / 21, f = i - r*21;
        sLp[r][f] = Linp[(size_t)(mt*64 + r)*LCOLS + t*672 + b*21 + f];
    }
    for (int i = tid; i < 21*40; i += 256) sWp[i] = Wp[i];
    if (tid < 40) sbp[tid] = bp[tid];
    if (tid < 64) ssr[tid] = srl[mt*64 + tid];
    __syncthreads();
    for (int o = tid; o < 64*40; o += 256) {
        int r = o / 40, a = o - r*40;
        float acc2 = ssr[r] * sbp[a];
        #pragma unroll
        for (int f = 0; f < 21; ++f) acc2 += sLp[r][f] * sWp[f*40 + a];
        agx[(size_t)(mt*64 + r)*1280 + b*40 + a] = f2bf(acc2);
    }
}

// ---------------- workspace layout (byte offsets, total ~239 MB of ~516 MB ws) ----------------
#define O_LHI   0ull
#define O_LINP  2097152ull
#define O_HLIN  134217728ull
#define O_ULIN  142409728ull
#define O_HTH   150601728ull
#define O_RHH   154796032ull
#define O_AGX0  158990336ull
#define O_AGX1  161611776ull
#define O_AGH   164233216ull
#define O_AGC   168427520ull
#define O_W1H   172621824ull
#define O_W2H   172654592ull
#define O_WP    172670976ull
#define O_BP    172675072ull
#define O_DINV  172675328ull
#define O_SRL   172679424ull
#define O_INT   172683520ull    // 66060288 -> end 238743808

extern "C" void kernel_launch(void* const* d_in, const int* in_sizes, int n_in,
                              void* d_out, int out_size, void* d_ws, size_t ws_size,
                              hipStream_t stream) {
    const float* inputs = (const float*)d_in[0];
    const float* adj    = (const float*)d_in[1];
    const float* Wo = (const float*)d_in[2];  const float* bo = (const float*)d_in[3];
    const float* Wd = (const float*)d_in[4];  const float* bd = (const float*)d_in[5];
    const float* We = (const float*)d_in[6];  const float* be = (const float*)d_in[7];
    const float* Wi = (const float*)d_in[8];  const float* bi = (const float*)d_in[9];
    const float* W1 = (const float*)d_in[10]; const float* b1 = (const float*)d_in[11];
    const float* W2 = (const float*)d_in[12]; const float* b2 = (const float*)d_in[13];
    float* out = (float*)d_out;

    char* ws = (char*)d_ws;
    u16*   Lhi   = (u16*)(ws + O_LHI);
    float* Linp  = (float*)(ws + O_LINP);
    float* h_lin = (float*)(ws + O_HLIN);
    float* u_lin = (float*)(ws + O_ULIN);
    u16*   hTh   = (u16*)(ws + O_HTH);
    u16*   rhh   = (u16*)(ws + O_RHH);
    u16*   agx0  = (u16*)(ws + O_AGX0);
    u16*   agx1  = (u16*)(ws + O_AGX1);
    u16*   agh   = (u16*)(ws + O_AGH);
    u16*   agc   = (u16*)(ws + O_AGC);
    u16*   W1h   = (u16*)(ws + O_W1H);
    u16*   W2h   = (u16*)(ws + O_W2H);
    float* Wp    = (float*)(ws + O_WP);
    float* bp    = (float*)(ws + O_BP);
    float* dinv  = (float*)(ws + O_DINV);
    float* srl   = (float*)(ws + O_SRL);
    u16*   inT   = (u16*)(ws + O_INT);

    k_rowsum<<<NN, 256, 0, stream>>>(adj, dinv);
    k_buildL<<<(KP*KP)/256, 256, 0, stream>>>(adj, dinv, Lhi);
    k_srow<<<KP, 256, 0, stream>>>(adj, dinv, srl);
    k_wconv<<<96, 256, 0, stream>>>(W1, W2, W1h, W2h);
    k_packW<<<1, 256, 0, stream>>>(Wo, bo, Wd, bd, We, be, Wi, bi, Wp, bp);
    k_transpose<<<dim3(BATCH*SEQ, 8), 256, 0, stream>>>(inputs, inT);
    k_gemm<0><<<dim3(LCOLS/64, 8), 512, 0, stream>>>(Lhi, inT, Linp, LCOLS);

    hipMemsetAsync(ws + O_HLIN, 0, 8192000ull, stream);
    hipMemsetAsync(ws + O_HTH,  0, 4194304ull, stream);
    hipMemsetAsync(ws + O_RHH,  0, 4194304ull, stream);
    k_xproj2<<<dim3(32,16), 256, 0, stream>>>(Linp, Wp, bp, srl, agx0, 0);

    for (int t = 0; t < SEQ; ++t) {
        u16* agxc = (t & 1) ? agx1 : agx0;
        u16* agxn = (t & 1) ? agx0 : agx1;
        k_gemm<1><<<dim3(HCOLS/64, 8), 512, 0, stream>>>(Lhi, hTh, agh, HCOLS);
        k_gate<<<dim3(32,16), 256, 0, stream>>>(agxc, agh, W1h, b1, h_lin, rhh, u_lin);
        k_gemm<1><<<dim3(HCOLS/64, 8), 512, 0, stream>>>(Lhi, rhh, agc, HCOLS);
        k_update<<<dim3(32,16), 256, 0, stream>>>(agxc, agc, W2h, b2, u_lin, h_lin, hTh,
                                                  Linp, Wp, bp, srl, agxn, t + 1,
                                                  out, t == SEQ - 1);
    }
}

// Round 6
// 2884.636 us; speedup vs baseline: 2.1137x; 1.3755x over previous
//
#include <hip/hip_runtime.h>
#include <math.h>

#define NN    1000
#define KP    1024
#define BATCH 32
#define SEQ   48
#define HID   64
#define LCOLS 32256                 // 48*32*21 premultiplied input cols
#define HCOLS 2048

typedef unsigned short u16;
typedef __attribute__((ext_vector_type(8))) short  short8v;
typedef __attribute__((ext_vector_type(8))) unsigned short ushort8v;
typedef __attribute__((ext_vector_type(4))) float  float4v;

__device__ __forceinline__ u16 f2bf(float x) {
    union { float f; unsigned u; } v; v.f = x;
    unsigned r = v.u + 0x7FFF + ((v.u >> 16) & 1);
    return (u16)(r >> 16);
}
__device__ __forceinline__ float bf2f(u16 h) {
    union { unsigned u; float f; } v; v.u = ((unsigned)h) << 16;
    return v.f;
}

// ---------------- Laplacian ----------------
__global__ void k_rowsum(const float* __restrict__ adj, float* __restrict__ dinv) {
    int m = blockIdx.x;
    float s = 0.f;
    for (int n = threadIdx.x; n < NN; n += blockDim.x)
        s += adj[(size_t)m*NN + n];
    __shared__ float red[256];
    red[threadIdx.x] = s; __syncthreads();
    for (int st = 128; st > 0; st >>= 1) {
        if (threadIdx.x < st) red[threadIdx.x] += red[threadIdx.x + st];
        __syncthreads();
    }
    if (threadIdx.x == 0) dinv[m] = rsqrtf(red[0] + 1.0f);
}

__global__ void k_buildL(const float* __restrict__ adj, const float* __restrict__ dinv,
                         u16* __restrict__ Lhi) {
    int idx = blockIdx.x * 256 + threadIdx.x;
    if (idx >= KP*KP) return;
    int m = idx >> 10, k = idx & (KP-1);
    float v = 0.f;
    if (m < NN && k < NN)
        v = dinv[m] * (adj[(size_t)m*NN + k] + (m == k ? 1.f : 0.f)) * dinv[k];
    Lhi[idx] = f2bf(v);
}

__global__ void k_srow(const float* __restrict__ adj, const float* __restrict__ dinv,
                       float* __restrict__ srl) {
    int m = blockIdx.x;
    __shared__ float red[256];
    float s = 0.f;
    if (m < NN)
        for (int n = threadIdx.x; n < NN; n += blockDim.x)
            s += adj[(size_t)m*NN + n] * dinv[n];
    red[threadIdx.x] = s; __syncthreads();
    for (int st = 128; st > 0; st >>= 1) {
        if (threadIdx.x < st) red[threadIdx.x] += red[threadIdx.x + st];
        __syncthreads();
    }
    if (threadIdx.x == 0) srl[m] = (m < NN) ? dinv[m] * (red[0] + dinv[m]) : 0.f;
}

// ---------------- W conversion ----------------
__global__ void k_wconv(const float* __restrict__ W1, const float* __restrict__ W2,
                        u16* __restrict__ W1h, u16* __restrict__ W2h) {
    int idx = blockIdx.x * 256 + threadIdx.x;
    if (idx < 128*128) {
        int k = idx >> 7, f = idx & 127;
        W1h[idx] = f2bf((f < 104) ? W1[f*128 + k] : 0.f);
    } else if (idx < 128*128 + 64*128) {
        int i2 = idx - 128*128;
        int c = i2 >> 7, f = i2 & 127;
        W2h[i2] = f2bf((f < 104) ? W2[f*64 + c] : 0.f);
    }
}

// ---------------- pack aspect projections ----------------
__global__ void k_packW(const float* __restrict__ Wo, const float* __restrict__ bo,
                        const float* __restrict__ Wd, const float* __restrict__ bd,
                        const float* __restrict__ We, const float* __restrict__ be,
                        const float* __restrict__ Wi, const float* __restrict__ bi,
                        float* __restrict__ Wp, float* __restrict__ bp) {
    for (int o = threadIdx.x; o < 21*40; o += 256) {
        int f = o / 40, a = o - f*40;
        int g = a / 10, aa = a - 10*g;
        float v = 0.f;
        if (g == 0) {
            if (f == 2) v = Wo[0*10+aa]; else if (f == 5) v = Wo[1*10+aa];
            else if (f == 8) v = Wo[2*10+aa]; else if (f == 9) v = Wo[3*10+aa];
            else if (f == 12) v = Wo[4*10+aa];
        } else if (g == 1) {
            if (f == 10) v = Wd[aa]; else if (f == 14) v = Wd[10+aa];
            else if (f == 15) v = Wd[20+aa];
        } else if (g == 2) {
            if (f == 13) v = We[aa]; else if (f == 17) v = We[10+aa];
        } else {
            if (f == 19) v = Wi[aa]; else if (f == 20) v = Wi[10+aa];
        }
        Wp[o] = v;
    }
    if (threadIdx.x < 40) {
        int a = threadIdx.x, g = a / 10, aa = a - 10*g;
        bp[a] = (g == 0) ? bo[aa] : (g == 1) ? bd[aa] : (g == 2) ? be[aa] : bi[aa];
    }
}

// ---------------- transpose inputs -> inT[(t*32+b)*21+f][1024] bf16 ----------------
__global__ __launch_bounds__(256)
void k_transpose(const float* __restrict__ inputs, u16* __restrict__ inT) {
    int bt = blockIdx.x;                // b*48 + t
    int b = bt / SEQ, t = bt - b*SEQ;
    int nt = blockIdx.y;
    __shared__ float sm[128][22];
    const float* base = inputs + ((size_t)bt * NN + nt*128) * 21;
    for (int i = threadIdx.x; i < 128*21; i += 256) {
        int nn = i / 21, f = i - nn*21;
        int n = nt*128 + nn;
        sm[nn][f] = (n < NN) ? base[(size_t)nn*21 + f] : 0.f;
    }
    __syncthreads();
    for (int o = threadIdx.x; o < 21*128; o += 256) {
        int f = o >> 7, nn = o & 127;
        inT[(size_t)((t*32 + b)*21 + f)*KP + nt*128 + nn] = f2bf(sm[nn][f]);
    }
}

// ---------------- plain MFMA GEMM (for the one-shot Linp), bf16 out ----------------
__global__ __launch_bounds__(512)
void k_gemm(const u16* __restrict__ A, const u16* __restrict__ B,
            u16* __restrict__ Cout, int ncols) {
    __shared__ char sA[128*64];
    __shared__ char sB[64*64];
    const int n0 = blockIdx.x * 64;
    const int m0 = blockIdx.y * 128;
    const int tid = threadIdx.x;
    const int w = tid >> 6, lane = tid & 63;
    const int l15 = lane & 15, l4 = lane >> 4;
    const int wm = w >> 1, wn = w & 1;

    float4v acc[2][2];
    #pragma unroll
    for (int i = 0; i < 2; ++i)
        #pragma unroll
        for (int j = 0; j < 2; ++j) acc[i][j] = (float4v){0.f,0.f,0.f,0.f};

    int aoff[2], boff[2];
    #pragma unroll
    for (int mf = 0; mf < 2; ++mf) {
        int r = wm*32 + mf*16 + l15;
        aoff[mf] = (r*64 + l4*16) ^ ((r & 7) << 4);
    }
    #pragma unroll
    for (int nf = 0; nf < 2; ++nf) {
        int r = wn*32 + nf*16 + l15;
        boff[nf] = (r*64 + l4*16) ^ ((r & 7) << 4);
    }
    const int rA = tid >> 2, qA = tid & 3;
    const int dA = (rA*64 + qA*16) ^ ((rA & 7) << 4);
    const size_t gA = (size_t)(m0 + rA)*KP + qA*8;
    const int rB = (tid & 255) >> 2, qB = tid & 3;
    const int dB = (rB*64 + qB*16) ^ ((rB & 7) << 4);
    const size_t gB = (size_t)(n0 + rB)*KP + qB*8;

    for (int kt = 0; kt < 32; ++kt) {
        const int k0 = kt*32;
        __syncthreads();
        *(uint4*)(sA + dA) = *(const uint4*)(A + gA + k0);
        if (tid < 256) *(uint4*)(sB + dB) = *(const uint4*)(B + gB + k0);
        __syncthreads();
        short8v a0 = *(const short8v*)(sA + aoff[0]);
        short8v a1 = *(const short8v*)(sA + aoff[1]);
        short8v b0 = *(const short8v*)(sB + boff[0]);
        short8v b1 = *(const short8v*)(sB + boff[1]);
        acc[0][0] = __builtin_amdgcn_mfma_f32_16x16x32_bf16(a0, b0, acc[0][0], 0, 0, 0);
        acc[0][1] = __builtin_amdgcn_mfma_f32_16x16x32_bf16(a0, b1, acc[0][1], 0, 0, 0);
        acc[1][0] = __builtin_amdgcn_mfma_f32_16x16x32_bf16(a1, b0, acc[1][0], 0, 0, 0);
        acc[1][1] = __builtin_amdgcn_mfma_f32_16x16x32_bf16(a1, b1, acc[1][1], 0, 0, 0);
    }
    #pragma unroll
    for (int mf = 0; mf < 2; ++mf)
        #pragma unroll
        for (int nf = 0; nf < 2; ++nf)
            #pragma unroll
            for (int i = 0; i < 4; ++i) {
                int m = m0 + wm*32 + mf*16 + l4*4 + i;
                int j = n0 + wn*32 + nf*16 + l15;
                Cout[(size_t)m*ncols + j] = f2bf(acc[mf][nf][i]);
            }
}

// ---------------- G1: agh = L@hT (one batch/block) + fused gate + r/u demux ----------------
__global__ __launch_bounds__(256)
void k_g1(const u16* __restrict__ Lhi, const u16* __restrict__ hTh,
          const u16* __restrict__ agx, const u16* __restrict__ W1h,
          const float* __restrict__ b1, const float* __restrict__ h_lin,
          u16* __restrict__ rhh, float* __restrict__ u_lin) {
    const int b = blockIdx.x, mt = blockIdx.y;
    const int m0 = mt*64;
    const int tid = threadIdx.x;
    const int w = tid >> 6, lane = tid & 63, l15 = lane & 15, l4 = lane >> 4;
    const int wm = w >> 1, wn = w & 1;

    __shared__ char smem[49408];
    char* sA = smem;                    // 4096 (main)
    char* sB = smem + 4096;             // 4096 (main)
    char* sF = smem;                    // 16384 (feature tile, after main)
    float* ru_s = (float*)(smem + 16384);   // 64*129*4 = 33024

    float4v acc[2][2];
    #pragma unroll
    for (int i = 0; i < 2; ++i)
        #pragma unroll
        for (int j = 0; j < 2; ++j) acc[i][j] = (float4v){0.f,0.f,0.f,0.f};

    int aoff[2], boff[2];
    #pragma unroll
    for (int mf = 0; mf < 2; ++mf) {
        int r = wm*32 + mf*16 + l15;
        aoff[mf] = (r*64 + l4*16) ^ ((r & 7) << 4);
    }
    #pragma unroll
    for (int nf = 0; nf < 2; ++nf) {
        int r = wn*32 + nf*16 + l15;
        boff[nf] = (r*64 + l4*16) ^ ((r & 7) << 4);
    }
    const int rA = tid >> 2, qA = tid & 3;
    const int dA = (rA*64 + qA*16) ^ ((rA & 7) << 4);
    const u16* Ap = Lhi + (size_t)(m0 + rA)*KP + qA*8;
    const u16* Bp = hTh + (size_t)(b*64 + rA)*KP + qA*8;

    for (int kt = 0; kt < 32; ++kt) {
        const int k0 = kt*32;
        __syncthreads();
        *(uint4*)(sA + dA) = *(const uint4*)(Ap + k0);
        *(uint4*)(sB + dA) = *(const uint4*)(Bp + k0);
        __syncthreads();
        short8v a0 = *(const short8v*)(sA + aoff[0]);
        short8v a1 = *(const short8v*)(sA + aoff[1]);
        short8v b0 = *(const short8v*)(sB + boff[0]);
        short8v b1 = *(const short8v*)(sB + boff[1]);
        acc[0][0] = __builtin_amdgcn_mfma_f32_16x16x32_bf16(a0, b0, acc[0][0], 0, 0, 0);
        acc[0][1] = __builtin_amdgcn_mfma_f32_16x16x32_bf16(a0, b1, acc[0][1], 0, 0, 0);
        acc[1][0] = __builtin_amdgcn_mfma_f32_16x16x32_bf16(a1, b0, acc[1][0], 0, 0, 0);
        acc[1][1] = __builtin_amdgcn_mfma_f32_16x16x32_bf16(a1, b1, acc[1][1], 0, 0, 0);
    }
    __syncthreads();   // main LDS dead; build feature tile sF [64 rows][128 f] bf16 swizzled
    if (tid < 192) {   // zero pad f 104..127
        int r = tid / 3, q = tid - 3*(tid/3);
        *(uint4*)(sF + ((r*256 + (13 + q)*16) ^ ((r & 7) << 4))) = (uint4){0,0,0,0};
    }
    for (int i = tid; i < 320; i += 256) {  // agx cols 0..39
        int r = i / 5, q = i - 5*(i/5);
        *(uint4*)(sF + ((r*256 + q*16) ^ ((r & 7) << 4))) =
            *(const uint4*)(agx + (size_t)(m0 + r)*1280 + b*40 + q*8);
    }
    #pragma unroll
    for (int mf = 0; mf < 2; ++mf)
        #pragma unroll
        for (int nf = 0; nf < 2; ++nf)
            #pragma unroll
            for (int i = 0; i < 4; ++i) {   // agh cols 40..103 from regs
                int row = wm*32 + mf*16 + l4*4 + i;
                int f = 40 + wn*32 + nf*16 + l15;
                *(u16*)(sF + ((row*256 + f*2) ^ ((row & 7) << 4))) = f2bf(acc[mf][nf][i]);
            }
    __syncthreads();

    // gate MFMA: 64 rows x 128 gate cols; wave: 32m x 64g
    const int gm = (w >> 1)*32, gn = (w & 1)*64;
    float4v acc2[2][4];
    #pragma unroll
    for (int i = 0; i < 2; ++i)
        #pragma unroll
        for (int j = 0; j < 4; ++j) acc2[i][j] = (float4v){0.f,0.f,0.f,0.f};
    for (int kt2 = 0; kt2 < 4; ++kt2) {
        #pragma unroll
        for (int mf = 0; mf < 2; ++mf) {
            int ar2 = gm + mf*16 + l15;
            short8v a = *(const short8v*)(sF + ((ar2*256 + kt2*64 + l4*16) ^ ((ar2 & 7) << 4)));
            #pragma unroll
            for (int nf = 0; nf < 4; ++nf) {
                short8v bb = *(const short8v*)(W1h + (gn + nf*16 + l15)*128 + kt2*32 + l4*8);
                acc2[mf][nf] = __builtin_amdgcn_mfma_f32_16x16x32_bf16(a, bb, acc2[mf][nf], 0, 0, 0);
            }
        }
    }
    #pragma unroll
    for (int mf = 0; mf < 2; ++mf)
        #pragma unroll
        for (int nf = 0; nf < 4; ++nf) {
            int col = gn + nf*16 + l15;
            float bias = b1[col];
            #pragma unroll
            for (int i = 0; i < 4; ++i) {
                int row = gm + mf*16 + l4*4 + i;
                ru_s[row*129 + col] = 1.f / (1.f + __expf(-(acc2[mf][nf][i] + bias)));
            }
        }
    __syncthreads();

    // demux: gate-row m<500 -> r for nodes 2m,2m+1 ; m>=500 -> u
    const int c = tid & 63, ng = tid >> 6;
    for (int lc = 0; lc < 16; lc += 4) {
        int lr = ng*16 + lc;
        int m = m0 + lr;
        if (m + 3 < 500) {
            unsigned hiw[4];
            #pragma unroll
            for (int d = 0; d < 4; ++d) {
                int mm = m + d;
                float r0 = ru_s[(lr+d)*129 + c];
                float r1 = ru_s[(lr+d)*129 + 64 + c];
                float h0 = h_lin[((size_t)b*NN + 2*mm)*64 + c];
                float h1 = h_lin[((size_t)b*NN + 2*mm + 1)*64 + c];
                u16 a0 = f2bf(r0*h0), a1 = f2bf(r1*h1);
                hiw[d] = (unsigned)a0 | ((unsigned)a1 << 16);
            }
            uint4 vh; vh.x = hiw[0]; vh.y = hiw[1]; vh.z = hiw[2]; vh.w = hiw[3];
            *(uint4*)(rhh + (size_t)(b*64 + c)*KP + 2*m) = vh;
        } else if (m >= 500) {
            #pragma unroll
            for (int d = 0; d < 4; ++d) {
                int mm = m + d;
                if (mm < 1000) {
                    int n = 2*(mm - 500);
                    u_lin[((size_t)b*NN + n)*64 + c]     = ru_s[(lr+d)*129 + c];
                    u_lin[((size_t)b*NN + n + 1)*64 + c] = ru_s[(lr+d)*129 + 64 + c];
                }
            }
        }
    }
}

// ---------------- G2: agc = L@rh + fused update + h'/hT/out/next-agx ----------------
__global__ __launch_bounds__(256)
void k_g2(const u16* __restrict__ Lhi, const u16* __restrict__ rhh,
          const u16* __restrict__ agx, const u16* __restrict__ W2h,
          const float* __restrict__ b2, const float* __restrict__ u_lin,
          float* __restrict__ h_lin, u16* __restrict__ hTh,
          const u16* __restrict__ LinpB, const float* __restrict__ Wp,
          const float* __restrict__ bp, const float* __restrict__ srl,
          u16* __restrict__ agx_next, int tnext,
          float* __restrict__ out, int write_out) {
    const int b = blockIdx.x, mt = blockIdx.y;
    const int m0 = mt*64;
    const int tid = threadIdx.x;
    const int w = tid >> 6, lane = tid & 63, l15 = lane & 15, l4 = lane >> 4;
    const int wm = w >> 1, wn = w & 1;

    __shared__ char smem[42016];
    char* sA = smem;                      // 4096
    char* sB = smem + 4096;               // 4096
    char* sF = smem;                      // 16384
    float* cs  = (float*)(smem + 16384);  // 64*65*4 = 16640
    float* sLp = (float*)(smem + 33024);  // 64*22*4 = 5632
    float* sWp = (float*)(smem + 38656);  // 21*40*4 = 3360
    __shared__ float sbp[40];
    __shared__ float ssr[64];

    float4v acc[2][2];
    #pragma unroll
    for (int i = 0; i < 2; ++i)
        #pragma unroll
        for (int j = 0; j < 2; ++j) acc[i][j] = (float4v){0.f,0.f,0.f,0.f};

    int aoff[2], boff[2];
    #pragma unroll
    for (int mf = 0; mf < 2; ++mf) {
        int r = wm*32 + mf*16 + l15;
        aoff[mf] = (r*64 + l4*16) ^ ((r & 7) << 4);
    }
    #pragma unroll
    for (int nf = 0; nf < 2; ++nf) {
        int r = wn*32 + nf*16 + l15;
        boff[nf] = (r*64 + l4*16) ^ ((r & 7) << 4);
    }
    const int rA = tid >> 2, qA = tid & 3;
    const int dA = (rA*64 + qA*16) ^ ((rA & 7) << 4);
    const u16* Ap = Lhi + (size_t)(m0 + rA)*KP + qA*8;
    const u16* Bp = rhh + (size_t)(b*64 + rA)*KP + qA*8;

    for (int kt = 0; kt < 32; ++kt) {
        const int k0 = kt*32;
        __syncthreads();
        *(uint4*)(sA + dA) = *(const uint4*)(Ap + k0);
        *(uint4*)(sB + dA) = *(const uint4*)(Bp + k0);
        __syncthreads();
        short8v a0 = *(const short8v*)(sA + aoff[0]);
        short8v a1 = *(const short8v*)(sA + aoff[1]);
        short8v b0 = *(const short8v*)(sB + boff[0]);
        short8v b1 = *(const short8v*)(sB + boff[1]);
        acc[0][0] = __builtin_amdgcn_mfma_f32_16x16x32_bf16(a0, b0, acc[0][0], 0, 0, 0);
        acc[0][1] = __builtin_amdgcn_mfma_f32_16x16x32_bf16(a0, b1, acc[0][1], 0, 0, 0);
        acc[1][0] = __builtin_amdgcn_mfma_f32_16x16x32_bf16(a1, b0, acc[1][0], 0, 0, 0);
        acc[1][1] = __builtin_amdgcn_mfma_f32_16x16x32_bf16(a1, b1, acc[1][1], 0, 0, 0);
    }
    __syncthreads();
    if (tid < 192) {
        int r = tid / 3, q = tid - 3*(tid/3);
        *(uint4*)(sF + ((r*256 + (13 + q)*16) ^ ((r & 7) << 4))) = (uint4){0,0,0,0};
    }
    for (int i = tid; i < 320; i += 256) {
        int r = i / 5, q = i - 5*(i/5);
        *(uint4*)(sF + ((r*256 + q*16) ^ ((r & 7) << 4))) =
            *(const uint4*)(agx + (size_t)(m0 + r)*1280 + b*40 + q*8);
    }
    #pragma unroll
    for (int mf = 0; mf < 2; ++mf)
        #pragma unroll
        for (int nf = 0; nf < 2; ++nf)
            #pragma unroll
            for (int i = 0; i < 4; ++i) {
                int row = wm*32 + mf*16 + l4*4 + i;
                int f = 40 + wn*32 + nf*16 + l15;
                *(u16*)(sF + ((row*256 + f*2) ^ ((row & 7) << 4))) = f2bf(acc[mf][nf][i]);
            }
    __syncthreads();

    // update MFMA: 64 rows x 64 cols; wave: 32m x 32c
    const int gm = (w >> 1)*32, gn = (w & 1)*32;
    float4v acc3[2][2];
    #pragma unroll
    for (int i = 0; i < 2; ++i)
        #pragma unroll
        for (int j = 0; j < 2; ++j) acc3[i][j] = (float4v){0.f,0.f,0.f,0.f};
    for (int kt2 = 0; kt2 < 4; ++kt2) {
        #pragma unroll
        for (int mf = 0; mf < 2; ++mf) {
            int ar2 = gm + mf*16 + l15;
            short8v a = *(const short8v*)(sF + ((ar2*256 + kt2*64 + l4*16) ^ ((ar2 & 7) << 4)));
            #pragma unroll
            for (int nf = 0; nf < 2; ++nf) {
                short8v bb = *(const short8v*)(W2h + (gn + nf*16 + l15)*128 + kt2*32 + l4*8);
                acc3[mf][nf] = __builtin_amdgcn_mfma_f32_16x16x32_bf16(a, bb, acc3[mf][nf], 0, 0, 0);
            }
        }
    }
    #pragma unroll
    for (int mf = 0; mf < 2; ++mf)
        #pragma unroll
        for (int nf = 0; nf < 2; ++nf) {
            int col = gn + nf*16 + l15;
            float bias = b2[col];
            #pragma unroll
            for (int i = 0; i < 4; ++i) {
                int row = gm + mf*16 + l4*4 + i;
                cs[row*65 + col] = acc3[mf][nf][i] + bias;
            }
        }
    __syncthreads();

    const int c = tid & 63, ng = tid >> 6;
    for (int lc = 0; lc < 16; lc += 8) {
        int lr = ng*16 + lc;
        int m = m0 + lr;
        ushort8v hiv;
        #pragma unroll
        for (int d = 0; d < 8; ++d) {
            int mm = m + d;
            float hn = 0.f;
            if (mm < NN) {
                float x = cs[(lr+d)*65 + c];
                x = fminf(fmaxf(x, -15.f), 15.f);
                float e = __expf(2.f*x);
                float cand = (e - 1.f) / (e + 1.f);
                size_t idx = ((size_t)b*NN + mm)*64 + c;
                float u = u_lin[idx], h = h_lin[idx];
                hn = u*h + (1.f - u)*cand;
                h_lin[idx] = hn;
                if (write_out) out[idx] = hn;
            }
            hiv[d] = f2bf(hn);
        }
        *(ushort8v*)(hTh + (size_t)(b*64 + c)*KP + m) = hiv;
    }

    if (tnext < SEQ) {
        for (int i = tid; i < 64*21; i += 256) {
            int r = i / 21, f = i - 21*(i/21);
            sLp[r*22 + f] = bf2f(LinpB[(size_t)(m0 + r)*LCOLS + tnext*672 + b*21 + f]);
        }
        for (int i = tid; i < 21*40; i += 256) sWp[i] = Wp[i];
        if (tid < 40) sbp[tid] = bp[tid];
        if (tid < 64) ssr[tid] = srl[m0 + tid];
        __syncthreads();
        for (int o = tid; o < 64*40; o += 256) {
            int r = o / 40, a = o - 40*(o/40);
            float acc4 = ssr[r] * sbp[a];
            #pragma unroll
            for (int f = 0; f < 21; ++f) acc4 += sLp[r*22 + f] * sWp[f*40 + a];
            agx_next[(size_t)(m0 + r)*1280 + b*40 + a] = f2bf(acc4);
        }
    }
}

// ---------------- standalone agx producer (t=0) ----------------
__global__ __launch_bounds__(256)
void k_xproj2(const u16* __restrict__ LinpB, const float* __restrict__ Wp,
              const float* __restrict__ bp, const float* __restrict__ srl,
              u16* __restrict__ agx, int t) {
    const int b = blockIdx.x, mt = blockIdx.y;
    const int tid = threadIdx.x;
    __shared__ float sLp[64][22];
    __shared__ float sWp[21*40];
    __shared__ float sbp[40];
    __shared__ float ssr[64];
    for (int i = tid; i < 64*21; i += 256) {
        int r = i / 21, f = i - 21*(i/21);
        sLp[r][f] = bf2f(LinpB[(size_t)(mt*64 + r)*LCOLS + t*672 + b*21 + f]);
    }
    for (int i = tid; i < 21*40; i += 256) sWp[i] = Wp[i];
    if (tid < 40) sbp[tid] = bp[tid];
    if (tid < 64) ssr[tid] = srl[mt*64 + tid];
    __syncthreads();
    for (int o = tid; o < 64*40; o += 256) {
        int r = o / 40, a = o - 40*(o/40);
        float acc2 = ssr[r] * sbp[a];
        #pragma unroll
        for (int f = 0; f < 21; ++f) acc2 += sLp[r][f] * sWp[f*40 + a];
        agx[(size_t)(mt*64 + r)*1280 + b*40 + a] = f2bf(acc2);
    }
}

// ---------------- workspace layout (byte offsets, ~164 MB of ~516 MB ws) ----------------
#define O_LHI   0ull
#define O_LINP  2097152ull       // bf16: 66060288 -> 68157440
#define O_HLIN  68157440ull      // 8192000
#define O_ULIN  76349440ull      // 8192000
#define O_HTH   84541440ull      // 4194304
#define O_RHH   88735744ull      // 4194304
#define O_AGX0  92930048ull      // 2621440
#define O_AGX1  95551488ull      // 2621440
#define O_W1H   98172928ull      // 32768
#define O_W2H   98205696ull      // 16384
#define O_WP    98222080ull      // 4096 (3360 used)
#define O_BP    98226176ull      // 256
#define O_DINV  98226432ull      // 4096
#define O_SRL   98230528ull      // 4096
#define O_INT   98234624ull      // 66060288 -> 164294912

extern "C" void kernel_launch(void* const* d_in, const int* in_sizes, int n_in,
                              void* d_out, int out_size, void* d_ws, size_t ws_size,
                              hipStream_t stream) {
    const float* inputs = (const float*)d_in[0];
    const float* adj    = (const float*)d_in[1];
    const float* Wo = (const float*)d_in[2];  const float* bo = (const float*)d_in[3];
    const float* Wd = (const float*)d_in[4];  const float* bd = (const float*)d_in[5];
    const float* We = (const float*)d_in[6];  const float* be = (const float*)d_in[7];
    const float* Wi = (const float*)d_in[8];  const float* bi = (const float*)d_in[9];
    const float* W1 = (const float*)d_in[10]; const float* b1 = (const float*)d_in[11];
    const float* W2 = (const float*)d_in[12]; const float* b2 = (const float*)d_in[13];
    float* out = (float*)d_out;

    char* ws = (char*)d_ws;
    u16*   Lhi   = (u16*)(ws + O_LHI);
    u16*   LinpB = (u16*)(ws + O_LINP);
    float* h_lin = (float*)(ws + O_HLIN);
    float* u_lin = (float*)(ws + O_ULIN);
    u16*   hTh   = (u16*)(ws + O_HTH);
    u16*   rhh   = (u16*)(ws + O_RHH);
    u16*   agx0  = (u16*)(ws + O_AGX0);
    u16*   agx1  = (u16*)(ws + O_AGX1);
    u16*   W1h   = (u16*)(ws + O_W1H);
    u16*   W2h   = (u16*)(ws + O_W2H);
    float* Wp    = (float*)(ws + O_WP);
    float* bp    = (float*)(ws + O_BP);
    float* dinv  = (float*)(ws + O_DINV);
    float* srl   = (float*)(ws + O_SRL);
    u16*   inT   = (u16*)(ws + O_INT);

    k_rowsum<<<NN, 256, 0, stream>>>(adj, dinv);
    k_buildL<<<(KP*KP)/256, 256, 0, stream>>>(adj, dinv, Lhi);
    k_srow<<<KP, 256, 0, stream>>>(adj, dinv, srl);
    k_wconv<<<96, 256, 0, stream>>>(W1, W2, W1h, W2h);
    k_packW<<<1, 256, 0, stream>>>(Wo, bo, Wd, bd, We, be, Wi, bi, Wp, bp);
    k_transpose<<<dim3(BATCH*SEQ, 8), 256, 0, stream>>>(inputs, inT);
    k_gemm<<<dim3(LCOLS/64, 8), 512, 0, stream>>>(Lhi, inT, LinpB, LCOLS);

    hipMemsetAsync(ws + O_HLIN, 0, 8192000ull, stream);
    hipMemsetAsync(ws + O_HTH,  0, 4194304ull, stream);
    hipMemsetAsync(ws + O_RHH,  0, 4194304ull, stream);
    k_xproj2<<<dim3(32,16), 256, 0, stream>>>(LinpB, Wp, bp, srl, agx0, 0);

    for (int t = 0; t < SEQ; ++t) {
        u16* agxc = (t & 1) ? agx1 : agx0;
        u16* agxn = (t & 1) ? agx0 : agx1;
        k_g1<<<dim3(32,16), 256, 0, stream>>>(Lhi, hTh, agxc, W1h, b1, h_lin, rhh, u_lin);
        k_g2<<<dim3(32,16), 256, 0, stream>>>(Lhi, rhh, agxc, W2h, b2, u_lin, h_lin, hTh,
                                              LinpB, Wp, bp, srl, agxn, t + 1,
                                              out, t == SEQ - 1);
    }
}

// Round 7
// 2689.520 us; speedup vs baseline: 2.2671x; 1.0725x over previous
//
#include <hip/hip_runtime.h>
#include <math.h>

#define NN    1000
#define KP    1024
#define BATCH 32
#define SEQ   48
#define HID   64
#define LCOLS 32256                 // 48*32*21 premultiplied input cols

typedef unsigned short u16;
typedef __attribute__((ext_vector_type(8))) short  short8v;
typedef __attribute__((ext_vector_type(8))) unsigned short ushort8v;
typedef __attribute__((ext_vector_type(4))) float  float4v;

__device__ __forceinline__ u16 f2bf(float x) {
    union { float f; unsigned u; } v; v.f = x;
    unsigned r = v.u + 0x7FFF + ((v.u >> 16) & 1);
    return (u16)(r >> 16);
}
__device__ __forceinline__ float bf2f(u16 h) {
    union { unsigned u; float f; } v; v.u = ((unsigned)h) << 16;
    return v.f;
}

// ---------------- Laplacian ----------------
__global__ void k_rowsum(const float* __restrict__ adj, float* __restrict__ dinv) {
    int m = blockIdx.x;
    float s = 0.f;
    for (int n = threadIdx.x; n < NN; n += blockDim.x)
        s += adj[(size_t)m*NN + n];
    __shared__ float red[256];
    red[threadIdx.x] = s; __syncthreads();
    for (int st = 128; st > 0; st >>= 1) {
        if (threadIdx.x < st) red[threadIdx.x] += red[threadIdx.x + st];
        __syncthreads();
    }
    if (threadIdx.x == 0) dinv[m] = rsqrtf(red[0] + 1.0f);
}

// row-major L (for the one-shot Linp GEMM)
__global__ void k_buildL(const float* __restrict__ adj, const float* __restrict__ dinv,
                         u16* __restrict__ Lhi) {
    int idx = blockIdx.x * 256 + threadIdx.x;
    if (idx >= KP*KP) return;
    int m = idx >> 10, k = idx & (KP-1);
    float v = 0.f;
    if (m < NN && k < NN)
        v = dinv[m] * (adj[(size_t)m*NN + k] + (m == k ? 1.f : 0.f)) * dinv[k];
    Lhi[idx] = f2bf(v);
}

// fragment-order L: idx = ((mg*32+kb)*64 + lane)*8 + e ; m=mg*16+(lane&15), k=kb*32+(lane>>4)*8+e
__global__ void k_buildLf(const float* __restrict__ adj, const float* __restrict__ dinv,
                          u16* __restrict__ Lf) {
    size_t idx = (size_t)blockIdx.x * 256 + threadIdx.x;
    if (idx >= (size_t)KP*KP) return;
    int e    = idx & 7;
    int lane = (idx >> 3) & 63;
    int kb   = (idx >> 9) & 31;
    int mg   = idx >> 14;
    int m = mg*16 + (lane & 15);
    int k = kb*32 + (lane >> 4)*8 + e;
    float v = 0.f;
    if (m < NN && k < NN)
        v = dinv[m] * (adj[(size_t)m*NN + k] + (m == k ? 1.f : 0.f)) * dinv[k];
    Lf[idx] = f2bf(v);
}

__global__ void k_srow(const float* __restrict__ adj, const float* __restrict__ dinv,
                       float* __restrict__ srl) {
    int m = blockIdx.x;
    __shared__ float red[256];
    float s = 0.f;
    if (m < NN)
        for (int n = threadIdx.x; n < NN; n += blockDim.x)
            s += adj[(size_t)m*NN + n] * dinv[n];
    red[threadIdx.x] = s; __syncthreads();
    for (int st = 128; st > 0; st >>= 1) {
        if (threadIdx.x < st) red[threadIdx.x] += red[threadIdx.x + st];
        __syncthreads();
    }
    if (threadIdx.x == 0) srl[m] = (m < NN) ? dinv[m] * (red[0] + dinv[m]) : 0.f;
}

// ---------------- W conversion ----------------
__global__ void k_wconv(const float* __restrict__ W1, const float* __restrict__ W2,
                        u16* __restrict__ W1h, u16* __restrict__ W2h) {
    int idx = blockIdx.x * 256 + threadIdx.x;
    if (idx < 128*128) {
        int k = idx >> 7, f = idx & 127;
        W1h[idx] = f2bf((f < 104) ? W1[f*128 + k] : 0.f);
    } else if (idx < 128*128 + 64*128) {
        int i2 = idx - 128*128;
        int c = i2 >> 7, f = i2 & 127;
        W2h[i2] = f2bf((f < 104) ? W2[f*64 + c] : 0.f);
    }
}

// ---------------- pack aspect projections ----------------
__global__ void k_packW(const float* __restrict__ Wo, const float* __restrict__ bo,
                        const float* __restrict__ Wd, const float* __restrict__ bd,
                        const float* __restrict__ We, const float* __restrict__ be,
                        const float* __restrict__ Wi, const float* __restrict__ bi,
                        float* __restrict__ Wp, float* __restrict__ bp) {
    for (int o = threadIdx.x; o < 21*40; o += 256) {
        int f = o / 40, a = o - f*40;
        int g = a / 10, aa = a - 10*g;
        float v = 0.f;
        if (g == 0) {
            if (f == 2) v = Wo[0*10+aa]; else if (f == 5) v = Wo[1*10+aa];
            else if (f == 8) v = Wo[2*10+aa]; else if (f == 9) v = Wo[3*10+aa];
            else if (f == 12) v = Wo[4*10+aa];
        } else if (g == 1) {
            if (f == 10) v = Wd[aa]; else if (f == 14) v = Wd[10+aa];
            else if (f == 15) v = Wd[20+aa];
        } else if (g == 2) {
            if (f == 13) v = We[aa]; else if (f == 17) v = We[10+aa];
        } else {
            if (f == 19) v = Wi[aa]; else if (f == 20) v = Wi[10+aa];
        }
        Wp[o] = v;
    }
    if (threadIdx.x < 40) {
        int a = threadIdx.x, g = a / 10, aa = a - 10*g;
        bp[a] = (g == 0) ? bo[aa] : (g == 1) ? bd[aa] : (g == 2) ? be[aa] : bi[aa];
    }
}

// ---------------- transpose inputs -> inT[(t*32+b)*21+f][1024] bf16 ----------------
__global__ __launch_bounds__(256)
void k_transpose(const float* __restrict__ inputs, u16* __restrict__ inT) {
    int bt = blockIdx.x;                // b*48 + t
    int b = bt / SEQ, t = bt - b*SEQ;
    int nt = blockIdx.y;
    __shared__ float sm[128][22];
    const float* base = inputs + ((size_t)bt * NN + nt*128) * 21;
    for (int i = threadIdx.x; i < 128*21; i += 256) {
        int nn = i / 21, f = i - nn*21;
        int n = nt*128 + nn;
        sm[nn][f] = (n < NN) ? base[(size_t)nn*21 + f] : 0.f;
    }
    __syncthreads();
    for (int o = threadIdx.x; o < 21*128; o += 256) {
        int f = o >> 7, nn = o & 127;
        inT[(size_t)((t*32 + b)*21 + f)*KP + nt*128 + nn] = f2bf(sm[nn][f]);
    }
}

// ---------------- plain MFMA GEMM (one-shot Linp), bf16 out ----------------
__global__ __launch_bounds__(512)
void k_gemm(const u16* __restrict__ A, const u16* __restrict__ B,
            u16* __restrict__ Cout, int ncols) {
    __shared__ char sA[128*64];
    __shared__ char sB[64*64];
    const int n0 = blockIdx.x * 64;
    const int m0 = blockIdx.y * 128;
    const int tid = threadIdx.x;
    const int w = tid >> 6, lane = tid & 63;
    const int l15 = lane & 15, l4 = lane >> 4;
    const int wm = w >> 1, wn = w & 1;

    float4v acc[2][2];
    #pragma unroll
    for (int i = 0; i < 2; ++i)
        #pragma unroll
        for (int j = 0; j < 2; ++j) acc[i][j] = (float4v){0.f,0.f,0.f,0.f};

    int aoff[2], boff[2];
    #pragma unroll
    for (int mf = 0; mf < 2; ++mf) {
        int r = wm*32 + mf*16 + l15;
        aoff[mf] = (r*64 + l4*16) ^ ((r & 7) << 4);
    }
    #pragma unroll
    for (int nf = 0; nf < 2; ++nf) {
        int r = wn*32 + nf*16 + l15;
        boff[nf] = (r*64 + l4*16) ^ ((r & 7) << 4);
    }
    const int rA = tid >> 2, qA = tid & 3;
    const int dA = (rA*64 + qA*16) ^ ((rA & 7) << 4);
    const size_t gA = (size_t)(m0 + rA)*KP + qA*8;
    const int rB = (tid & 255) >> 2, qB = tid & 3;
    const int dB = (rB*64 + qB*16) ^ ((rB & 7) << 4);
    const size_t gB = (size_t)(n0 + rB)*KP + qB*8;

    for (int kt = 0; kt < 32; ++kt) {
        const int k0 = kt*32;
        __syncthreads();
        *(uint4*)(sA + dA) = *(const uint4*)(A + gA + k0);
        if (tid < 256) *(uint4*)(sB + dB) = *(const uint4*)(B + gB + k0);
        __syncthreads();
        short8v a0 = *(const short8v*)(sA + aoff[0]);
        short8v a1 = *(const short8v*)(sA + aoff[1]);
        short8v b0 = *(const short8v*)(sB + boff[0]);
        short8v b1 = *(const short8v*)(sB + boff[1]);
        acc[0][0] = __builtin_amdgcn_mfma_f32_16x16x32_bf16(a0, b0, acc[0][0], 0, 0, 0);
        acc[0][1] = __builtin_amdgcn_mfma_f32_16x16x32_bf16(a0, b1, acc[0][1], 0, 0, 0);
        acc[1][0] = __builtin_amdgcn_mfma_f32_16x16x32_bf16(a1, b0, acc[1][0], 0, 0, 0);
        acc[1][1] = __builtin_amdgcn_mfma_f32_16x16x32_bf16(a1, b1, acc[1][1], 0, 0, 0);
    }
    #pragma unroll
    for (int mf = 0; mf < 2; ++mf)
        #pragma unroll
        for (int nf = 0; nf < 2; ++nf)
            #pragma unroll
            for (int i = 0; i < 4; ++i) {
                int m = m0 + wm*32 + mf*16 + l4*4 + i;
                int j = n0 + wn*32 + nf*16 + l15;
                Cout[(size_t)m*ncols + j] = f2bf(acc[mf][nf][i]);
            }
}

// frag helper: offset (in u16) of fragment (grp, kb) for this lane
__device__ __forceinline__ size_t frag_off(int grp, int kb, int lane) {
    return (((size_t)grp*32 + kb)*64 + lane)*8;
}

// ---------------- G1: agh = L@hT (frag-direct) + fused gate + r/u demux ----------------
__global__ __launch_bounds__(256)
void k_g1(const u16* __restrict__ Lf, const u16* __restrict__ hTf,
          const u16* __restrict__ agx, const u16* __restrict__ W1h,
          const float* __restrict__ b1, const float* __restrict__ h_lin,
          u16* __restrict__ rhf, float* __restrict__ u_lin) {
    const int b = blockIdx.x, mt = blockIdx.y;
    const int m0 = mt*64;
    const int tid = threadIdx.x;
    const int w = tid >> 6, lane = tid & 63, l15 = lane & 15, l4 = lane >> 4;
    const int wm = w >> 1, wn = w & 1;

    __shared__ char smem[49408];
    char* sF = smem;                        // 16384: feature tile [64][128] bf16 swizzled
    float* ru_s = (float*)(smem + 16384);   // 64*129*4

    float4v acc[2][2];
    #pragma unroll
    for (int i = 0; i < 2; ++i)
        #pragma unroll
        for (int j = 0; j < 2; ++j) acc[i][j] = (float4v){0.f,0.f,0.f,0.f};

    const u16* A0 = Lf  + frag_off(mt*4 + wm*2 + 0, 0, lane);
    const u16* A1 = Lf  + frag_off(mt*4 + wm*2 + 1, 0, lane);
    const u16* B0 = hTf + frag_off(b*4  + wn*2 + 0, 0, lane);
    const u16* B1 = hTf + frag_off(b*4  + wn*2 + 1, 0, lane);
    #pragma unroll 8
    for (int kb = 0; kb < 32; ++kb) {
        short8v a0 = *(const short8v*)(A0 + kb*512);
        short8v a1 = *(const short8v*)(A1 + kb*512);
        short8v b0 = *(const short8v*)(B0 + kb*512);
        short8v b1 = *(const short8v*)(B1 + kb*512);
        acc[0][0] = __builtin_amdgcn_mfma_f32_16x16x32_bf16(a0, b0, acc[0][0], 0, 0, 0);
        acc[0][1] = __builtin_amdgcn_mfma_f32_16x16x32_bf16(a0, b1, acc[0][1], 0, 0, 0);
        acc[1][0] = __builtin_amdgcn_mfma_f32_16x16x32_bf16(a1, b0, acc[1][0], 0, 0, 0);
        acc[1][1] = __builtin_amdgcn_mfma_f32_16x16x32_bf16(a1, b1, acc[1][1], 0, 0, 0);
    }

    // build feature tile sF [64 rows][128 f] bf16 swizzled
    if (tid < 192) {   // zero pad f 104..127
        int r = tid / 3, q = tid - 3*(tid/3);
        *(uint4*)(sF + ((r*256 + (13 + q)*16) ^ ((r & 7) << 4))) = (uint4){0,0,0,0};
    }
    for (int i = tid; i < 320; i += 256) {  // agx cols 0..39
        int r = i / 5, q = i - 5*(i/5);
        *(uint4*)(sF + ((r*256 + q*16) ^ ((r & 7) << 4))) =
            *(const uint4*)(agx + (size_t)(m0 + r)*1280 + b*40 + q*8);
    }
    #pragma unroll
    for (int mf = 0; mf < 2; ++mf)
        #pragma unroll
        for (int nf = 0; nf < 2; ++nf)
            #pragma unroll
            for (int i = 0; i < 4; ++i) {   // agh cols 40..103 from regs
                int row = wm*32 + mf*16 + l4*4 + i;
                int f = 40 + wn*32 + nf*16 + l15;
                *(u16*)(sF + ((row*256 + f*2) ^ ((row & 7) << 4))) = f2bf(acc[mf][nf][i]);
            }
    __syncthreads();

    // gate MFMA: 64 rows x 128 gate cols; wave: 32m x 64g
    const int gm = (w >> 1)*32, gn = (w & 1)*64;
    float4v acc2[2][4];
    #pragma unroll
    for (int i = 0; i < 2; ++i)
        #pragma unroll
        for (int j = 0; j < 4; ++j) acc2[i][j] = (float4v){0.f,0.f,0.f,0.f};
    for (int kt2 = 0; kt2 < 4; ++kt2) {
        #pragma unroll
        for (int mf = 0; mf < 2; ++mf) {
            int ar2 = gm + mf*16 + l15;
            short8v a = *(const short8v*)(sF + ((ar2*256 + kt2*64 + l4*16) ^ ((ar2 & 7) << 4)));
            #pragma unroll
            for (int nf = 0; nf < 4; ++nf) {
                short8v bb = *(const short8v*)(W1h + (gn + nf*16 + l15)*128 + kt2*32 + l4*8);
                acc2[mf][nf] = __builtin_amdgcn_mfma_f32_16x16x32_bf16(a, bb, acc2[mf][nf], 0, 0, 0);
            }
        }
    }
    #pragma unroll
    for (int mf = 0; mf < 2; ++mf)
        #pragma unroll
        for (int nf = 0; nf < 4; ++nf) {
            int col = gn + nf*16 + l15;
            float bias = b1[col];
            #pragma unroll
            for (int i = 0; i < 4; ++i) {
                int row = gm + mf*16 + l4*4 + i;
                ru_s[row*129 + col] = 1.f / (1.f + __expf(-(acc2[mf][nf][i] + bias)));
            }
        }
    __syncthreads();

    // demux. r: gate row m<500 -> r(2m), r(2m+1); write rh in fragment order.
    const int c = tid & 63, ng = tid >> 6;
    #pragma unroll
    for (int it = 0; it < 4; ++it) {
        int nc = (it*4 + ng)*8;            // local node offset 0..120
        int n = 2*m0 + nc;                 // global start node (even, mult of 8)
        if ((n >> 1) + 3 < 500) {          // rows n/2..n/2+3 all in r-region
            ushort8v ov;
            #pragma unroll
            for (int d = 0; d < 8; ++d) {
                int nn = n + d;
                float r = ru_s[((nc + d) >> 1)*129 + (nn & 1)*64 + c];
                float h = h_lin[((size_t)b*NN + nn)*64 + c];
                ov[d] = f2bf(r*h);
            }
            *(ushort8v*)(rhf + frag_off(b*4 + (c >> 4), n >> 5, (c & 15) + 16*((n >> 3) & 3))) = ov;
        }
    }
    // u: gate row m>=500 -> u nodes 2(m-500), +1 (linear layout)
    for (int lc = 0; lc < 16; lc += 4) {
        int lr = ng*16 + lc;
        int m = m0 + lr;
        if (m >= 500) {
            #pragma unroll
            for (int d = 0; d < 4; ++d) {
                int mm = m + d;
                if (mm < 1000) {
                    int n = 2*(mm - 500);
                    u_lin[((size_t)b*NN + n)*64 + c]     = ru_s[(lr+d)*129 + c];
                    u_lin[((size_t)b*NN + n + 1)*64 + c] = ru_s[(lr+d)*129 + 64 + c];
                }
            }
        }
    }
}

// ---------------- G2: agc = L@rh (frag-direct) + fused update + h'/hT/out/next-agx ----------------
__global__ __launch_bounds__(256)
void k_g2(const u16* __restrict__ Lf, const u16* __restrict__ rhf,
          const u16* __restrict__ agx, const u16* __restrict__ W2h,
          const float* __restrict__ b2, const float* __restrict__ u_lin,
          float* __restrict__ h_lin, u16* __restrict__ hTf,
          const u16* __restrict__ LinpB, const float* __restrict__ Wp,
          const float* __restrict__ bp, const float* __restrict__ srl,
          u16* __restrict__ agx_next, int tnext,
          float* __restrict__ out, int write_out) {
    const int b = blockIdx.x, mt = blockIdx.y;
    const int m0 = mt*64;
    const int tid = threadIdx.x;
    const int w = tid >> 6, lane = tid & 63, l15 = lane & 15, l4 = lane >> 4;
    const int wm = w >> 1, wn = w & 1;

    __shared__ char smem[42016];
    char* sF = smem;                      // 16384
    float* cs  = (float*)(smem + 16384);  // 64*65*4 = 16640
    float* sLp = (float*)(smem + 33024);  // 64*22*4 = 5632
    float* sWp = (float*)(smem + 38656);  // 21*40*4 = 3360
    __shared__ float sbp[40];
    __shared__ float ssr[64];

    float4v acc[2][2];
    #pragma unroll
    for (int i = 0; i < 2; ++i)
        #pragma unroll
        for (int j = 0; j < 2; ++j) acc[i][j] = (float4v){0.f,0.f,0.f,0.f};

    const u16* A0 = Lf  + frag_off(mt*4 + wm*2 + 0, 0, lane);
    const u16* A1 = Lf  + frag_off(mt*4 + wm*2 + 1, 0, lane);
    const u16* B0 = rhf + frag_off(b*4  + wn*2 + 0, 0, lane);
    const u16* B1 = rhf + frag_off(b*4  + wn*2 + 1, 0, lane);
    #pragma unroll 8
    for (int kb = 0; kb < 32; ++kb) {
        short8v a0 = *(const short8v*)(A0 + kb*512);
        short8v a1 = *(const short8v*)(A1 + kb*512);
        short8v b0 = *(const short8v*)(B0 + kb*512);
        short8v b1 = *(const short8v*)(B1 + kb*512);
        acc[0][0] = __builtin_amdgcn_mfma_f32_16x16x32_bf16(a0, b0, acc[0][0], 0, 0, 0);
        acc[0][1] = __builtin_amdgcn_mfma_f32_16x16x32_bf16(a0, b1, acc[0][1], 0, 0, 0);
        acc[1][0] = __builtin_amdgcn_mfma_f32_16x16x32_bf16(a1, b0, acc[1][0], 0, 0, 0);
        acc[1][1] = __builtin_amdgcn_mfma_f32_16x16x32_bf16(a1, b1, acc[1][1], 0, 0, 0);
    }

    if (tid < 192) {
        int r = tid / 3, q = tid - 3*(tid/3);
        *(uint4*)(sF + ((r*256 + (13 + q)*16) ^ ((r & 7) << 4))) = (uint4){0,0,0,0};
    }
    for (int i = tid; i < 320; i += 256) {
        int r = i / 5, q = i - 5*(i/5);
        *(uint4*)(sF + ((r*256 + q*16) ^ ((r & 7) << 4))) =
            *(const uint4*)(agx + (size_t)(m0 + r)*1280 + b*40 + q*8);
    }
    #pragma unroll
    for (int mf = 0; mf < 2; ++mf)
        #pragma unroll
        for (int nf = 0; nf < 2; ++nf)
            #pragma unroll
            for (int i = 0; i < 4; ++i) {
                int row = wm*32 + mf*16 + l4*4 + i;
                int f = 40 + wn*32 + nf*16 + l15;
                *(u16*)(sF + ((row*256 + f*2) ^ ((row & 7) << 4))) = f2bf(acc[mf][nf][i]);
            }
    __syncthreads();

    // update MFMA: 64 rows x 64 cols; wave: 32m x 32c
    const int gm = (w >> 1)*32, gn = (w & 1)*32;
    float4v acc3[2][2];
    #pragma unroll
    for (int i = 0; i < 2; ++i)
        #pragma unroll
        for (int j = 0; j < 2; ++j) acc3[i][j] = (float4v){0.f,0.f,0.f,0.f};
    for (int kt2 = 0; kt2 < 4; ++kt2) {
        #pragma unroll
        for (int mf = 0; mf < 2; ++mf) {
            int ar2 = gm + mf*16 + l15;
            short8v a = *(const short8v*)(sF + ((ar2*256 + kt2*64 + l4*16) ^ ((ar2 & 7) << 4)));
            #pragma unroll
            for (int nf = 0; nf < 2; ++nf) {
                short8v bb = *(const short8v*)(W2h + (gn + nf*16 + l15)*128 + kt2*32 + l4*8);
                acc3[mf][nf] = __builtin_amdgcn_mfma_f32_16x16x32_bf16(a, bb, acc3[mf][nf], 0, 0, 0);
            }
        }
    }
    #pragma unroll
    for (int mf = 0; mf < 2; ++mf)
        #pragma unroll
        for (int nf = 0; nf < 2; ++nf) {
            int col = gn + nf*16 + l15;
            float bias = b2[col];
            #pragma unroll
            for (int i = 0; i < 4; ++i) {
                int row = gm + mf*16 + l4*4 + i;
                cs[row*65 + col] = acc3[mf][nf][i] + bias;
            }
        }
    __syncthreads();

    const int c = tid & 63, ng = tid >> 6;
    for (int lc = 0; lc < 16; lc += 8) {
        int lr = ng*16 + lc;
        int m = m0 + lr;                     // node chunk m..m+7
        ushort8v hiv;
        #pragma unroll
        for (int d = 0; d < 8; ++d) {
            int mm = m + d;
            float hn = 0.f;
            if (mm < NN) {
                float x = cs[(lr+d)*65 + c];
                x = fminf(fmaxf(x, -15.f), 15.f);
                float e = __expf(2.f*x);
                float cand = (e - 1.f) / (e + 1.f);
                size_t idx = ((size_t)b*NN + mm)*64 + c;
                float u = u_lin[idx], h = h_lin[idx];
                hn = u*h + (1.f - u)*cand;
                h_lin[idx] = hn;
                if (write_out) out[idx] = hn;
            }
            hiv[d] = f2bf(hn);
        }
        *(ushort8v*)(hTf + frag_off(b*4 + (c >> 4), m >> 5, (c & 15) + 16*((m >> 3) & 3))) = hiv;
    }

    if (tnext < SEQ) {
        for (int i = tid; i < 64*21; i += 256) {
            int r = i / 21, f = i - 21*(i/21);
            sLp[r*22 + f] = bf2f(LinpB[(size_t)(m0 + r)*LCOLS + tnext*672 + b*21 + f]);
        }
        for (int i = tid; i < 21*40; i += 256) sWp[i] = Wp[i];
        if (tid < 40) sbp[tid] = bp[tid];
        if (tid < 64) ssr[tid] = srl[m0 + tid];
        __syncthreads();
        for (int o = tid; o < 64*40; o += 256) {
            int r = o / 40, a = o - 40*(o/40);
            float acc4 = ssr[r] * sbp[a];
            #pragma unroll
            for (int f = 0; f < 21; ++f) acc4 += sLp[r*22 + f] * sWp[f*40 + a];
            agx_next[(size_t)(m0 + r)*1280 + b*40 + a] = f2bf(acc4);
        }
    }
}

// ---------------- standalone agx producer (t=0) ----------------
__global__ __launch_bounds__(256)
void k_xproj2(const u16* __restrict__ LinpB, const float* __restrict__ Wp,
              const float* __restrict__ bp, const float* __restrict__ srl,
              u16* __restrict__ agx, int t) {
    const int b = blockIdx.x, mt = blockIdx.y;
    const int tid = threadIdx.x;
    __shared__ float sLp[64][22];
    __shared__ float sWp[21*40];
    __shared__ float sbp[40];
    __shared__ float ssr[64];
    for (int i = tid; i < 64*21; i += 256) {
        int r = i / 21, f = i - 21*(i/21);
        sLp[r][f] = bf2f(LinpB[(size_t)(mt*64 + r)*LCOLS + t*672 + b*21 + f]);
    }
    for (int i = tid; i < 21*40; i += 256) sWp[i] = Wp[i];
    if (tid < 40) sbp[tid] = bp[tid];
    if (tid < 64) ssr[tid] = srl[mt*64 + tid];
    __syncthreads();
    for (int o = tid; o < 64*40; o += 256) {
        int r = o / 40, a = o - 40*(o/40);
        float acc2 = ssr[r] * sbp[a];
        #pragma unroll
        for (int f = 0; f < 21; ++f) acc2 += sLp[r][f] * sWp[f*40 + a];
        agx[(size_t)(mt*64 + r)*1280 + b*40 + a] = f2bf(acc2);
    }
}

// ---------------- workspace layout (byte offsets, ~166 MB of ~516 MB ws) ----------------
#define O_LHI   0ull             // 2097152
#define O_LF    2097152ull       // 2097152
#define O_LINP  4194304ull       // 66060288 (bf16)
#define O_HLIN  70254592ull      // 8192000
#define O_ULIN  78446592ull      // 8192000
#define O_HTF   86638592ull      // 4194304
#define O_RHF   90832896ull      // 4194304
#define O_AGX0  95027200ull      // 2621440
#define O_AGX1  97648640ull      // 2621440
#define O_W1H   100270080ull     // 32768
#define O_W2H   100302848ull     // 16384
#define O_WP    100319232ull     // 4096
#define O_BP    100323328ull     // 256
#define O_DINV  100323584ull     // 4096
#define O_SRL   100327680ull     // 4096
#define O_INT   100331776ull     // 66060288 -> end 166392064

extern "C" void kernel_launch(void* const* d_in, const int* in_sizes, int n_in,
                              void* d_out, int out_size, void* d_ws, size_t ws_size,
                              hipStream_t stream) {
    const float* inputs = (const float*)d_in[0];
    const float* adj    = (const float*)d_in[1];
    const float* Wo = (const float*)d_in[2];  const float* bo = (const float*)d_in[3];
    const float* Wd = (const float*)d_in[4];  const float* bd = (const float*)d_in[5];
    const float* We = (const float*)d_in[6];  const float* be = (const float*)d_in[7];
    const float* Wi = (const float*)d_in[8];  const float* bi = (const float*)d_in[9];
    const float* W1 = (const float*)d_in[10]; const float* b1 = (const float*)d_in[11];
    const float* W2 = (const float*)d_in[12]; const float* b2 = (const float*)d_in[13];
    float* out = (float*)d_out;

    char* ws = (char*)d_ws;
    u16*   Lhi   = (u16*)(ws + O_LHI);
    u16*   Lf    = (u16*)(ws + O_LF);
    u16*   LinpB = (u16*)(ws + O_LINP);
    float* h_lin = (float*)(ws + O_HLIN);
    float* u_lin = (float*)(ws + O_ULIN);
    u16*   hTf   = (u16*)(ws + O_HTF);
    u16*   rhf   = (u16*)(ws + O_RHF);
    u16*   agx0  = (u16*)(ws + O_AGX0);
    u16*   agx1  = (u16*)(ws + O_AGX1);
    u16*   W1h   = (u16*)(ws + O_W1H);
    u16*   W2h   = (u16*)(ws + O_W2H);
    float* Wp    = (float*)(ws + O_WP);
    float* bp    = (float*)(ws + O_BP);
    float* dinv  = (float*)(ws + O_DINV);
    float* srl   = (float*)(ws + O_SRL);
    u16*   inT   = (u16*)(ws + O_INT);

    k_rowsum<<<NN, 256, 0, stream>>>(adj, dinv);
    k_buildL<<<(KP*KP)/256, 256, 0, stream>>>(adj, dinv, Lhi);
    k_buildLf<<<(KP*KP)/256, 256, 0, stream>>>(adj, dinv, Lf);
    k_srow<<<KP, 256, 0, stream>>>(adj, dinv, srl);
    k_wconv<<<96, 256, 0, stream>>>(W1, W2, W1h, W2h);
    k_packW<<<1, 256, 0, stream>>>(Wo, bo, Wd, bd, We, be, Wi, bi, Wp, bp);
    k_transpose<<<dim3(BATCH*SEQ, 8), 256, 0, stream>>>(inputs, inT);
    k_gemm<<<dim3(LCOLS/64, 8), 512, 0, stream>>>(Lhi, inT, LinpB, LCOLS);

    hipMemsetAsync(ws + O_HLIN, 0, 8192000ull, stream);   // h0 = 0
    hipMemsetAsync(ws + O_HTF,  0, 4194304ull, stream);   // hT frags = 0
    hipMemsetAsync(ws + O_RHF,  0, 4194304ull, stream);   // rh pad frags = 0
    k_xproj2<<<dim3(32,16), 256, 0, stream>>>(LinpB, Wp, bp, srl, agx0, 0);

    for (int t = 0; t < SEQ; ++t) {
        u16* agxc = (t & 1) ? agx1 : agx0;
        u16* agxn = (t & 1) ? agx0 : agx1;
        k_g1<<<dim3(32,16), 256, 0, stream>>>(Lf, hTf, agxc, W1h, b1, h_lin, rhf, u_lin);
        k_g2<<<dim3(32,16), 256, 0, stream>>>(Lf, rhf, agxc, W2h, b2, u_lin, h_lin, hTf,
                                              LinpB, Wp, bp, srl, agxn, t + 1,
                                              out, t == SEQ - 1);
    }
}

// Round 9
// 2679.932 us; speedup vs baseline: 2.2752x; 1.0036x over previous
//
#include <hip/hip_runtime.h>
#include <hip/hip_cooperative_groups.h>
#include <math.h>

namespace cg = cooperative_groups;

#define NN    1000
#define KP    1024
#define BATCH 32
#define SEQ   48
#define HID   64
#define LCOLS 32256                 // 48*32*21 premultiplied input cols

typedef unsigned short u16;
typedef __attribute__((ext_vector_type(8))) short  short8v;
typedef __attribute__((ext_vector_type(8))) unsigned short ushort8v;
typedef __attribute__((ext_vector_type(4))) float  float4v;

__device__ __forceinline__ u16 f2bf(float x) {
    union { float f; unsigned u; } v; v.f = x;
    unsigned r = v.u + 0x7FFF + ((v.u >> 16) & 1);
    return (u16)(r >> 16);
}
__device__ __forceinline__ float bf2f(u16 h) {
    union { unsigned u; float f; } v; v.u = ((unsigned)h) << 16;
    return v.f;
}

// ---------------- Laplacian ----------------
__global__ void k_rowsum(const float* __restrict__ adj, float* __restrict__ dinv) {
    int m = blockIdx.x;
    float s = 0.f;
    for (int n = threadIdx.x; n < NN; n += blockDim.x)
        s += adj[(size_t)m*NN + n];
    __shared__ float red[256];
    red[threadIdx.x] = s; __syncthreads();
    for (int st = 128; st > 0; st >>= 1) {
        if (threadIdx.x < st) red[threadIdx.x] += red[threadIdx.x + st];
        __syncthreads();
    }
    if (threadIdx.x == 0) dinv[m] = rsqrtf(red[0] + 1.0f);
}

__global__ void k_buildL(const float* __restrict__ adj, const float* __restrict__ dinv,
                         u16* __restrict__ Lhi) {
    int idx = blockIdx.x * 256 + threadIdx.x;
    if (idx >= KP*KP) return;
    int m = idx >> 10, k = idx & (KP-1);
    float v = 0.f;
    if (m < NN && k < NN)
        v = dinv[m] * (adj[(size_t)m*NN + k] + (m == k ? 1.f : 0.f)) * dinv[k];
    Lhi[idx] = f2bf(v);
}

// fragment-order L
__global__ void k_buildLf(const float* __restrict__ adj, const float* __restrict__ dinv,
                          u16* __restrict__ Lf) {
    size_t idx = (size_t)blockIdx.x * 256 + threadIdx.x;
    if (idx >= (size_t)KP*KP) return;
    int e    = idx & 7;
    int lane = (idx >> 3) & 63;
    int kb   = (idx >> 9) & 31;
    int mg   = idx >> 14;
    int m = mg*16 + (lane & 15);
    int k = kb*32 + (lane >> 4)*8 + e;
    float v = 0.f;
    if (m < NN && k < NN)
        v = dinv[m] * (adj[(size_t)m*NN + k] + (m == k ? 1.f : 0.f)) * dinv[k];
    Lf[idx] = f2bf(v);
}

__global__ void k_srow(const float* __restrict__ adj, const float* __restrict__ dinv,
                       float* __restrict__ srl) {
    int m = blockIdx.x;
    __shared__ float red[256];
    float s = 0.f;
    if (m < NN)
        for (int n = threadIdx.x; n < NN; n += blockDim.x)
            s += adj[(size_t)m*NN + n] * dinv[n];
    red[threadIdx.x] = s; __syncthreads();
    for (int st = 128; st > 0; st >>= 1) {
        if (threadIdx.x < st) red[threadIdx.x] += red[threadIdx.x + st];
        __syncthreads();
    }
    if (threadIdx.x == 0) srl[m] = (m < NN) ? dinv[m] * (red[0] + dinv[m]) : 0.f;
}

// ---------------- W conversion ----------------
__global__ void k_wconv(const float* __restrict__ W1, const float* __restrict__ W2,
                        u16* __restrict__ W1h, u16* __restrict__ W2h) {
    int idx = blockIdx.x * 256 + threadIdx.x;
    if (idx < 128*128) {
        int k = idx >> 7, f = idx & 127;
        W1h[idx] = f2bf((f < 104) ? W1[f*128 + k] : 0.f);
    } else if (idx < 128*128 + 64*128) {
        int i2 = idx - 128*128;
        int c = i2 >> 7, f = i2 & 127;
        W2h[i2] = f2bf((f < 104) ? W2[f*64 + c] : 0.f);
    }
}

// ---------------- pack aspect projections ----------------
__global__ void k_packW(const float* __restrict__ Wo, const float* __restrict__ bo,
                        const float* __restrict__ Wd, const float* __restrict__ bd,
                        const float* __restrict__ We, const float* __restrict__ be,
                        const float* __restrict__ Wi, const float* __restrict__ bi,
                        float* __restrict__ Wp, float* __restrict__ bp) {
    for (int o = threadIdx.x; o < 21*40; o += 256) {
        int f = o / 40, a = o - f*40;
        int g = a / 10, aa = a - 10*g;
        float v = 0.f;
        if (g == 0) {
            if (f == 2) v = Wo[0*10+aa]; else if (f == 5) v = Wo[1*10+aa];
            else if (f == 8) v = Wo[2*10+aa]; else if (f == 9) v = Wo[3*10+aa];
            else if (f == 12) v = Wo[4*10+aa];
        } else if (g == 1) {
            if (f == 10) v = Wd[aa]; else if (f == 14) v = Wd[10+aa];
            else if (f == 15) v = Wd[20+aa];
        } else if (g == 2) {
            if (f == 13) v = We[aa]; else if (f == 17) v = We[10+aa];
        } else {
            if (f == 19) v = Wi[aa]; else if (f == 20) v = Wi[10+aa];
        }
        Wp[o] = v;
    }
    if (threadIdx.x < 40) {
        int a = threadIdx.x, g = a / 10, aa = a - 10*g;
        bp[a] = (g == 0) ? bo[aa] : (g == 1) ? bd[aa] : (g == 2) ? be[aa] : bi[aa];
    }
}

// ---------------- transpose inputs -> inT[(t*32+b)*21+f][1024] bf16 ----------------
__global__ __launch_bounds__(256)
void k_transpose(const float* __restrict__ inputs, u16* __restrict__ inT) {
    int bt = blockIdx.x;                // b*48 + t
    int b = bt / SEQ, t = bt - b*SEQ;
    int nt = blockIdx.y;
    __shared__ float sm[128][22];
    const float* base = inputs + ((size_t)bt * NN + nt*128) * 21;
    for (int i = threadIdx.x; i < 128*21; i += 256) {
        int nn = i / 21, f = i - nn*21;
        int n = nt*128 + nn;
        sm[nn][f] = (n < NN) ? base[(size_t)nn*21 + f] : 0.f;
    }
    __syncthreads();
    for (int o = threadIdx.x; o < 21*128; o += 256) {
        int f = o >> 7, nn = o & 127;
        inT[(size_t)((t*32 + b)*21 + f)*KP + nt*128 + nn] = f2bf(sm[nn][f]);
    }
}

// ---------------- plain MFMA GEMM (one-shot Linp), bf16 out ----------------
__global__ __launch_bounds__(512)
void k_gemm(const u16* __restrict__ A, const u16* __restrict__ B,
            u16* __restrict__ Cout, int ncols) {
    __shared__ char sA[128*64];
    __shared__ char sB[64*64];
    const int n0 = blockIdx.x * 64;
    const int m0 = blockIdx.y * 128;
    const int tid = threadIdx.x;
    const int w = tid >> 6, lane = tid & 63;
    const int l15 = lane & 15, l4 = lane >> 4;
    const int wm = w >> 1, wn = w & 1;

    float4v acc[2][2];
    #pragma unroll
    for (int i = 0; i < 2; ++i)
        #pragma unroll
        for (int j = 0; j < 2; ++j) acc[i][j] = (float4v){0.f,0.f,0.f,0.f};

    int aoff[2], boff[2];
    #pragma unroll
    for (int mf = 0; mf < 2; ++mf) {
        int r = wm*32 + mf*16 + l15;
        aoff[mf] = (r*64 + l4*16) ^ ((r & 7) << 4);
    }
    #pragma unroll
    for (int nf = 0; nf < 2; ++nf) {
        int r = wn*32 + nf*16 + l15;
        boff[nf] = (r*64 + l4*16) ^ ((r & 7) << 4);
    }
    const int rA = tid >> 2, qA = tid & 3;
    const int dA = (rA*64 + qA*16) ^ ((rA & 7) << 4);
    const size_t gA = (size_t)(m0 + rA)*KP + qA*8;
    const int rB = (tid & 255) >> 2, qB = tid & 3;
    const int dB = (rB*64 + qB*16) ^ ((rB & 7) << 4);
    const size_t gB = (size_t)(n0 + rB)*KP + qB*8;

    for (int kt = 0; kt < 32; ++kt) {
        const int k0 = kt*32;
        __syncthreads();
        *(uint4*)(sA + dA) = *(const uint4*)(A + gA + k0);
        if (tid < 256) *(uint4*)(sB + dB) = *(const uint4*)(B + gB + k0);
        __syncthreads();
        short8v a0 = *(const short8v*)(sA + aoff[0]);
        short8v a1 = *(const short8v*)(sA + aoff[1]);
        short8v b0 = *(const short8v*)(sB + boff[0]);
        short8v b1 = *(const short8v*)(sB + boff[1]);
        acc[0][0] = __builtin_amdgcn_mfma_f32_16x16x32_bf16(a0, b0, acc[0][0], 0, 0, 0);
        acc[0][1] = __builtin_amdgcn_mfma_f32_16x16x32_bf16(a0, b1, acc[0][1], 0, 0, 0);
        acc[1][0] = __builtin_amdgcn_mfma_f32_16x16x32_bf16(a1, b0, acc[1][0], 0, 0, 0);
        acc[1][1] = __builtin_amdgcn_mfma_f32_16x16x32_bf16(a1, b1, acc[1][1], 0, 0, 0);
    }
    #pragma unroll
    for (int mf = 0; mf < 2; ++mf)
        #pragma unroll
        for (int nf = 0; nf < 2; ++nf)
            #pragma unroll
            for (int i = 0; i < 4; ++i) {
                int m = m0 + wm*32 + mf*16 + l4*4 + i;
                int j = n0 + wn*32 + nf*16 + l15;
                Cout[(size_t)m*ncols + j] = f2bf(acc[mf][nf][i]);
            }
}

// frag helper: offset (in u16) of fragment (grp, kb) for this lane
__device__ __forceinline__ size_t frag_off(int grp, int kb, int lane) {
    return (((size_t)grp*32 + kb)*64 + lane)*8;
}

// =================================================================
// Persistent cooperative kernel. WPB = logical workgroups per block.
// Logical wg W = s*(512/WPB) + bid ; b = W>>4 ; mt = W&15 (mt equal
// across s because (512/WPB) % 16 == 0 for WPB in {1,2}).
// =================================================================
template<int WPB>
__global__ __launch_bounds__(256)
void k_loop(const u16* __restrict__ Lf, u16* __restrict__ hTf, u16* __restrict__ rhf,
            u16* __restrict__ agx0, u16* __restrict__ agx1,
            const u16* __restrict__ W1h, const u16* __restrict__ W2h,
            const float* __restrict__ b1, const float* __restrict__ b2,
            float* __restrict__ h_lin, float* __restrict__ u_lin,
            const u16* __restrict__ LinpB, const float* __restrict__ Wp,
            const float* __restrict__ bp, const float* __restrict__ srl,
            float* __restrict__ out) {
    cg::grid_group grid = cg::this_grid();
    const int bid = blockIdx.x;
    const int NBLK = 512 / WPB;
    const int mt = bid & 15;
    const int m0 = mt*64;
    const int tid = threadIdx.x;
    const int w = tid >> 6, lane = tid & 63, l15 = lane & 15, l4 = lane >> 4;
    const int wm = w >> 1, wn = w & 1;
    const int c = tid & 63, ng = tid >> 6;

    __shared__ char smem[49408];
    __shared__ float sWp2[21*40];
    __shared__ float sbp2[40];
    __shared__ float ssr2[64];

    for (int i = tid; i < 21*40; i += 256) sWp2[i] = Wp[i];
    if (tid < 40) sbp2[tid] = bp[tid];
    if (tid < 64) ssr2[tid] = srl[m0 + tid];

    const u16* LA0 = Lf + frag_off(mt*4 + wm*2 + 0, 0, lane);
    const u16* LA1 = Lf + frag_off(mt*4 + wm*2 + 1, 0, lane);
    __syncthreads();

    #pragma unroll 1
    for (int t = 0; t < SEQ; ++t) {
        const u16* agxc = (t & 1) ? agx1 : agx0;
        u16*       agxn = (t & 1) ? agx0 : agx1;

        // ================= phase 1 (gate) =================
        #pragma unroll 1
        for (int s = 0; s < WPB; ++s) {
            const int b = (s*NBLK + bid) >> 4;
            __syncthreads();
            char* sF = smem;                        // 16384
            float* ru_s = (float*)(smem + 16384);   // 33024

            float4v acc[2][2];
            #pragma unroll
            for (int i = 0; i < 2; ++i)
                #pragma unroll
                for (int j = 0; j < 2; ++j) acc[i][j] = (float4v){0.f,0.f,0.f,0.f};

            const u16* B0 = hTf + frag_off(b*4 + wn*2 + 0, 0, lane);
            const u16* B1 = hTf + frag_off(b*4 + wn*2 + 1, 0, lane);
            #pragma unroll 8
            for (int kb = 0; kb < 32; ++kb) {
                short8v a0 = *(const short8v*)(LA0 + kb*512);
                short8v a1 = *(const short8v*)(LA1 + kb*512);
                short8v b0 = *(const short8v*)(B0 + kb*512);
                short8v b1 = *(const short8v*)(B1 + kb*512);
                acc[0][0] = __builtin_amdgcn_mfma_f32_16x16x32_bf16(a0, b0, acc[0][0], 0, 0, 0);
                acc[0][1] = __builtin_amdgcn_mfma_f32_16x16x32_bf16(a0, b1, acc[0][1], 0, 0, 0);
                acc[1][0] = __builtin_amdgcn_mfma_f32_16x16x32_bf16(a1, b0, acc[1][0], 0, 0, 0);
                acc[1][1] = __builtin_amdgcn_mfma_f32_16x16x32_bf16(a1, b1, acc[1][1], 0, 0, 0);
            }

            if (tid < 192) {   // zero pad f 104..127
                int r = tid / 3, q = tid - 3*(tid/3);
                *(uint4*)(sF + ((r*256 + (13 + q)*16) ^ ((r & 7) << 4))) = (uint4){0,0,0,0};
            }
            for (int i = tid; i < 320; i += 256) {  // agx cols 0..39
                int r = i / 5, q = i - 5*(i/5);
                *(uint4*)(sF + ((r*256 + q*16) ^ ((r & 7) << 4))) =
                    *(const uint4*)(agxc + (size_t)(m0 + r)*1280 + b*40 + q*8);
            }
            #pragma unroll
            for (int mf = 0; mf < 2; ++mf)
                #pragma unroll
                for (int nf = 0; nf < 2; ++nf)
                    #pragma unroll
                    for (int i = 0; i < 4; ++i) {
                        int row = wm*32 + mf*16 + l4*4 + i;
                        int f = 40 + wn*32 + nf*16 + l15;
                        *(u16*)(sF + ((row*256 + f*2) ^ ((row & 7) << 4))) = f2bf(acc[mf][nf][i]);
                    }
            __syncthreads();

            const int gm = wm*32, gn = wn*64;
            float4v acc2[2][4];
            #pragma unroll
            for (int i = 0; i < 2; ++i)
                #pragma unroll
                for (int j = 0; j < 4; ++j) acc2[i][j] = (float4v){0.f,0.f,0.f,0.f};
            for (int kt2 = 0; kt2 < 4; ++kt2) {
                #pragma unroll
                for (int mf = 0; mf < 2; ++mf) {
                    int ar2 = gm + mf*16 + l15;
                    short8v a = *(const short8v*)(sF + ((ar2*256 + kt2*64 + l4*16) ^ ((ar2 & 7) << 4)));
                    #pragma unroll
                    for (int nf = 0; nf < 4; ++nf) {
                        short8v bb = *(const short8v*)(W1h + (gn + nf*16 + l15)*128 + kt2*32 + l4*8);
                        acc2[mf][nf] = __builtin_amdgcn_mfma_f32_16x16x32_bf16(a, bb, acc2[mf][nf], 0, 0, 0);
                    }
                }
            }
            #pragma unroll
            for (int mf = 0; mf < 2; ++mf)
                #pragma unroll
                for (int nf = 0; nf < 4; ++nf) {
                    int col = gn + nf*16 + l15;
                    float bias = b1[col];
                    #pragma unroll
                    for (int i = 0; i < 4; ++i) {
                        int row = gm + mf*16 + l4*4 + i;
                        ru_s[row*129 + col] = 1.f / (1.f + __expf(-(acc2[mf][nf][i] + bias)));
                    }
                }
            __syncthreads();

            #pragma unroll
            for (int it = 0; it < 4; ++it) {
                int nc = (it*4 + ng)*8;
                int n = 2*m0 + nc;
                if ((n >> 1) + 3 < 500) {
                    ushort8v ov;
                    #pragma unroll
                    for (int d = 0; d < 8; ++d) {
                        int nn = n + d;
                        float r = ru_s[((nc + d) >> 1)*129 + (nn & 1)*64 + c];
                        float h = h_lin[((size_t)b*NN + nn)*64 + c];
                        ov[d] = f2bf(r*h);
                    }
                    *(ushort8v*)(rhf + frag_off(b*4 + (c >> 4), n >> 5, (c & 15) + 16*((n >> 3) & 3))) = ov;
                }
            }
            for (int lc = 0; lc < 16; lc += 4) {
                int lr = ng*16 + lc;
                int m = m0 + lr;
                if (m >= 500) {
                    #pragma unroll
                    for (int d = 0; d < 4; ++d) {
                        int mm = m + d;
                        if (mm < 1000) {
                            int n = 2*(mm - 500);
                            u_lin[((size_t)b*NN + n)*64 + c]     = ru_s[(lr+d)*129 + c];
                            u_lin[((size_t)b*NN + n + 1)*64 + c] = ru_s[(lr+d)*129 + 64 + c];
                        }
                    }
                }
            }
        }
        grid.sync();

        // ================= phase 2 (candidate + update) =================
        #pragma unroll 1
        for (int s = 0; s < WPB; ++s) {
            const int b = (s*NBLK + bid) >> 4;
            __syncthreads();
            char* sF = smem;                      // 16384
            float* cs  = (float*)(smem + 16384);  // 16640
            float* sLp = (float*)(smem + 33024);  // 5632

            float4v acc[2][2];
            #pragma unroll
            for (int i = 0; i < 2; ++i)
                #pragma unroll
                for (int j = 0; j < 2; ++j) acc[i][j] = (float4v){0.f,0.f,0.f,0.f};

            const u16* B0 = rhf + frag_off(b*4 + wn*2 + 0, 0, lane);
            const u16* B1 = rhf + frag_off(b*4 + wn*2 + 1, 0, lane);
            #pragma unroll 8
            for (int kb = 0; kb < 32; ++kb) {
                short8v a0 = *(const short8v*)(LA0 + kb*512);
                short8v a1 = *(const short8v*)(LA1 + kb*512);
                short8v b0 = *(const short8v*)(B0 + kb*512);
                short8v b1 = *(const short8v*)(B1 + kb*512);
                acc[0][0] = __builtin_amdgcn_mfma_f32_16x16x32_bf16(a0, b0, acc[0][0], 0, 0, 0);
                acc[0][1] = __builtin_amdgcn_mfma_f32_16x16x32_bf16(a0, b1, acc[0][1], 0, 0, 0);
                acc[1][0] = __builtin_amdgcn_mfma_f32_16x16x32_bf16(a1, b0, acc[1][0], 0, 0, 0);
                acc[1][1] = __builtin_amdgcn_mfma_f32_16x16x32_bf16(a1, b1, acc[1][1], 0, 0, 0);
            }

            if (tid < 192) {
                int r = tid / 3, q = tid - 3*(tid/3);
                *(uint4*)(sF + ((r*256 + (13 + q)*16) ^ ((r & 7) << 4))) = (uint4){0,0,0,0};
            }
            for (int i = tid; i < 320; i += 256) {
                int r = i / 5, q = i - 5*(i/5);
                *(uint4*)(sF + ((r*256 + q*16) ^ ((r & 7) << 4))) =
                    *(const uint4*)(agxc + (size_t)(m0 + r)*1280 + b*40 + q*8);
            }
            #pragma unroll
            for (int mf = 0; mf < 2; ++mf)
                #pragma unroll
                for (int nf = 0; nf < 2; ++nf)
                    #pragma unroll
                    for (int i = 0; i < 4; ++i) {
                        int row = wm*32 + mf*16 + l4*4 + i;
                        int f = 40 + wn*32 + nf*16 + l15;
                        *(u16*)(sF + ((row*256 + f*2) ^ ((row & 7) << 4))) = f2bf(acc[mf][nf][i]);
                    }
            __syncthreads();

            const int gm = wm*32, gn = wn*32;
            float4v acc3[2][2];
            #pragma unroll
            for (int i = 0; i < 2; ++i)
                #pragma unroll
                for (int j = 0; j < 2; ++j) acc3[i][j] = (float4v){0.f,0.f,0.f,0.f};
            for (int kt2 = 0; kt2 < 4; ++kt2) {
                #pragma unroll
                for (int mf = 0; mf < 2; ++mf) {
                    int ar2 = gm + mf*16 + l15;
                    short8v a = *(const short8v*)(sF + ((ar2*256 + kt2*64 + l4*16) ^ ((ar2 & 7) << 4)));
                    #pragma unroll
                    for (int nf = 0; nf < 2; ++nf) {
                        short8v bb = *(const short8v*)(W2h + (gn + nf*16 + l15)*128 + kt2*32 + l4*8);
                        acc3[mf][nf] = __builtin_amdgcn_mfma_f32_16x16x32_bf16(a, bb, acc3[mf][nf], 0, 0, 0);
                    }
                }
            }
            #pragma unroll
            for (int mf = 0; mf < 2; ++mf)
                #pragma unroll
                for (int nf = 0; nf < 2; ++nf) {
                    int col = gn + nf*16 + l15;
                    float bias = b2[col];
                    #pragma unroll
                    for (int i = 0; i < 4; ++i) {
                        int row = gm + mf*16 + l4*4 + i;
                        cs[row*65 + col] = acc3[mf][nf][i] + bias;
                    }
                }
            __syncthreads();

            const int write_out = (t == SEQ - 1);
            for (int lc = 0; lc < 16; lc += 8) {
                int lr = ng*16 + lc;
                int m = m0 + lr;
                ushort8v hiv;
                #pragma unroll
                for (int d = 0; d < 8; ++d) {
                    int mm = m + d;
                    float hn = 0.f;
                    if (mm < NN) {
                        float x = cs[(lr+d)*65 + c];
                        x = fminf(fmaxf(x, -15.f), 15.f);
                        float e = __expf(2.f*x);
                        float cand = (e - 1.f) / (e + 1.f);
                        size_t idx = ((size_t)b*NN + mm)*64 + c;
                        float u = u_lin[idx], h = h_lin[idx];
                        hn = u*h + (1.f - u)*cand;
                        h_lin[idx] = hn;
                        if (write_out) out[idx] = hn;
                    }
                    hiv[d] = f2bf(hn);
                }
                *(ushort8v*)(hTf + frag_off(b*4 + (c >> 4), m >> 5, (c & 15) + 16*((m >> 3) & 3))) = hiv;
            }

            if (t + 1 < SEQ) {
                for (int i = tid; i < 64*21; i += 256) {
                    int r = i / 21, f = i - 21*(i/21);
                    sLp[r*22 + f] = bf2f(LinpB[(size_t)(m0 + r)*LCOLS + (t+1)*672 + b*21 + f]);
                }
                __syncthreads();
                for (int o = tid; o < 64*40; o += 256) {
                    int r = o / 40, a = o - 40*(o/40);
                    float acc4 = ssr2[r] * sbp2[a];
                    #pragma unroll
                    for (int f = 0; f < 21; ++f) acc4 += sLp[r*22 + f] * sWp2[f*40 + a];
                    agxn[(size_t)(m0 + r)*1280 + b*40 + a] = f2bf(acc4);
                }
            }
        }
        grid.sync();
    }
}

// ---------------- fallback per-step kernels (proven round-7 path) ----------------
__global__ __launch_bounds__(256)
void k_g1(const u16* __restrict__ Lf, const u16* __restrict__ hTf,
          const u16* __restrict__ agx, const u16* __restrict__ W1h,
          const float* __restrict__ b1, const float* __restrict__ h_lin,
          u16* __restrict__ rhf, float* __restrict__ u_lin) {
    const int b = blockIdx.x, mt = blockIdx.y;
    const int m0 = mt*64;
    const int tid = threadIdx.x;
    const int w = tid >> 6, lane = tid & 63, l15 = lane & 15, l4 = lane >> 4;
    const int wm = w >> 1, wn = w & 1;

    __shared__ char smem[49408];
    char* sF = smem;
    float* ru_s = (float*)(smem + 16384);

    float4v acc[2][2];
    #pragma unroll
    for (int i = 0; i < 2; ++i)
        #pragma unroll
        for (int j = 0; j < 2; ++j) acc[i][j] = (float4v){0.f,0.f,0.f,0.f};

    const u16* A0 = Lf  + frag_off(mt*4 + wm*2 + 0, 0, lane);
    const u16* A1 = Lf  + frag_off(mt*4 + wm*2 + 1, 0, lane);
    const u16* B0 = hTf + frag_off(b*4  + wn*2 + 0, 0, lane);
    const u16* B1 = hTf + frag_off(b*4  + wn*2 + 1, 0, lane);
    #pragma unroll 8
    for (int kb = 0; kb < 32; ++kb) {
        short8v a0 = *(const short8v*)(A0 + kb*512);
        short8v a1 = *(const short8v*)(A1 + kb*512);
        short8v b0 = *(const short8v*)(B0 + kb*512);
        short8v b1 = *(const short8v*)(B1 + kb*512);
        acc[0][0] = __builtin_amdgcn_mfma_f32_16x16x32_bf16(a0, b0, acc[0][0], 0, 0, 0);
        acc[0][1] = __builtin_amdgcn_mfma_f32_16x16x32_bf16(a0, b1, acc[0][1], 0, 0, 0);
        acc[1][0] = __builtin_amdgcn_mfma_f32_16x16x32_bf16(a1, b0, acc[1][0], 0, 0, 0);
        acc[1][1] = __builtin_amdgcn_mfma_f32_16x16x32_bf16(a1, b1, acc[1][1], 0, 0, 0);
    }

    if (tid < 192) {
        int r = tid / 3, q = tid - 3*(tid/3);
        *(uint4*)(sF + ((r*256 + (13 + q)*16) ^ ((r & 7) << 4))) = (uint4){0,0,0,0};
    }
    for (int i = tid; i < 320; i += 256) {
        int r = i / 5, q = i - 5*(i/5);
        *(uint4*)(sF + ((r*256 + q*16) ^ ((r & 7) << 4))) =
            *(const uint4*)(agx + (size_t)(m0 + r)*1280 + b*40 + q*8);
    }
    #pragma unroll
    for (int mf = 0; mf < 2; ++mf)
        #pragma unroll
        for (int nf = 0; nf < 2; ++nf)
            #pragma unroll
            for (int i = 0; i < 4; ++i) {
                int row = wm*32 + mf*16 + l4*4 + i;
                int f = 40 + wn*32 + nf*16 + l15;
                *(u16*)(sF + ((row*256 + f*2) ^ ((row & 7) << 4))) = f2bf(acc[mf][nf][i]);
            }
    __syncthreads();

    const int gm = wm*32, gn = wn*64;
    float4v acc2[2][4];
    #pragma unroll
    for (int i = 0; i < 2; ++i)
        #pragma unroll
        for (int j = 0; j < 4; ++j) acc2[i][j] = (float4v){0.f,0.f,0.f,0.f};
    for (int kt2 = 0; kt2 < 4; ++kt2) {
        #pragma unroll
        for (int mf = 0; mf < 2; ++mf) {
            int ar2 = gm + mf*16 + l15;
            short8v a = *(const short8v*)(sF + ((ar2*256 + kt2*64 + l4*16) ^ ((ar2 & 7) << 4)));
            #pragma unroll
            for (int nf = 0; nf < 4; ++nf) {
                short8v bb = *(const short8v*)(W1h + (gn + nf*16 + l15)*128 + kt2*32 + l4*8);
                acc2[mf][nf] = __builtin_amdgcn_mfma_f32_16x16x32_bf16(a, bb, acc2[mf][nf], 0, 0, 0);
            }
        }
    }
    #pragma unroll
    for (int mf = 0; mf < 2; ++mf)
        #pragma unroll
        for (int nf = 0; nf < 4; ++nf) {
            int col = gn + nf*16 + l15;
            float bias = b1[col];
            #pragma unroll
            for (int i = 0; i < 4; ++i) {
                int row = gm + mf*16 + l4*4 + i;
                ru_s[row*129 + col] = 1.f / (1.f + __expf(-(acc2[mf][nf][i] + bias)));
            }
        }
    __syncthreads();

    const int c = tid & 63, ng = tid >> 6;
    #pragma unroll
    for (int it = 0; it < 4; ++it) {
        int nc = (it*4 + ng)*8;
        int n = 2*m0 + nc;
        if ((n >> 1) + 3 < 500) {
            ushort8v ov;
            #pragma unroll
            for (int d = 0; d < 8; ++d) {
                int nn = n + d;
                float r = ru_s[((nc + d) >> 1)*129 + (nn & 1)*64 + c];
                float h = h_lin[((size_t)b*NN + nn)*64 + c];
                ov[d] = f2bf(r*h);
            }
            *(ushort8v*)(rhf + frag_off(b*4 + (c >> 4), n >> 5, (c & 15) + 16*((n >> 3) & 3))) = ov;
        }
    }
    for (int lc = 0; lc < 16; lc += 4) {
        int lr = ng*16 + lc;
        int m = m0 + lr;
        if (m >= 500) {
            #pragma unroll
            for (int d = 0; d < 4; ++d) {
                int mm = m + d;
                if (mm < 1000) {
                    int n = 2*(mm - 500);
                    u_lin[((size_t)b*NN + n)*64 + c]     = ru_s[(lr+d)*129 + c];
                    u_lin[((size_t)b*NN + n + 1)*64 + c] = ru_s[(lr+d)*129 + 64 + c];
                }
            }
        }
    }
}

__global__ __launch_bounds__(256)
void k_g2(const u16* __restrict__ Lf, const u16* __restrict__ rhf,
          const u16* __restrict__ agx, const u16* __restrict__ W2h,
          const float* __restrict__ b2, const float* __restrict__ u_lin,
          float* __restrict__ h_lin, u16* __restrict__ hTf,
          const u16* __restrict__ LinpB, const float* __restrict__ Wp,
          const float* __restrict__ bp, const float* __restrict__ srl,
          u16* __restrict__ agx_next, int tnext,
          float* __restrict__ out, int write_out) {
    const int b = blockIdx.x, mt = blockIdx.y;
    const int m0 = mt*64;
    const int tid = threadIdx.x;
    const int w = tid >> 6, lane = tid & 63, l15 = lane & 15, l4 = lane >> 4;
    const int wm = w >> 1, wn = w & 1;

    __shared__ char smem[42016];
    char* sF = smem;
    float* cs  = (float*)(smem + 16384);
    float* sLp = (float*)(smem + 33024);
    float* sWp = (float*)(smem + 38656);
    __shared__ float sbp[40];
    __shared__ float ssr[64];

    float4v acc[2][2];
    #pragma unroll
    for (int i = 0; i < 2; ++i)
        #pragma unroll
        for (int j = 0; j < 2; ++j) acc[i][j] = (float4v){0.f,0.f,0.f,0.f};

    const u16* A0 = Lf  + frag_off(mt*4 + wm*2 + 0, 0, lane);
    const u16* A1 = Lf  + frag_off(mt*4 + wm*2 + 1, 0, lane);
    const u16* B0 = rhf + frag_off(b*4  + wn*2 + 0, 0, lane);
    const u16* B1 = rhf + frag_off(b*4  + wn*2 + 1, 0, lane);
    #pragma unroll 8
    for (int kb = 0; kb < 32; ++kb) {
        short8v a0 = *(const short8v*)(A0 + kb*512);
        short8v a1 = *(const short8v*)(A1 + kb*512);
        short8v b0 = *(const short8v*)(B0 + kb*512);
        short8v b1 = *(const short8v*)(B1 + kb*512);
        acc[0][0] = __builtin_amdgcn_mfma_f32_16x16x32_bf16(a0, b0, acc[0][0], 0, 0, 0);
        acc[0][1] = __builtin_amdgcn_mfma_f32_16x16x32_bf16(a0, b1, acc[0][1], 0, 0, 0);
        acc[1][0] = __builtin_amdgcn_mfma_f32_16x16x32_bf16(a1, b0, acc[1][0], 0, 0, 0);
        acc[1][1] = __builtin_amdgcn_mfma_f32_16x16x32_bf16(a1, b1, acc[1][1], 0, 0, 0);
    }

    if (tid < 192) {
        int r = tid / 3, q = tid - 3*(tid/3);
        *(uint4*)(sF + ((r*256 + (13 + q)*16) ^ ((r & 7) << 4))) = (uint4){0,0,0,0};
    }
    for (int i = tid; i < 320; i += 256) {
        int r = i / 5, q = i - 5*(i/5);
        *(uint4*)(sF + ((r*256 + q*16) ^ ((r & 7) << 4))) =
            *(const uint4*)(agx + (size_t)(m0 + r)*1280 + b*40 + q*8);
    }
    #pragma unroll
    for (int mf = 0; mf < 2; ++mf)
        #pragma unroll
        for (int nf = 0; nf < 2; ++nf)
            #pragma unroll
            for (int i = 0; i < 4; ++i) {
                int row = wm*32 + mf*16 + l4*4 + i;
                int f = 40 + wn*32 + nf*16 + l15;
                *(u16*)(sF + ((row*256 + f*2) ^ ((row & 7) << 4))) = f2bf(acc[mf][nf][i]);
            }
    __syncthreads();

    const int gm = wm*32, gn = wn*32;
    float4v acc3[2][2];
    #pragma unroll
    for (int i = 0; i < 2; ++i)
        #pragma unroll
        for (int j = 0; j < 2; ++j) acc3[i][j] = (float4v){0.f,0.f,0.f,0.f};
    for (int kt2 = 0; kt2 < 4; ++kt2) {
        #pragma unroll
        for (int mf = 0; mf < 2; ++mf) {
            int ar2 = gm + mf*16 + l15;
            short8v a = *(const short8v*)(sF + ((ar2*256 + kt2*64 + l4*16) ^ ((ar2 & 7) << 4)));
            #pragma unroll
            for (int nf = 0; nf < 2; ++nf) {
                short8v bb = *(const short8v*)(W2h + (gn + nf*16 + l15)*128 + kt2*32 + l4*8);
                acc3[mf][nf] = __builtin_amdgcn_mfma_f32_16x16x32_bf16(a, bb, acc3[mf][nf], 0, 0, 0);
            }
        }
    }
    #pragma unroll
    for (int mf = 0; mf < 2; ++mf)
        #pragma unroll
        for (int nf = 0; nf < 2; ++nf) {
            int col = gn + nf*16 + l15;
            float bias = b2[col];
            #pragma unroll
            for (int i = 0; i < 4; ++i) {
                int row = gm + mf*16 + l4*4 + i;
                cs[row*65 + col] = acc3[mf][nf][i] + bias;
            }
        }
    __syncthreads();

    const int c = tid & 63, ng = tid >> 6;
    for (int lc = 0; lc < 16; lc += 8) {
        int lr = ng*16 + lc;
        int m = m0 + lr;
        ushort8v hiv;
        #pragma unroll
        for (int d = 0; d < 8; ++d) {
            int mm = m + d;
            float hn = 0.f;
            if (mm < NN) {
                float x = cs[(lr+d)*65 + c];
                x = fminf(fmaxf(x, -15.f), 15.f);
                float e = __expf(2.f*x);
                float cand = (e - 1.f) / (e + 1.f);
                size_t idx = ((size_t)b*NN + mm)*64 + c;
                float u = u_lin[idx], h = h_lin[idx];
                hn = u*h + (1.f - u)*cand;
                h_lin[idx] = hn;
                if (write_out) out[idx] = hn;
            }
            hiv[d] = f2bf(hn);
        }
        *(ushort8v*)(hTf + frag_off(b*4 + (c >> 4), m >> 5, (c & 15) + 16*((m >> 3) & 3))) = hiv;
    }

    if (tnext < SEQ) {
        for (int i = tid; i < 64*21; i += 256) {
            int r = i / 21, f = i - 21*(i/21);
            sLp[r*22 + f] = bf2f(LinpB[(size_t)(m0 + r)*LCOLS + tnext*672 + b*21 + f]);
        }
        for (int i = tid; i < 21*40; i += 256) sWp[i] = Wp[i];
        if (tid < 40) sbp[tid] = bp[tid];
        if (tid < 64) ssr[tid] = srl[m0 + tid];
        __syncthreads();
        for (int o = tid; o < 64*40; o += 256) {
            int r = o / 40, a = o - 40*(o/40);
            float acc4 = ssr[r] * sbp[a];
            #pragma unroll
            for (int f = 0; f < 21; ++f) acc4 += sLp[r*22 + f] * sWp[f*40 + a];
            agx_next[(size_t)(m0 + r)*1280 + b*40 + a] = f2bf(acc4);
        }
    }
}

// ---------------- standalone agx producer (t=0) ----------------
__global__ __launch_bounds__(256)
void k_xproj2(const u16* __restrict__ LinpB, const float* __restrict__ Wp,
              const float* __restrict__ bp, const float* __restrict__ srl,
              u16* __restrict__ agx, int t) {
    const int b = blockIdx.x, mt = blockIdx.y;
    const int tid = threadIdx.x;
    __shared__ float sLp[64][22];
    __shared__ float sWp[21*40];
    __shared__ float sbp[40];
    __shared__ float ssr[64];
    for (int i = tid; i < 64*21; i += 256) {
        int r = i / 21, f = i - 21*(i/21);
        sLp[r][f] = bf2f(LinpB[(size_t)(mt*64 + r)*LCOLS + t*672 + b*21 + f]);
    }
    for (int i = tid; i < 21*40; i += 256) sWp[i] = Wp[i];
    if (tid < 40) sbp[tid] = bp[tid];
    if (tid < 64) ssr[tid] = srl[mt*64 + tid];
    __syncthreads();
    for (int o = tid; o < 64*40; o += 256) {
        int r = o / 40, a = o - 40*(o/40);
        float acc2 = ssr[r] * sbp[a];
        #pragma unroll
        for (int f = 0; f < 21; ++f) acc2 += sLp[r][f] * sWp[f*40 + a];
        agx[(size_t)(mt*64 + r)*1280 + b*40 + a] = f2bf(acc2);
    }
}

// ---------------- workspace layout ----------------
#define O_LHI   0ull
#define O_LF    2097152ull
#define O_LINP  4194304ull
#define O_HLIN  70254592ull
#define O_ULIN  78446592ull
#define O_HTF   86638592ull
#define O_RHF   90832896ull
#define O_AGX0  95027200ull
#define O_AGX1  97648640ull
#define O_W1H   100270080ull
#define O_W2H   100302848ull
#define O_WP    100319232ull
#define O_BP    100323328ull
#define O_DINV  100323584ull
#define O_SRL   100327680ull
#define O_INT   100331776ull

extern "C" void kernel_launch(void* const* d_in, const int* in_sizes, int n_in,
                              void* d_out, int out_size, void* d_ws, size_t ws_size,
                              hipStream_t stream) {
    const float* inputs = (const float*)d_in[0];
    const float* adj    = (const float*)d_in[1];
    const float* Wo = (const float*)d_in[2];  const float* bo = (const float*)d_in[3];
    const float* Wd = (const float*)d_in[4];  const float* bd = (const float*)d_in[5];
    const float* We = (const float*)d_in[6];  const float* be = (const float*)d_in[7];
    const float* Wi = (const float*)d_in[8];  const float* bi = (const float*)d_in[9];
    const float* W1 = (const float*)d_in[10]; const float* b1 = (const float*)d_in[11];
    const float* W2 = (const float*)d_in[12]; const float* b2 = (const float*)d_in[13];
    float* out = (float*)d_out;

    char* ws = (char*)d_ws;
    u16*   Lhi   = (u16*)(ws + O_LHI);
    u16*   Lf    = (u16*)(ws + O_LF);
    u16*   LinpB = (u16*)(ws + O_LINP);
    float* h_lin = (float*)(ws + O_HLIN);
    float* u_lin = (float*)(ws + O_ULIN);
    u16*   hTf   = (u16*)(ws + O_HTF);
    u16*   rhf   = (u16*)(ws + O_RHF);
    u16*   agx0  = (u16*)(ws + O_AGX0);
    u16*   agx1  = (u16*)(ws + O_AGX1);
    u16*   W1h   = (u16*)(ws + O_W1H);
    u16*   W2h   = (u16*)(ws + O_W2H);
    float* Wp    = (float*)(ws + O_WP);
    float* bp    = (float*)(ws + O_BP);
    float* dinv  = (float*)(ws + O_DINV);
    float* srl   = (float*)(ws + O_SRL);
    u16*   inT   = (u16*)(ws + O_INT);

    k_rowsum<<<NN, 256, 0, stream>>>(adj, dinv);
    k_buildL<<<(KP*KP)/256, 256, 0, stream>>>(adj, dinv, Lhi);
    k_buildLf<<<(KP*KP)/256, 256, 0, stream>>>(adj, dinv, Lf);
    k_srow<<<KP, 256, 0, stream>>>(adj, dinv, srl);
    k_wconv<<<96, 256, 0, stream>>>(W1, W2, W1h, W2h);
    k_packW<<<1, 256, 0, stream>>>(Wo, bo, Wd, bd, We, be, Wi, bi, Wp, bp);
    k_transpose<<<dim3(BATCH*SEQ, 8), 256, 0, stream>>>(inputs, inT);
    k_gemm<<<dim3(LCOLS/64, 8), 512, 0, stream>>>(Lhi, inT, LinpB, LCOLS);

    hipMemsetAsync(ws + O_HLIN, 0, 8192000ull, stream);   // h0 = 0
    hipMemsetAsync(ws + O_HTF,  0, 4194304ull, stream);   // hT frags = 0
    hipMemsetAsync(ws + O_RHF,  0, 4194304ull, stream);   // rh pad frags = 0
    k_xproj2<<<dim3(32,16), 256, 0, stream>>>(LinpB, Wp, bp, srl, agx0, 0);

    void* args[] = {
        (void*)&Lf, (void*)&hTf, (void*)&rhf, (void*)&agx0, (void*)&agx1,
        (void*)&W1h, (void*)&W2h, (void*)&b1, (void*)&b2,
        (void*)&h_lin, (void*)&u_lin, (void*)&LinpB, (void*)&Wp,
        (void*)&bp, (void*)&srl, (void*)&out
    };

    hipError_t le = hipErrorUnknown;
    int occ1 = 0;
    if (hipOccupancyMaxActiveBlocksPerMultiprocessor(
            &occ1, reinterpret_cast<const void*>(&k_loop<1>), 256, 0) == hipSuccess
        && occ1 >= 2) {
        le = hipLaunchCooperativeKernel(reinterpret_cast<const void*>(&k_loop<1>),
                                        dim3(512), dim3(256), args, 0, stream);
    }
    if (le != hipSuccess) {
        int occ2 = 0;
        if (hipOccupancyMaxActiveBlocksPerMultiprocessor(
                &occ2, reinterpret_cast<const void*>(&k_loop<2>), 256, 0) == hipSuccess
            && occ2 >= 1) {
            le = hipLaunchCooperativeKernel(reinterpret_cast<const void*>(&k_loop<2>),
                                            dim3(256), dim3(256), args, 0, stream);
        }
    }
    if (le != hipSuccess) {
        // proven per-step fallback (round-7 path, identical math)
        for (int t = 0; t < SEQ; ++t) {
            u16* agxc = (t & 1) ? agx1 : agx0;
            u16* agxn = (t & 1) ? agx0 : agx1;
            k_g1<<<dim3(32,16), 256, 0, stream>>>(Lf, hTf, agxc, W1h, b1, h_lin, rhf, u_lin);
            k_g2<<<dim3(32,16), 256, 0, stream>>>(Lf, rhf, agxc, W2h, b2, u_lin, h_lin, hTf,
                                                  LinpB, Wp, bp, srl, agxn, t + 1,
                                                  out, t == SEQ - 1);
        }
    }
}

// Round 10
// 2603.884 us; speedup vs baseline: 2.3416x; 1.0292x over previous
//
#include <hip/hip_runtime.h>
#include <math.h>

#define NN    1000
#define KP    1024
#define BATCH 32
#define SEQ   48
#define HID   64
#define LCOLS 32256                 // 48*32*21 premultiplied input cols

typedef unsigned short u16;
typedef __attribute__((ext_vector_type(8))) short  short8v;
typedef __attribute__((ext_vector_type(8))) unsigned short ushort8v;
typedef __attribute__((ext_vector_type(4))) float  float4v;

__device__ __forceinline__ u16 f2bf(float x) {
    union { float f; unsigned u; } v; v.f = x;
    unsigned r = v.u + 0x7FFF + ((v.u >> 16) & 1);
    return (u16)(r >> 16);
}
__device__ __forceinline__ float bf2f(u16 h) {
    union { unsigned u; float f; } v; v.u = ((unsigned)h) << 16;
    return v.f;
}

// ---------------- Laplacian ----------------
__global__ void k_rowsum(const float* __restrict__ adj, float* __restrict__ dinv) {
    int m = blockIdx.x;
    float s = 0.f;
    for (int n = threadIdx.x; n < NN; n += blockDim.x)
        s += adj[(size_t)m*NN + n];
    __shared__ float red[256];
    red[threadIdx.x] = s; __syncthreads();
    for (int st = 128; st > 0; st >>= 1) {
        if (threadIdx.x < st) red[threadIdx.x] += red[threadIdx.x + st];
        __syncthreads();
    }
    if (threadIdx.x == 0) dinv[m] = rsqrtf(red[0] + 1.0f);
}

// row-major L (for the one-shot Linp GEMM)
__global__ void k_buildL(const float* __restrict__ adj, const float* __restrict__ dinv,
                         u16* __restrict__ Lhi) {
    int idx = blockIdx.x * 256 + threadIdx.x;
    if (idx >= KP*KP) return;
    int m = idx >> 10, k = idx & (KP-1);
    float v = 0.f;
    if (m < NN && k < NN)
        v = dinv[m] * (adj[(size_t)m*NN + k] + (m == k ? 1.f : 0.f)) * dinv[k];
    Lhi[idx] = f2bf(v);
}

// fragment-order L: idx = ((mg*32+kb)*64 + lane)*8 + e
__global__ void k_buildLf(const float* __restrict__ adj, const float* __restrict__ dinv,
                          u16* __restrict__ Lf) {
    size_t idx = (size_t)blockIdx.x * 256 + threadIdx.x;
    if (idx >= (size_t)KP*KP) return;
    int e    = idx & 7;
    int lane = (idx >> 3) & 63;
    int kb   = (idx >> 9) & 31;
    int mg   = idx >> 14;
    int m = mg*16 + (lane & 15);
    int k = kb*32 + (lane >> 4)*8 + e;
    float v = 0.f;
    if (m < NN && k < NN)
        v = dinv[m] * (adj[(size_t)m*NN + k] + (m == k ? 1.f : 0.f)) * dinv[k];
    Lf[idx] = f2bf(v);
}

__global__ void k_srow(const float* __restrict__ adj, const float* __restrict__ dinv,
                       float* __restrict__ srl) {
    int m = blockIdx.x;
    __shared__ float red[256];
    float s = 0.f;
    if (m < NN)
        for (int n = threadIdx.x; n < NN; n += blockDim.x)
            s += adj[(size_t)m*NN + n] * dinv[n];
    red[threadIdx.x] = s; __syncthreads();
    for (int st = 128; st > 0; st >>= 1) {
        if (threadIdx.x < st) red[threadIdx.x] += red[threadIdx.x + st];
        __syncthreads();
    }
    if (threadIdx.x == 0) srl[m] = (m < NN) ? dinv[m] * (red[0] + dinv[m]) : 0.f;
}

// ---------------- W conversion ----------------
__global__ void k_wconv(const float* __restrict__ W1, const float* __restrict__ W2,
                        u16* __restrict__ W1h, u16* __restrict__ W2h) {
    int idx = blockIdx.x * 256 + threadIdx.x;
    if (idx < 128*128) {
        int k = idx >> 7, f = idx & 127;
        W1h[idx] = f2bf((f < 104) ? W1[f*128 + k] : 0.f);
    } else if (idx < 128*128 + 64*128) {
        int i2 = idx - 128*128;
        int c = i2 >> 7, f = i2 & 127;
        W2h[i2] = f2bf((f < 104) ? W2[f*64 + c] : 0.f);
    }
}

// ---------------- pack aspect projections ----------------
__global__ void k_packW(const float* __restrict__ Wo, const float* __restrict__ bo,
                        const float* __restrict__ Wd, const float* __restrict__ bd,
                        const float* __restrict__ We, const float* __restrict__ be,
                        const float* __restrict__ Wi, const float* __restrict__ bi,
                        float* __restrict__ Wp, float* __restrict__ bp) {
    for (int o = threadIdx.x; o < 21*40; o += 256) {
        int f = o / 40, a = o - f*40;
        int g = a / 10, aa = a - 10*g;
        float v = 0.f;
        if (g == 0) {
            if (f == 2) v = Wo[0*10+aa]; else if (f == 5) v = Wo[1*10+aa];
            else if (f == 8) v = Wo[2*10+aa]; else if (f == 9) v = Wo[3*10+aa];
            else if (f == 12) v = Wo[4*10+aa];
        } else if (g == 1) {
            if (f == 10) v = Wd[aa]; else if (f == 14) v = Wd[10+aa];
            else if (f == 15) v = Wd[20+aa];
        } else if (g == 2) {
            if (f == 13) v = We[aa]; else if (f == 17) v = We[10+aa];
        } else {
            if (f == 19) v = Wi[aa]; else if (f == 20) v = Wi[10+aa];
        }
        Wp[o] = v;
    }
    if (threadIdx.x < 40) {
        int a = threadIdx.x, g = a / 10, aa = a - 10*g;
        bp[a] = (g == 0) ? bo[aa] : (g == 1) ? bd[aa] : (g == 2) ? be[aa] : bi[aa];
    }
}

// ---------------- transpose inputs -> inT[(t*32+b)*21+f][1024] bf16 ----------------
__global__ __launch_bounds__(256)
void k_transpose(const float* __restrict__ inputs, u16* __restrict__ inT) {
    int bt = blockIdx.x;                // b*48 + t
    int b = bt / SEQ, t = bt - b*SEQ;
    int nt = blockIdx.y;
    __shared__ float sm[128][22];
    const float* base = inputs + ((size_t)bt * NN + nt*128) * 21;
    for (int i = threadIdx.x; i < 128*21; i += 256) {
        int nn = i / 21, f = i - nn*21;
        int n = nt*128 + nn;
        sm[nn][f] = (n < NN) ? base[(size_t)nn*21 + f] : 0.f;
    }
    __syncthreads();
    for (int o = threadIdx.x; o < 21*128; o += 256) {
        int f = o >> 7, nn = o & 127;
        inT[(size_t)((t*32 + b)*21 + f)*KP + nt*128 + nn] = f2bf(sm[nn][f]);
    }
}

// ---------------- plain MFMA GEMM (one-shot Linp), bf16 out ----------------
// grid (8 m-tiles, 504 col-tiles): consecutive blockIdx covers all m of one
// col-tile -> col-slice stays hot in L2/L3 for its 8 readers.
__global__ __launch_bounds__(512)
void k_gemm(const u16* __restrict__ A, const u16* __restrict__ B,
            u16* __restrict__ Cout, int ncols) {
    __shared__ char sA[128*64];
    __shared__ char sB[64*64];
    const int m0 = blockIdx.x * 128;
    const int n0 = blockIdx.y * 64;
    const int tid = threadIdx.x;
    const int w = tid >> 6, lane = tid & 63;
    const int l15 = lane & 15, l4 = lane >> 4;
    const int wm = w >> 1, wn = w & 1;

    float4v acc[2][2];
    #pragma unroll
    for (int i = 0; i < 2; ++i)
        #pragma unroll
        for (int j = 0; j < 2; ++j) acc[i][j] = (float4v){0.f,0.f,0.f,0.f};

    int aoff[2], boff[2];
    #pragma unroll
    for (int mf = 0; mf < 2; ++mf) {
        int r = wm*32 + mf*16 + l15;
        aoff[mf] = (r*64 + l4*16) ^ ((r & 7) << 4);
    }
    #pragma unroll
    for (int nf = 0; nf < 2; ++nf) {
        int r = wn*32 + nf*16 + l15;
        boff[nf] = (r*64 + l4*16) ^ ((r & 7) << 4);
    }
    const int rA = tid >> 2, qA = tid & 3;
    const int dA = (rA*64 + qA*16) ^ ((rA & 7) << 4);
    const size_t gA = (size_t)(m0 + rA)*KP + qA*8;
    const int rB = (tid & 255) >> 2, qB = tid & 3;
    const int dB = (rB*64 + qB*16) ^ ((rB & 7) << 4);
    const size_t gB = (size_t)(n0 + rB)*KP + qB*8;

    for (int kt = 0; kt < 32; ++kt) {
        const int k0 = kt*32;
        __syncthreads();
        *(uint4*)(sA + dA) = *(const uint4*)(A + gA + k0);
        if (tid < 256) *(uint4*)(sB + dB) = *(const uint4*)(B + gB + k0);
        __syncthreads();
        short8v a0 = *(const short8v*)(sA + aoff[0]);
        short8v a1 = *(const short8v*)(sA + aoff[1]);
        short8v b0 = *(const short8v*)(sB + boff[0]);
        short8v b1 = *(const short8v*)(sB + boff[1]);
        acc[0][0] = __builtin_amdgcn_mfma_f32_16x16x32_bf16(a0, b0, acc[0][0], 0, 0, 0);
        acc[0][1] = __builtin_amdgcn_mfma_f32_16x16x32_bf16(a0, b1, acc[0][1], 0, 0, 0);
        acc[1][0] = __builtin_amdgcn_mfma_f32_16x16x32_bf16(a1, b0, acc[1][0], 0, 0, 0);
        acc[1][1] = __builtin_amdgcn_mfma_f32_16x16x32_bf16(a1, b1, acc[1][1], 0, 0, 0);
    }
    #pragma unroll
    for (int mf = 0; mf < 2; ++mf)
        #pragma unroll
        for (int nf = 0; nf < 2; ++nf)
            #pragma unroll
            for (int i = 0; i < 4; ++i) {
                int m = m0 + wm*32 + mf*16 + l4*4 + i;
                int j = n0 + wn*32 + nf*16 + l15;
                Cout[(size_t)m*ncols + j] = f2bf(acc[mf][nf][i]);
            }
}

// frag helper: offset (in u16) of fragment (grp, kb) for this lane
__device__ __forceinline__ size_t frag_off(int grp, int kb, int lane) {
    return (((size_t)grp*32 + kb)*64 + lane)*8;
}

// ---------------- G1: agh = L@hT (frag-direct) + fused gate + r/u demux ----------------
__global__ __launch_bounds__(256)
void k_g1(const u16* __restrict__ Lf, const u16* __restrict__ hTf,
          const u16* __restrict__ agx, const u16* __restrict__ W1h,
          const float* __restrict__ b1, const float* __restrict__ h_lin,
          u16* __restrict__ rhf, float* __restrict__ u_lin) {
    const int b = blockIdx.x, mt = blockIdx.y;
    const int m0 = mt*64;
    const int tid = threadIdx.x;
    const int w = tid >> 6, lane = tid & 63, l15 = lane & 15, l4 = lane >> 4;
    const int wm = w >> 1, wn = w & 1;
    const int c = tid & 63, ng = tid >> 6;

    __shared__ char smem[49408];
    char* sF = smem;                        // 16384: feature tile [64][128] bf16 swizzled
    float* ru_s = (float*)(smem + 16384);   // 64*129*4

    float4v acc[2][2];
    #pragma unroll
    for (int i = 0; i < 2; ++i)
        #pragma unroll
        for (int j = 0; j < 2; ++j) acc[i][j] = (float4v){0.f,0.f,0.f,0.f};

    const u16* A0 = Lf  + frag_off(mt*4 + wm*2 + 0, 0, lane);
    const u16* A1 = Lf  + frag_off(mt*4 + wm*2 + 1, 0, lane);
    const u16* B0 = hTf + frag_off(b*4  + wn*2 + 0, 0, lane);
    const u16* B1 = hTf + frag_off(b*4  + wn*2 + 1, 0, lane);
    #pragma unroll 8
    for (int kb = 0; kb < 32; ++kb) {
        short8v a0 = *(const short8v*)(A0 + kb*512);
        short8v a1 = *(const short8v*)(A1 + kb*512);
        short8v b0 = *(const short8v*)(B0 + kb*512);
        short8v b1 = *(const short8v*)(B1 + kb*512);
        acc[0][0] = __builtin_amdgcn_mfma_f32_16x16x32_bf16(a0, b0, acc[0][0], 0, 0, 0);
        acc[0][1] = __builtin_amdgcn_mfma_f32_16x16x32_bf16(a0, b1, acc[0][1], 0, 0, 0);
        acc[1][0] = __builtin_amdgcn_mfma_f32_16x16x32_bf16(a1, b0, acc[1][0], 0, 0, 0);
        acc[1][1] = __builtin_amdgcn_mfma_f32_16x16x32_bf16(a1, b1, acc[1][1], 0, 0, 0);
    }

    // T14 prefetch: issue the demux-phase h_lin reads now; latency hides
    // under the gate MFMA phase below.
    float hpre[4][8];
    #pragma unroll
    for (int it = 0; it < 4; ++it) {
        int nc = (it*4 + ng)*8;
        int n = 2*m0 + nc;
        if ((n >> 1) + 3 < 500) {
            #pragma unroll
            for (int d = 0; d < 8; ++d)
                hpre[it][d] = h_lin[((size_t)b*NN + n + d)*64 + c];
        }
    }

    // build feature tile sF [64 rows][128 f] bf16 swizzled
    if (tid < 192) {   // zero pad f 104..127
        int r = tid / 3, q = tid - 3*(tid/3);
        *(uint4*)(sF + ((r*256 + (13 + q)*16) ^ ((r & 7) << 4))) = (uint4){0,0,0,0};
    }
    for (int i = tid; i < 320; i += 256) {  // agx cols 0..39
        int r = i / 5, q = i - 5*(i/5);
        *(uint4*)(sF + ((r*256 + q*16) ^ ((r & 7) << 4))) =
            *(const uint4*)(agx + (size_t)(m0 + r)*1280 + b*40 + q*8);
    }
    #pragma unroll
    for (int mf = 0; mf < 2; ++mf)
        #pragma unroll
        for (int nf = 0; nf < 2; ++nf)
            #pragma unroll
            for (int i = 0; i < 4; ++i) {   // agh cols 40..103 from regs
                int row = wm*32 + mf*16 + l4*4 + i;
                int f = 40 + wn*32 + nf*16 + l15;
                *(u16*)(sF + ((row*256 + f*2) ^ ((row & 7) << 4))) = f2bf(acc[mf][nf][i]);
            }
    __syncthreads();

    // gate MFMA: 64 rows x 128 gate cols; wave: 32m x 64g
    const int gm = wm*32, gn = wn*64;
    float4v acc2[2][4];
    #pragma unroll
    for (int i = 0; i < 2; ++i)
        #pragma unroll
        for (int j = 0; j < 4; ++j) acc2[i][j] = (float4v){0.f,0.f,0.f,0.f};
    for (int kt2 = 0; kt2 < 4; ++kt2) {
        #pragma unroll
        for (int mf = 0; mf < 2; ++mf) {
            int ar2 = gm + mf*16 + l15;
            short8v a = *(const short8v*)(sF + ((ar2*256 + kt2*64 + l4*16) ^ ((ar2 & 7) << 4)));
            #pragma unroll
            for (int nf = 0; nf < 4; ++nf) {
                short8v bb = *(const short8v*)(W1h + (gn + nf*16 + l15)*128 + kt2*32 + l4*8);
                acc2[mf][nf] = __builtin_amdgcn_mfma_f32_16x16x32_bf16(a, bb, acc2[mf][nf], 0, 0, 0);
            }
        }
    }
    #pragma unroll
    for (int mf = 0; mf < 2; ++mf)
        #pragma unroll
        for (int nf = 0; nf < 4; ++nf) {
            int col = gn + nf*16 + l15;
            float bias = b1[col];
            #pragma unroll
            for (int i = 0; i < 4; ++i) {
                int row = gm + mf*16 + l4*4 + i;
                ru_s[row*129 + col] = 1.f / (1.f + __expf(-(acc2[mf][nf][i] + bias)));
            }
        }
    __syncthreads();

    // demux. r: gate row m<500 -> r(2m), r(2m+1); write rh in fragment order.
    #pragma unroll
    for (int it = 0; it < 4; ++it) {
        int nc = (it*4 + ng)*8;            // local node offset 0..120
        int n = 2*m0 + nc;                 // global start node (even, mult of 8)
        if ((n >> 1) + 3 < 500) {
            ushort8v ov;
            #pragma unroll
            for (int d = 0; d < 8; ++d) {
                int nn = n + d;
                float r = ru_s[((nc + d) >> 1)*129 + (nn & 1)*64 + c];
                ov[d] = f2bf(r * hpre[it][d]);
            }
            *(ushort8v*)(rhf + frag_off(b*4 + (c >> 4), n >> 5, (c & 15) + 16*((n >> 3) & 3))) = ov;
        }
    }
    // u: gate row m>=500 -> u nodes 2(m-500), +1 (linear layout)
    for (int lc = 0; lc < 16; lc += 4) {
        int lr = ng*16 + lc;
        int m = m0 + lr;
        if (m >= 500) {
            #pragma unroll
            for (int d = 0; d < 4; ++d) {
                int mm = m + d;
                if (mm < 1000) {
                    int n = 2*(mm - 500);
                    u_lin[((size_t)b*NN + n)*64 + c]     = ru_s[(lr+d)*129 + c];
                    u_lin[((size_t)b*NN + n + 1)*64 + c] = ru_s[(lr+d)*129 + 64 + c];
                }
            }
        }
    }
}

// ---------------- G2: agc = L@rh (frag-direct) + fused update + h'/hT/out/next-agx ----------------
__global__ __launch_bounds__(256)
void k_g2(const u16* __restrict__ Lf, const u16* __restrict__ rhf,
          const u16* __restrict__ agx, const u16* __restrict__ W2h,
          const float* __restrict__ b2, const float* __restrict__ u_lin,
          float* __restrict__ h_lin, u16* __restrict__ hTf,
          const u16* __restrict__ LinpB, const float* __restrict__ Wp,
          const float* __restrict__ bp, const float* __restrict__ srl,
          u16* __restrict__ agx_next, int tnext,
          float* __restrict__ out, int write_out) {
    const int b = blockIdx.x, mt = blockIdx.y;
    const int m0 = mt*64;
    const int tid = threadIdx.x;
    const int w = tid >> 6, lane = tid & 63, l15 = lane & 15, l4 = lane >> 4;
    const int wm = w >> 1, wn = w & 1;
    const int c = tid & 63, ng = tid >> 6;

    __shared__ char smem[42016];
    char* sF = smem;                      // 16384
    float* cs  = (float*)(smem + 16384);  // 64*65*4 = 16640
    float* sLp = (float*)(smem + 33024);  // 64*22*4 = 5632
    float* sWp = (float*)(smem + 38656);  // 21*40*4 = 3360
    __shared__ float sbp[40];
    __shared__ float ssr[64];

    float4v acc[2][2];
    #pragma unroll
    for (int i = 0; i < 2; ++i)
        #pragma unroll
        for (int j = 0; j < 2; ++j) acc[i][j] = (float4v){0.f,0.f,0.f,0.f};

    const u16* A0 = Lf  + frag_off(mt*4 + wm*2 + 0, 0, lane);
    const u16* A1 = Lf  + frag_off(mt*4 + wm*2 + 1, 0, lane);
    const u16* B0 = rhf + frag_off(b*4  + wn*2 + 0, 0, lane);
    const u16* B1 = rhf + frag_off(b*4  + wn*2 + 1, 0, lane);
    #pragma unroll 8
    for (int kb = 0; kb < 32; ++kb) {
        short8v a0 = *(const short8v*)(A0 + kb*512);
        short8v a1 = *(const short8v*)(A1 + kb*512);
        short8v b0 = *(const short8v*)(B0 + kb*512);
        short8v b1 = *(const short8v*)(B1 + kb*512);
        acc[0][0] = __builtin_amdgcn_mfma_f32_16x16x32_bf16(a0, b0, acc[0][0], 0, 0, 0);
        acc[0][1] = __builtin_amdgcn_mfma_f32_16x16x32_bf16(a0, b1, acc[0][1], 0, 0, 0);
        acc[1][0] = __builtin_amdgcn_mfma_f32_16x16x32_bf16(a1, b0, acc[1][0], 0, 0, 0);
        acc[1][1] = __builtin_amdgcn_mfma_f32_16x16x32_bf16(a1, b1, acc[1][1], 0, 0, 0);
    }

    // T14 prefetch: u/h for the update epilogue; latency hides under the
    // update MFMA phase.
    float upre[2][8], hpre[2][8];
    #pragma unroll
    for (int q2 = 0; q2 < 2; ++q2) {
        int m = m0 + ng*16 + q2*8;
        #pragma unroll
        for (int d = 0; d < 8; ++d) {
            int mm = m + d;
            size_t idx = ((size_t)b*NN + mm)*64 + c;
            bool ok = mm < NN;
            upre[q2][d] = ok ? u_lin[idx] : 0.f;
            hpre[q2][d] = ok ? h_lin[idx] : 0.f;
        }
    }

    if (tid < 192) {
        int r = tid / 3, q = tid - 3*(tid/3);
        *(uint4*)(sF + ((r*256 + (13 + q)*16) ^ ((r & 7) << 4))) = (uint4){0,0,0,0};
    }
    for (int i = tid; i < 320; i += 256) {
        int r = i / 5, q = i - 5*(i/5);
        *(uint4*)(sF + ((r*256 + q*16) ^ ((r & 7) << 4))) =
            *(const uint4*)(agx + (size_t)(m0 + r)*1280 + b*40 + q*8);
    }
    #pragma unroll
    for (int mf = 0; mf < 2; ++mf)
        #pragma unroll
        for (int nf = 0; nf < 2; ++nf)
            #pragma unroll
            for (int i = 0; i < 4; ++i) {
                int row = wm*32 + mf*16 + l4*4 + i;
                int f = 40 + wn*32 + nf*16 + l15;
                *(u16*)(sF + ((row*256 + f*2) ^ ((row & 7) << 4))) = f2bf(acc[mf][nf][i]);
            }
    __syncthreads();

    // early sLp/sWp staging: independent of update MFMA; overlaps with it.
    if (tnext < SEQ) {
        for (int i = tid; i < 64*21; i += 256) {
            int r = i / 21, f = i - 21*(i/21);
            sLp[r*22 + f] = bf2f(LinpB[(size_t)(m0 + r)*LCOLS + tnext*672 + b*21 + f]);
        }
        for (int i = tid; i < 21*40; i += 256) sWp[i] = Wp[i];
        if (tid < 40) sbp[tid] = bp[tid];
        if (tid < 64) ssr[tid] = srl[m0 + tid];
    }

    // update MFMA: 64 rows x 64 cols; wave: 32m x 32c
    const int gm = wm*32, gn = wn*32;
    float4v acc3[2][2];
    #pragma unroll
    for (int i = 0; i < 2; ++i)
        #pragma unroll
        for (int j = 0; j < 2; ++j) acc3[i][j] = (float4v){0.f,0.f,0.f,0.f};
    for (int kt2 = 0; kt2 < 4; ++kt2) {
        #pragma unroll
        for (int mf = 0; mf < 2; ++mf) {
            int ar2 = gm + mf*16 + l15;
            short8v a = *(const short8v*)(sF + ((ar2*256 + kt2*64 + l4*16) ^ ((ar2 & 7) << 4)));
            #pragma unroll
            for (int nf = 0; nf < 2; ++nf) {
                short8v bb = *(const short8v*)(W2h + (gn + nf*16 + l15)*128 + kt2*32 + l4*8);
                acc3[mf][nf] = __builtin_amdgcn_mfma_f32_16x16x32_bf16(a, bb, acc3[mf][nf], 0, 0, 0);
            }
        }
    }
    #pragma unroll
    for (int mf = 0; mf < 2; ++mf)
        #pragma unroll
        for (int nf = 0; nf < 2; ++nf) {
            int col = gn + nf*16 + l15;
            float bias = b2[col];
            #pragma unroll
            for (int i = 0; i < 4; ++i) {
                int row = gm + mf*16 + l4*4 + i;
                cs[row*65 + col] = acc3[mf][nf][i] + bias;
            }
        }
    __syncthreads();

    #pragma unroll
    for (int q2 = 0; q2 < 2; ++q2) {
        int lr = ng*16 + q2*8;
        int m = m0 + lr;                     // node chunk m..m+7
        ushort8v hiv;
        #pragma unroll
        for (int d = 0; d < 8; ++d) {
            int mm = m + d;
            float hn = 0.f;
            if (mm < NN) {
                float x = cs[(lr+d)*65 + c];
                x = fminf(fmaxf(x, -15.f), 15.f);
                float e = __expf(2.f*x);
                float cand = (e - 1.f) / (e + 1.f);
                float u = upre[q2][d], h = hpre[q2][d];
                hn = u*h + (1.f - u)*cand;
                size_t idx = ((size_t)b*NN + mm)*64 + c;
                h_lin[idx] = hn;
                if (write_out) out[idx] = hn;
            }
            hiv[d] = f2bf(hn);
        }
        *(ushort8v*)(hTf + frag_off(b*4 + (c >> 4), m >> 5, (c & 15) + 16*((m >> 3) & 3))) = hiv;
    }

    if (tnext < SEQ) {
        __syncthreads();   // (already synced above; keep write->read order for sLp)
        for (int o = tid; o < 64*40; o += 256) {
            int r = o / 40, a = o - 40*(o/40);
            float acc4 = ssr[r] * sbp[a];
            #pragma unroll
            for (int f = 0; f < 21; ++f) acc4 += sLp[r*22 + f] * sWp[f*40 + a];
            agx_next[(size_t)(m0 + r)*1280 + b*40 + a] = f2bf(acc4);
        }
    }
}

// ---------------- standalone agx producer (t=0) ----------------
__global__ __launch_bounds__(256)
void k_xproj2(const u16* __restrict__ LinpB, const float* __restrict__ Wp,
              const float* __restrict__ bp, const float* __restrict__ srl,
              u16* __restrict__ agx, int t) {
    const int b = blockIdx.x, mt = blockIdx.y;
    const int tid = threadIdx.x;
    __shared__ float sLp[64][22];
    __shared__ float sWp[21*40];
    __shared__ float sbp[40];
    __shared__ float ssr[64];
    for (int i = tid; i < 64*21; i += 256) {
        int r = i / 21, f = i - 21*(i/21);
        sLp[r][f] = bf2f(LinpB[(size_t)(mt*64 + r)*LCOLS + t*672 + b*21 + f]);
    }
    for (int i = tid; i < 21*40; i += 256) sWp[i] = Wp[i];
    if (tid < 40) sbp[tid] = bp[tid];
    if (tid < 64) ssr[tid] = srl[mt*64 + tid];
    __syncthreads();
    for (int o = tid; o < 64*40; o += 256) {
        int r = o / 40, a = o - 40*(o/40);
        float acc2 = ssr[r] * sbp[a];
        #pragma unroll
        for (int f = 0; f < 21; ++f) acc2 += sLp[r][f] * sWp[f*40 + a];
        agx[(size_t)(mt*64 + r)*1280 + b*40 + a] = f2bf(acc2);
    }
}

// ---------------- workspace layout (byte offsets, ~166 MB of ~516 MB ws) ----------------
#define O_LHI   0ull
#define O_LF    2097152ull
#define O_LINP  4194304ull
#define O_HLIN  70254592ull
#define O_ULIN  78446592ull
#define O_HTF   86638592ull
#define O_RHF   90832896ull
#define O_AGX0  95027200ull
#define O_AGX1  97648640ull
#define O_W1H   100270080ull
#define O_W2H   100302848ull
#define O_WP    100319232ull
#define O_BP    100323328ull
#define O_DINV  100323584ull
#define O_SRL   100327680ull
#define O_INT   100331776ull

extern "C" void kernel_launch(void* const* d_in, const int* in_sizes, int n_in,
                              void* d_out, int out_size, void* d_ws, size_t ws_size,
                              hipStream_t stream) {
    const float* inputs = (const float*)d_in[0];
    const float* adj    = (const float*)d_in[1];
    const float* Wo = (const float*)d_in[2];  const float* bo = (const float*)d_in[3];
    const float* Wd = (const float*)d_in[4];  const float* bd = (const float*)d_in[5];
    const float* We = (const float*)d_in[6];  const float* be = (const float*)d_in[7];
    const float* Wi = (const float*)d_in[8];  const float* bi = (const float*)d_in[9];
    const float* W1 = (const float*)d_in[10]; const float* b1 = (const float*)d_in[11];
    const float* W2 = (const float*)d_in[12]; const float* b2 = (const float*)d_in[13];
    float* out = (float*)d_out;

    char* ws = (char*)d_ws;
    u16*   Lhi   = (u16*)(ws + O_LHI);
    u16*   Lf    = (u16*)(ws + O_LF);
    u16*   LinpB = (u16*)(ws + O_LINP);
    float* h_lin = (float*)(ws + O_HLIN);
    float* u_lin = (float*)(ws + O_ULIN);
    u16*   hTf   = (u16*)(ws + O_HTF);
    u16*   rhf   = (u16*)(ws + O_RHF);
    u16*   agx0  = (u16*)(ws + O_AGX0);
    u16*   agx1  = (u16*)(ws + O_AGX1);
    u16*   W1h   = (u16*)(ws + O_W1H);
    u16*   W2h   = (u16*)(ws + O_W2H);
    float* Wp    = (float*)(ws + O_WP);
    float* bp    = (float*)(ws + O_BP);
    float* dinv  = (float*)(ws + O_DINV);
    float* srl   = (float*)(ws + O_SRL);
    u16*   inT   = (u16*)(ws + O_INT);

    k_rowsum<<<NN, 256, 0, stream>>>(adj, dinv);
    k_buildL<<<(KP*KP)/256, 256, 0, stream>>>(adj, dinv, Lhi);
    k_buildLf<<<(KP*KP)/256, 256, 0, stream>>>(adj, dinv, Lf);
    k_srow<<<KP, 256, 0, stream>>>(adj, dinv, srl);
    k_wconv<<<96, 256, 0, stream>>>(W1, W2, W1h, W2h);
    k_packW<<<1, 256, 0, stream>>>(Wo, bo, Wd, bd, We, be, Wi, bi, Wp, bp);
    k_transpose<<<dim3(BATCH*SEQ, 8), 256, 0, stream>>>(inputs, inT);
    k_gemm<<<dim3(8, LCOLS/64), 512, 0, stream>>>(Lhi, inT, LinpB, LCOLS);

    hipMemsetAsync(ws + O_HLIN, 0, 8192000ull, stream);   // h0 = 0
    hipMemsetAsync(ws + O_HTF,  0, 4194304ull, stream);   // hT frags = 0
    hipMemsetAsync(ws + O_RHF,  0, 4194304ull, stream);   // rh pad frags = 0
    k_xproj2<<<dim3(32,16), 256, 0, stream>>>(LinpB, Wp, bp, srl, agx0, 0);

    for (int t = 0; t < SEQ; ++t) {
        u16* agxc = (t & 1) ? agx1 : agx0;
        u16* agxn = (t & 1) ? agx0 : agx1;
        k_g1<<<dim3(32,16), 256, 0, stream>>>(Lf, hTf, agxc, W1h, b1, h_lin, rhf, u_lin);
        k_g2<<<dim3(32,16), 256, 0, stream>>>(Lf, rhf, agxc, W2h, b2, u_lin, h_lin, hTf,
                                              LinpB, Wp, bp, srl, agxn, t + 1,
                                              out, t == SEQ - 1);
    }
}

// Round 11
// 2427.824 us; speedup vs baseline: 2.5114x; 1.0725x over previous
//
#include <hip/hip_runtime.h>
#include <math.h>

#define NN    1000
#define KP    1024
#define BATCH 32
#define SEQ   48
#define HID   64
#define LCOLS 32256                 // 48*32*21 premultiplied input cols

typedef unsigned short u16;
typedef __attribute__((ext_vector_type(8))) short  short8v;
typedef __attribute__((ext_vector_type(8))) unsigned short ushort8v;
typedef __attribute__((ext_vector_type(4))) float  float4v;

__device__ __forceinline__ u16 f2bf(float x) {
    union { float f; unsigned u; } v; v.f = x;
    unsigned r = v.u + 0x7FFF + ((v.u >> 16) & 1);
    return (u16)(r >> 16);
}
__device__ __forceinline__ float bf2f(u16 h) {
    union { unsigned u; float f; } v; v.u = ((unsigned)h) << 16;
    return v.f;
}

// ---------------- Laplacian ----------------
__global__ void k_rowsum(const float* __restrict__ adj, float* __restrict__ dinv) {
    int m = blockIdx.x;
    float s = 0.f;
    for (int n = threadIdx.x; n < NN; n += blockDim.x)
        s += adj[(size_t)m*NN + n];
    __shared__ float red[256];
    red[threadIdx.x] = s; __syncthreads();
    for (int st = 128; st > 0; st >>= 1) {
        if (threadIdx.x < st) red[threadIdx.x] += red[threadIdx.x + st];
        __syncthreads();
    }
    if (threadIdx.x == 0) dinv[m] = rsqrtf(red[0] + 1.0f);
}

__global__ void k_buildL(const float* __restrict__ adj, const float* __restrict__ dinv,
                         u16* __restrict__ Lhi) {
    int idx = blockIdx.x * 256 + threadIdx.x;
    if (idx >= KP*KP) return;
    int m = idx >> 10, k = idx & (KP-1);
    float v = 0.f;
    if (m < NN && k < NN)
        v = dinv[m] * (adj[(size_t)m*NN + k] + (m == k ? 1.f : 0.f)) * dinv[k];
    Lhi[idx] = f2bf(v);
}

// fragment-order L: idx = ((mg*32+kb)*64 + lane)*8 + e
__global__ void k_buildLf(const float* __restrict__ adj, const float* __restrict__ dinv,
                          u16* __restrict__ Lf) {
    size_t idx = (size_t)blockIdx.x * 256 + threadIdx.x;
    if (idx >= (size_t)KP*KP) return;
    int e    = idx & 7;
    int lane = (idx >> 3) & 63;
    int kb   = (idx >> 9) & 31;
    int mg   = idx >> 14;
    int m = mg*16 + (lane & 15);
    int k = kb*32 + (lane >> 4)*8 + e;
    float v = 0.f;
    if (m < NN && k < NN)
        v = dinv[m] * (adj[(size_t)m*NN + k] + (m == k ? 1.f : 0.f)) * dinv[k];
    Lf[idx] = f2bf(v);
}

__global__ void k_srow(const float* __restrict__ adj, const float* __restrict__ dinv,
                       float* __restrict__ srl) {
    int m = blockIdx.x;
    __shared__ float red[256];
    float s = 0.f;
    if (m < NN)
        for (int n = threadIdx.x; n < NN; n += blockDim.x)
            s += adj[(size_t)m*NN + n] * dinv[n];
    red[threadIdx.x] = s; __syncthreads();
    for (int st = 128; st > 0; st >>= 1) {
        if (threadIdx.x < st) red[threadIdx.x] += red[threadIdx.x + st];
        __syncthreads();
    }
    if (threadIdx.x == 0) srl[m] = (m < NN) ? dinv[m] * (red[0] + dinv[m]) : 0.f;
}

// ---------------- W conversion ----------------
__global__ void k_wconv(const float* __restrict__ W1, const float* __restrict__ W2,
                        u16* __restrict__ W1h, u16* __restrict__ W2h) {
    int idx = blockIdx.x * 256 + threadIdx.x;
    if (idx < 128*128) {
        int k = idx >> 7, f = idx & 127;
        W1h[idx] = f2bf((f < 104) ? W1[f*128 + k] : 0.f);
    } else if (idx < 128*128 + 64*128) {
        int i2 = idx - 128*128;
        int c = i2 >> 7, f = i2 & 127;
        W2h[i2] = f2bf((f < 104) ? W2[f*64 + c] : 0.f);
    }
}

// ---------------- pack aspect projections ----------------
__global__ void k_packW(const float* __restrict__ Wo, const float* __restrict__ bo,
                        const float* __restrict__ Wd, const float* __restrict__ bd,
                        const float* __restrict__ We, const float* __restrict__ be,
                        const float* __restrict__ Wi, const float* __restrict__ bi,
                        float* __restrict__ Wp, float* __restrict__ bp) {
    for (int o = threadIdx.x; o < 21*40; o += 256) {
        int f = o / 40, a = o - f*40;
        int g = a / 10, aa = a - 10*g;
        float v = 0.f;
        if (g == 0) {
            if (f == 2) v = Wo[0*10+aa]; else if (f == 5) v = Wo[1*10+aa];
            else if (f == 8) v = Wo[2*10+aa]; else if (f == 9) v = Wo[3*10+aa];
            else if (f == 12) v = Wo[4*10+aa];
        } else if (g == 1) {
            if (f == 10) v = Wd[aa]; else if (f == 14) v = Wd[10+aa];
            else if (f == 15) v = Wd[20+aa];
        } else if (g == 2) {
            if (f == 13) v = We[aa]; else if (f == 17) v = We[10+aa];
        } else {
            if (f == 19) v = Wi[aa]; else if (f == 20) v = Wi[10+aa];
        }
        Wp[o] = v;
    }
    if (threadIdx.x < 40) {
        int a = threadIdx.x, g = a / 10, aa = a - 10*g;
        bp[a] = (g == 0) ? bo[aa] : (g == 1) ? bd[aa] : (g == 2) ? be[aa] : bi[aa];
    }
}

// ---------------- transpose inputs -> inT[(t*32+b)*21+f][1024] bf16 ----------------
__global__ __launch_bounds__(256)
void k_transpose(const float* __restrict__ inputs, u16* __restrict__ inT) {
    int bt = blockIdx.x;                // b*48 + t
    int b = bt / SEQ, t = bt - b*SEQ;
    int nt = blockIdx.y;
    __shared__ float sm[128][22];
    const float* base = inputs + ((size_t)bt * NN + nt*128) * 21;
    for (int i = threadIdx.x; i < 128*21; i += 256) {
        int nn = i / 21, f = i - nn*21;
        int n = nt*128 + nn;
        sm[nn][f] = (n < NN) ? base[(size_t)nn*21 + f] : 0.f;
    }
    __syncthreads();
    for (int o = threadIdx.x; o < 21*128; o += 256) {
        int f = o >> 7, nn = o & 127;
        inT[(size_t)((t*32 + b)*21 + f)*KP + nt*128 + nn] = f2bf(sm[nn][f]);
    }
}

// ---------------- plain MFMA GEMM (one-shot Linp), bf16 out ----------------
__global__ __launch_bounds__(512)
void k_gemm(const u16* __restrict__ A, const u16* __restrict__ B,
            u16* __restrict__ Cout, int ncols) {
    __shared__ char sA[128*64];
    __shared__ char sB[64*64];
    const int n0 = blockIdx.x * 64;
    const int m0 = blockIdx.y * 128;
    const int tid = threadIdx.x;
    const int w = tid >> 6, lane = tid & 63;
    const int l15 = lane & 15, l4 = lane >> 4;
    const int wm = w >> 1, wn = w & 1;

    float4v acc[2][2];
    #pragma unroll
    for (int i = 0; i < 2; ++i)
        #pragma unroll
        for (int j = 0; j < 2; ++j) acc[i][j] = (float4v){0.f,0.f,0.f,0.f};

    int aoff[2], boff[2];
    #pragma unroll
    for (int mf = 0; mf < 2; ++mf) {
        int r = wm*32 + mf*16 + l15;
        aoff[mf] = (r*64 + l4*16) ^ ((r & 7) << 4);
    }
    #pragma unroll
    for (int nf = 0; nf < 2; ++nf) {
        int r = wn*32 + nf*16 + l15;
        boff[nf] = (r*64 + l4*16) ^ ((r & 7) << 4);
    }
    const int rA = tid >> 2, qA = tid & 3;
    const int dA = (rA*64 + qA*16) ^ ((rA & 7) << 4);
    const size_t gA = (size_t)(m0 + rA)*KP + qA*8;
    const int rB = (tid & 255) >> 2, qB = tid & 3;
    const int dB = (rB*64 + qB*16) ^ ((rB & 7) << 4);
    const size_t gB = (size_t)(n0 + rB)*KP + qB*8;

    for (int kt = 0; kt < 32; ++kt) {
        const int k0 = kt*32;
        __syncthreads();
        *(uint4*)(sA + dA) = *(const uint4*)(A + gA + k0);
        if (tid < 256) *(uint4*)(sB + dB) = *(const uint4*)(B + gB + k0);
        __syncthreads();
        short8v a0 = *(const short8v*)(sA + aoff[0]);
        short8v a1 = *(const short8v*)(sA + aoff[1]);
        short8v b0 = *(const short8v*)(sB + boff[0]);
        short8v b1 = *(const short8v*)(sB + boff[1]);
        acc[0][0] = __builtin_amdgcn_mfma_f32_16x16x32_bf16(a0, b0, acc[0][0], 0, 0, 0);
        acc[0][1] = __builtin_amdgcn_mfma_f32_16x16x32_bf16(a0, b1, acc[0][1], 0, 0, 0);
        acc[1][0] = __builtin_amdgcn_mfma_f32_16x16x32_bf16(a1, b0, acc[1][0], 0, 0, 0);
        acc[1][1] = __builtin_amdgcn_mfma_f32_16x16x32_bf16(a1, b1, acc[1][1], 0, 0, 0);
    }
    #pragma unroll
    for (int mf = 0; mf < 2; ++mf)
        #pragma unroll
        for (int nf = 0; nf < 2; ++nf)
            #pragma unroll
            for (int i = 0; i < 4; ++i) {
                int m = m0 + wm*32 + mf*16 + l4*4 + i;
                int j = n0 + wn*32 + nf*16 + l15;
                Cout[(size_t)m*ncols + j] = f2bf(acc[mf][nf][i]);
            }
}

// frag helper: offset (in u16) of fragment (grp, kb) for this lane
__device__ __forceinline__ size_t frag_off(int grp, int kb, int lane) {
    return (((size_t)grp*32 + kb)*64 + lane)*8;
}

// ---------------- G1 (512 thr / 8 waves): agh = L@hT + fused gate + r/u demux ----------------
__global__ __launch_bounds__(512)
void k_g1(const u16* __restrict__ Lf, const u16* __restrict__ hTf,
          const u16* __restrict__ agx, const u16* __restrict__ W1h,
          const float* __restrict__ b1, const float* __restrict__ h_lin,
          u16* __restrict__ rhf, float* __restrict__ u_lin) {
    const int b = blockIdx.x, mt = blockIdx.y;
    const int m0 = mt*64;
    const int tid = threadIdx.x;
    const int w = tid >> 6, lane = tid & 63, l15 = lane & 15, l4 = lane >> 4;
    const int wm = w >> 2, wn = w & 3;        // 2m x 4n waves
    const int c = tid & 63, ng = tid >> 6;    // ng in 0..7

    __shared__ char smem[49408];
    char* sF = smem;                        // 16384: feature tile [64][128] bf16 swizzled
    float* ru_s = (float*)(smem + 16384);   // 64*129*4

    // K-loop: wave (wm, wn): A-groups {wm*2, wm*2+1}, B-group wn
    float4v acc[2];
    acc[0] = (float4v){0.f,0.f,0.f,0.f};
    acc[1] = (float4v){0.f,0.f,0.f,0.f};
    const u16* A0 = Lf  + frag_off(mt*4 + wm*2 + 0, 0, lane);
    const u16* A1 = Lf  + frag_off(mt*4 + wm*2 + 1, 0, lane);
    const u16* B0 = hTf + frag_off(b*4  + wn, 0, lane);
    #pragma unroll 8
    for (int kb = 0; kb < 32; ++kb) {
        short8v a0 = *(const short8v*)(A0 + kb*512);
        short8v a1 = *(const short8v*)(A1 + kb*512);
        short8v b0 = *(const short8v*)(B0 + kb*512);
        acc[0] = __builtin_amdgcn_mfma_f32_16x16x32_bf16(a0, b0, acc[0], 0, 0, 0);
        acc[1] = __builtin_amdgcn_mfma_f32_16x16x32_bf16(a1, b0, acc[1], 0, 0, 0);
    }

    // T14 prefetch: demux-phase h_lin reads (hide under gate MFMA)
    float hpre[2][8];
    #pragma unroll
    for (int it = 0; it < 2; ++it) {
        int nc = (it*8 + ng)*8;
        int n = 2*m0 + nc;
        if ((n >> 1) + 3 < 500) {
            #pragma unroll
            for (int d = 0; d < 8; ++d)
                hpre[it][d] = h_lin[((size_t)b*NN + n + d)*64 + c];
        }
    }

    // feature tile sF [64 rows][128 f] bf16 swizzled
    if (tid < 192) {   // zero pad f 104..127
        int r = tid / 3, q = tid - 3*(tid/3);
        *(uint4*)(sF + ((r*256 + (13 + q)*16) ^ ((r & 7) << 4))) = (uint4){0,0,0,0};
    }
    if (tid < 320) {   // agx cols 0..39
        int r = tid / 5, q = tid - 5*(tid/5);
        *(uint4*)(sF + ((r*256 + q*16) ^ ((r & 7) << 4))) =
            *(const uint4*)(agx + (size_t)(m0 + r)*1280 + b*40 + q*8);
    }
    #pragma unroll
    for (int mf = 0; mf < 2; ++mf)
        #pragma unroll
        for (int i = 0; i < 4; ++i) {   // agh cols 40..103 from regs
            int row = (wm*2 + mf)*16 + l4*4 + i;
            int f = 40 + wn*16 + l15;
            *(u16*)(sF + ((row*256 + f*2) ^ ((row & 7) << 4))) = f2bf(acc[mf][i]);
        }
    __syncthreads();

    // gate MFMA: 64 rows x 128 gate cols; 8 waves = 2m x 4g of 32x32
    const int gm = (w >> 2)*32, gn = (w & 3)*32;
    float4v acc2[2][2];
    #pragma unroll
    for (int i = 0; i < 2; ++i)
        #pragma unroll
        for (int j = 0; j < 2; ++j) acc2[i][j] = (float4v){0.f,0.f,0.f,0.f};
    for (int kt2 = 0; kt2 < 4; ++kt2) {
        #pragma unroll
        for (int mf = 0; mf < 2; ++mf) {
            int ar2 = gm + mf*16 + l15;
            short8v a = *(const short8v*)(sF + ((ar2*256 + kt2*64 + l4*16) ^ ((ar2 & 7) << 4)));
            #pragma unroll
            for (int nf = 0; nf < 2; ++nf) {
                short8v bb = *(const short8v*)(W1h + (gn + nf*16 + l15)*128 + kt2*32 + l4*8);
                acc2[mf][nf] = __builtin_amdgcn_mfma_f32_16x16x32_bf16(a, bb, acc2[mf][nf], 0, 0, 0);
            }
        }
    }
    #pragma unroll
    for (int mf = 0; mf < 2; ++mf)
        #pragma unroll
        for (int nf = 0; nf < 2; ++nf) {
            int col = gn + nf*16 + l15;
            float bias = b1[col];
            #pragma unroll
            for (int i = 0; i < 4; ++i) {
                int row = gm + mf*16 + l4*4 + i;
                ru_s[row*129 + col] = 1.f / (1.f + __expf(-(acc2[mf][nf][i] + bias)));
            }
        }
    __syncthreads();

    // demux. r: gate row m<500 -> r(2m), r(2m+1); write rh in fragment order.
    #pragma unroll
    for (int it = 0; it < 2; ++it) {
        int nc = (it*8 + ng)*8;            // local node offset 0..120
        int n = 2*m0 + nc;                 // global start node (even, mult of 8)
        if ((n >> 1) + 3 < 500) {
            ushort8v ov;
            #pragma unroll
            for (int d = 0; d < 8; ++d) {
                int nn = n + d;
                float r = ru_s[((nc + d) >> 1)*129 + (nn & 1)*64 + c];
                ov[d] = f2bf(r * hpre[it][d]);
            }
            *(ushort8v*)(rhf + frag_off(b*4 + (c >> 4), n >> 5, (c & 15) + 16*((n >> 3) & 3))) = ov;
        }
    }
    // u: gate row m>=500 -> u nodes 2(m-500), +1 (linear layout)
    #pragma unroll
    for (int lc = 0; lc < 8; lc += 4) {
        int lr = ng*8 + lc;
        int m = m0 + lr;
        if (m >= 500) {
            #pragma unroll
            for (int d = 0; d < 4; ++d) {
                int mm = m + d;
                if (mm < 1000) {
                    int n = 2*(mm - 500);
                    u_lin[((size_t)b*NN + n)*64 + c]     = ru_s[(lr+d)*129 + c];
                    u_lin[((size_t)b*NN + n + 1)*64 + c] = ru_s[(lr+d)*129 + 64 + c];
                }
            }
        }
    }
}

// ---------------- G2 (512 thr / 8 waves): agc = L@rh + fused update + h'/hT/out/next-agx ----------------
__global__ __launch_bounds__(512)
void k_g2(const u16* __restrict__ Lf, const u16* __restrict__ rhf,
          const u16* __restrict__ agx, const u16* __restrict__ W2h,
          const float* __restrict__ b2, const float* __restrict__ u_lin,
          float* __restrict__ h_lin, u16* __restrict__ hTf,
          const u16* __restrict__ LinpB, const float* __restrict__ Wp,
          const float* __restrict__ bp, const float* __restrict__ srl,
          u16* __restrict__ agx_next, int tnext,
          float* __restrict__ out, int write_out) {
    const int b = blockIdx.x, mt = blockIdx.y;
    const int m0 = mt*64;
    const int tid = threadIdx.x;
    const int w = tid >> 6, lane = tid & 63, l15 = lane & 15, l4 = lane >> 4;
    const int wm = w >> 2, wn = w & 3;
    const int c = tid & 63, ng = tid >> 6;

    __shared__ char smem[42016];
    char* sF = smem;                      // 16384
    float* cs  = (float*)(smem + 16384);  // 64*65*4 = 16640
    float* sLp = (float*)(smem + 33024);  // 64*22*4 = 5632
    float* sWp = (float*)(smem + 38656);  // 21*40*4 = 3360
    __shared__ float sbp[40];
    __shared__ float ssr[64];

    float4v acc[2];
    acc[0] = (float4v){0.f,0.f,0.f,0.f};
    acc[1] = (float4v){0.f,0.f,0.f,0.f};
    const u16* A0 = Lf  + frag_off(mt*4 + wm*2 + 0, 0, lane);
    const u16* A1 = Lf  + frag_off(mt*4 + wm*2 + 1, 0, lane);
    const u16* B0 = rhf + frag_off(b*4  + wn, 0, lane);
    #pragma unroll 8
    for (int kb = 0; kb < 32; ++kb) {
        short8v a0 = *(const short8v*)(A0 + kb*512);
        short8v a1 = *(const short8v*)(A1 + kb*512);
        short8v b0 = *(const short8v*)(B0 + kb*512);
        acc[0] = __builtin_amdgcn_mfma_f32_16x16x32_bf16(a0, b0, acc[0], 0, 0, 0);
        acc[1] = __builtin_amdgcn_mfma_f32_16x16x32_bf16(a1, b0, acc[1], 0, 0, 0);
    }

    // T14 prefetch: u/h for the update epilogue (hide under update MFMA)
    float upre[8], hpre[8];
    {
        int m = m0 + ng*8;
        #pragma unroll
        for (int d = 0; d < 8; ++d) {
            int mm = m + d;
            size_t idx = ((size_t)b*NN + mm)*64 + c;
            bool ok = mm < NN;
            upre[d] = ok ? u_lin[idx] : 0.f;
            hpre[d] = ok ? h_lin[idx] : 0.f;
        }
    }

    if (tid < 192) {
        int r = tid / 3, q = tid - 3*(tid/3);
        *(uint4*)(sF + ((r*256 + (13 + q)*16) ^ ((r & 7) << 4))) = (uint4){0,0,0,0};
    }
    if (tid < 320) {
        int r = tid / 5, q = tid - 5*(tid/5);
        *(uint4*)(sF + ((r*256 + q*16) ^ ((r & 7) << 4))) =
            *(const uint4*)(agx + (size_t)(m0 + r)*1280 + b*40 + q*8);
    }
    #pragma unroll
    for (int mf = 0; mf < 2; ++mf)
        #pragma unroll
        for (int i = 0; i < 4; ++i) {
            int row = (wm*2 + mf)*16 + l4*4 + i;
            int f = 40 + wn*16 + l15;
            *(u16*)(sF + ((row*256 + f*2) ^ ((row & 7) << 4))) = f2bf(acc[mf][i]);
        }
    __syncthreads();

    // early sLp/sWp staging: independent of update MFMA; overlaps with it.
    if (tnext < SEQ) {
        for (int i = tid; i < 64*21; i += 512) {
            int r = i / 21, f = i - 21*(i/21);
            sLp[r*22 + f] = bf2f(LinpB[(size_t)(m0 + r)*LCOLS + tnext*672 + b*21 + f]);
        }
        for (int i = tid; i < 21*40; i += 512) sWp[i] = Wp[i];
        if (tid < 40) sbp[tid] = bp[tid];
        if (tid < 64) ssr[tid] = srl[m0 + tid];
    }

    // update MFMA: 64 rows x 64 cols; 8 waves = 2m x 4c of 32x16
    const int gm = (w >> 2)*32, gn = (w & 3)*16;
    float4v acc3[2];
    acc3[0] = (float4v){0.f,0.f,0.f,0.f};
    acc3[1] = (float4v){0.f,0.f,0.f,0.f};
    for (int kt2 = 0; kt2 < 4; ++kt2) {
        #pragma unroll
        for (int mf = 0; mf < 2; ++mf) {
            int ar2 = gm + mf*16 + l15;
            short8v a = *(const short8v*)(sF + ((ar2*256 + kt2*64 + l4*16) ^ ((ar2 & 7) << 4)));
            short8v bb = *(const short8v*)(W2h + (gn + l15)*128 + kt2*32 + l4*8);
            acc3[mf] = __builtin_amdgcn_mfma_f32_16x16x32_bf16(a, bb, acc3[mf], 0, 0, 0);
        }
    }
    #pragma unroll
    for (int mf = 0; mf < 2; ++mf) {
        int col = gn + l15;
        float bias = b2[col];
        #pragma unroll
        for (int i = 0; i < 4; ++i) {
            int row = gm + mf*16 + l4*4 + i;
            cs[row*65 + col] = acc3[mf][i] + bias;
        }
    }
    __syncthreads();

    {
        int lr = ng*8;
        int m = m0 + lr;                     // node chunk m..m+7
        ushort8v hiv;
        #pragma unroll
        for (int d = 0; d < 8; ++d) {
            int mm = m + d;
            float hn = 0.f;
            if (mm < NN) {
                float x = cs[(lr+d)*65 + c];
                x = fminf(fmaxf(x, -15.f), 15.f);
                float e = __expf(2.f*x);
                float cand = (e - 1.f) / (e + 1.f);
                float u = upre[d], h = hpre[d];
                hn = u*h + (1.f - u)*cand;
                size_t idx = ((size_t)b*NN + mm)*64 + c;
                h_lin[idx] = hn;
                if (write_out) out[idx] = hn;
            }
            hiv[d] = f2bf(hn);
        }
        *(ushort8v*)(hTf + frag_off(b*4 + (c >> 4), m >> 5, (c & 15) + 16*((m >> 3) & 3))) = hiv;
    }

    if (tnext < SEQ) {
        __syncthreads();
        for (int o = tid; o < 64*40; o += 512) {
            int r = o / 40, a = o - 40*(o/40);
            float acc4 = ssr[r] * sbp[a];
            #pragma unroll
            for (int f = 0; f < 21; ++f) acc4 += sLp[r*22 + f] * sWp[f*40 + a];
            agx_next[(size_t)(m0 + r)*1280 + b*40 + a] = f2bf(acc4);
        }
    }
}

// ---------------- standalone agx producer (t=0) ----------------
__global__ __launch_bounds__(256)
void k_xproj2(const u16* __restrict__ LinpB, const float* __restrict__ Wp,
              const float* __restrict__ bp, const float* __restrict__ srl,
              u16* __restrict__ agx, int t) {
    const int b = blockIdx.x, mt = blockIdx.y;
    const int tid = threadIdx.x;
    __shared__ float sLp[64][22];
    __shared__ float sWp[21*40];
    __shared__ float sbp[40];
    __shared__ float ssr[64];
    for (int i = tid; i < 64*21; i += 256) {
        int r = i / 21, f = i - 21*(i/21);
        sLp[r][f] = bf2f(LinpB[(size_t)(mt*64 + r)*LCOLS + t*672 + b*21 + f]);
    }
    for (int i = tid; i < 21*40; i += 256) sWp[i] = Wp[i];
    if (tid < 40) sbp[tid] = bp[tid];
    if (tid < 64) ssr[tid] = srl[mt*64 + tid];
    __syncthreads();
    for (int o = tid; o < 64*40; o += 256) {
        int r = o / 40, a = o - 40*(o/40);
        float acc2 = ssr[r] * sbp[a];
        #pragma unroll
        for (int f = 0; f < 21; ++f) acc2 += sLp[r][f] * sWp[f*40 + a];
        agx[(size_t)(mt*64 + r)*1280 + b*40 + a] = f2bf(acc2);
    }
}

// ---------------- workspace layout (byte offsets, ~166 MB of ~516 MB ws) ----------------
#define O_LHI   0ull
#define O_LF    2097152ull
#define O_LINP  4194304ull
#define O_HLIN  70254592ull
#define O_ULIN  78446592ull
#define O_HTF   86638592ull
#define O_RHF   90832896ull
#define O_AGX0  95027200ull
#define O_AGX1  97648640ull
#define O_W1H   100270080ull
#define O_W2H   100302848ull
#define O_WP    100319232ull
#define O_BP    100323328ull
#define O_DINV  100323584ull
#define O_SRL   100327680ull
#define O_INT   100331776ull

extern "C" void kernel_launch(void* const* d_in, const int* in_sizes, int n_in,
                              void* d_out, int out_size, void* d_ws, size_t ws_size,
                              hipStream_t stream) {
    const float* inputs = (const float*)d_in[0];
    const float* adj    = (const float*)d_in[1];
    const float* Wo = (const float*)d_in[2];  const float* bo = (const float*)d_in[3];
    const float* Wd = (const float*)d_in[4];  const float* bd = (const float*)d_in[5];
    const float* We = (const float*)d_in[6];  const float* be = (const float*)d_in[7];
    const float* Wi = (const float*)d_in[8];  const float* bi = (const float*)d_in[9];
    const float* W1 = (const float*)d_in[10]; const float* b1 = (const float*)d_in[11];
    const float* W2 = (const float*)d_in[12]; const float* b2 = (const float*)d_in[13];
    float* out = (float*)d_out;

    char* ws = (char*)d_ws;
    u16*   Lhi   = (u16*)(ws + O_LHI);
    u16*   Lf    = (u16*)(ws + O_LF);
    u16*   LinpB = (u16*)(ws + O_LINP);
    float* h_lin = (float*)(ws + O_HLIN);
    float* u_lin = (float*)(ws + O_ULIN);
    u16*   hTf   = (u16*)(ws + O_HTF);
    u16*   rhf   = (u16*)(ws + O_RHF);
    u16*   agx0  = (u16*)(ws + O_AGX0);
    u16*   agx1  = (u16*)(ws + O_AGX1);
    u16*   W1h   = (u16*)(ws + O_W1H);
    u16*   W2h   = (u16*)(ws + O_W2H);
    float* Wp    = (float*)(ws + O_WP);
    float* bp    = (float*)(ws + O_BP);
    float* dinv  = (float*)(ws + O_DINV);
    float* srl   = (float*)(ws + O_SRL);
    u16*   inT   = (u16*)(ws + O_INT);

    k_rowsum<<<NN, 256, 0, stream>>>(adj, dinv);
    k_buildL<<<(KP*KP)/256, 256, 0, stream>>>(adj, dinv, Lhi);
    k_buildLf<<<(KP*KP)/256, 256, 0, stream>>>(adj, dinv, Lf);
    k_srow<<<KP, 256, 0, stream>>>(adj, dinv, srl);
    k_wconv<<<96, 256, 0, stream>>>(W1, W2, W1h, W2h);
    k_packW<<<1, 256, 0, stream>>>(Wo, bo, Wd, bd, We, be, Wi, bi, Wp, bp);
    k_transpose<<<dim3(BATCH*SEQ, 8), 256, 0, stream>>>(inputs, inT);
    k_gemm<<<dim3(LCOLS/64, 8), 512, 0, stream>>>(Lhi, inT, LinpB, LCOLS);

    hipMemsetAsync(ws + O_HLIN, 0, 8192000ull, stream);   // h0 = 0
    hipMemsetAsync(ws + O_HTF,  0, 4194304ull, stream);   // hT frags = 0
    hipMemsetAsync(ws + O_RHF,  0, 4194304ull, stream);   // rh pad frags = 0
    k_xproj2<<<dim3(32,16), 256, 0, stream>>>(LinpB, Wp, bp, srl, agx0, 0);

    for (int t = 0; t < SEQ; ++t) {
        u16* agxc = (t & 1) ? agx1 : agx0;
        u16* agxn = (t & 1) ? agx0 : agx1;
        k_g1<<<dim3(32,16), 512, 0, stream>>>(Lf, hTf, agxc, W1h, b1, h_lin, rhf, u_lin);
        k_g2<<<dim3(32,16), 512, 0, stream>>>(Lf, rhf, agxc, W2h, b2, u_lin, h_lin, hTf,
                                              LinpB, Wp, bp, srl, agxn, t + 1,
                                              out, t == SEQ - 1);
    }
}

// Round 12
// 2238.123 us; speedup vs baseline: 2.7243x; 1.0848x over previous
//
#include <hip/hip_runtime.h>
#include <math.h>

#define NN    1000
#define KP    1024
#define BATCH 32
#define SEQ   48
#define HID   64
#define LCOLS 32256                 // 48*32*21 premultiplied input cols

typedef unsigned short u16;
typedef __attribute__((ext_vector_type(8))) short  short8v;
typedef __attribute__((ext_vector_type(8))) unsigned short ushort8v;
typedef __attribute__((ext_vector_type(4))) float  float4v;

__device__ __forceinline__ u16 f2bf(float x) {
    union { float f; unsigned u; } v; v.f = x;
    unsigned r = v.u + 0x7FFF + ((v.u >> 16) & 1);
    return (u16)(r >> 16);
}
__device__ __forceinline__ float bf2f(u16 h) {
    union { unsigned u; float f; } v; v.u = ((unsigned)h) << 16;
    return v.f;
}

// ---------------- Laplacian ----------------
__global__ void k_rowsum(const float* __restrict__ adj, float* __restrict__ dinv) {
    int m = blockIdx.x;
    float s = 0.f;
    for (int n = threadIdx.x; n < NN; n += blockDim.x)
        s += adj[(size_t)m*NN + n];
    __shared__ float red[256];
    red[threadIdx.x] = s; __syncthreads();
    for (int st = 128; st > 0; st >>= 1) {
        if (threadIdx.x < st) red[threadIdx.x] += red[threadIdx.x + st];
        __syncthreads();
    }
    if (threadIdx.x == 0) dinv[m] = rsqrtf(red[0] + 1.0f);
}

__global__ void k_buildL(const float* __restrict__ adj, const float* __restrict__ dinv,
                         u16* __restrict__ Lhi) {
    int idx = blockIdx.x * 256 + threadIdx.x;
    if (idx >= KP*KP) return;
    int m = idx >> 10, k = idx & (KP-1);
    float v = 0.f;
    if (m < NN && k < NN)
        v = dinv[m] * (adj[(size_t)m*NN + k] + (m == k ? 1.f : 0.f)) * dinv[k];
    Lhi[idx] = f2bf(v);
}

// fragment-order L: idx = ((mg*32+kb)*64 + lane)*8 + e
__global__ void k_buildLf(const float* __restrict__ adj, const float* __restrict__ dinv,
                          u16* __restrict__ Lf) {
    size_t idx = (size_t)blockIdx.x * 256 + threadIdx.x;
    if (idx >= (size_t)KP*KP) return;
    int e    = idx & 7;
    int lane = (idx >> 3) & 63;
    int kb   = (idx >> 9) & 31;
    int mg   = idx >> 14;
    int m = mg*16 + (lane & 15);
    int k = kb*32 + (lane >> 4)*8 + e;
    float v = 0.f;
    if (m < NN && k < NN)
        v = dinv[m] * (adj[(size_t)m*NN + k] + (m == k ? 1.f : 0.f)) * dinv[k];
    Lf[idx] = f2bf(v);
}

__global__ void k_srow(const float* __restrict__ adj, const float* __restrict__ dinv,
                       float* __restrict__ srl) {
    int m = blockIdx.x;
    __shared__ float red[256];
    float s = 0.f;
    if (m < NN)
        for (int n = threadIdx.x; n < NN; n += blockDim.x)
            s += adj[(size_t)m*NN + n] * dinv[n];
    red[threadIdx.x] = s; __syncthreads();
    for (int st = 128; st > 0; st >>= 1) {
        if (threadIdx.x < st) red[threadIdx.x] += red[threadIdx.x + st];
        __syncthreads();
    }
    if (threadIdx.x == 0) srl[m] = (m < NN) ? dinv[m] * (red[0] + dinv[m]) : 0.f;
}

// ---------------- W conversion ----------------
__global__ void k_wconv(const float* __restrict__ W1, const float* __restrict__ W2,
                        u16* __restrict__ W1h, u16* __restrict__ W2h) {
    int idx = blockIdx.x * 256 + threadIdx.x;
    if (idx < 128*128) {
        int k = idx >> 7, f = idx & 127;
        W1h[idx] = f2bf((f < 104) ? W1[f*128 + k] : 0.f);
    } else if (idx < 128*128 + 64*128) {
        int i2 = idx - 128*128;
        int c = i2 >> 7, f = i2 & 127;
        W2h[i2] = f2bf((f < 104) ? W2[f*64 + c] : 0.f);
    }
}

// ---------------- pack aspect projections ----------------
__global__ void k_packW(const float* __restrict__ Wo, const float* __restrict__ bo,
                        const float* __restrict__ Wd, const float* __restrict__ bd,
                        const float* __restrict__ We, const float* __restrict__ be,
                        const float* __restrict__ Wi, const float* __restrict__ bi,
                        float* __restrict__ Wp, float* __restrict__ bp) {
    for (int o = threadIdx.x; o < 21*40; o += 256) {
        int f = o / 40, a = o - f*40;
        int g = a / 10, aa = a - 10*g;
        float v = 0.f;
        if (g == 0) {
            if (f == 2) v = Wo[0*10+aa]; else if (f == 5) v = Wo[1*10+aa];
            else if (f == 8) v = Wo[2*10+aa]; else if (f == 9) v = Wo[3*10+aa];
            else if (f == 12) v = Wo[4*10+aa];
        } else if (g == 1) {
            if (f == 10) v = Wd[aa]; else if (f == 14) v = Wd[10+aa];
            else if (f == 15) v = Wd[20+aa];
        } else if (g == 2) {
            if (f == 13) v = We[aa]; else if (f == 17) v = We[10+aa];
        } else {
            if (f == 19) v = Wi[aa]; else if (f == 20) v = Wi[10+aa];
        }
        Wp[o] = v;
    }
    if (threadIdx.x < 40) {
        int a = threadIdx.x, g = a / 10, aa = a - 10*g;
        bp[a] = (g == 0) ? bo[aa] : (g == 1) ? bd[aa] : (g == 2) ? be[aa] : bi[aa];
    }
}

// ---------------- transpose inputs -> inT[(t*32+b)*21+f][1024] bf16 ----------------
__global__ __launch_bounds__(256)
void k_transpose(const float* __restrict__ inputs, u16* __restrict__ inT) {
    int bt = blockIdx.x;                // b*48 + t
    int b = bt / SEQ, t = bt - b*SEQ;
    int nt = blockIdx.y;
    __shared__ float sm[128][22];
    const float* base = inputs + ((size_t)bt * NN + nt*128) * 21;
    for (int i = threadIdx.x; i < 128*21; i += 256) {
        int nn = i / 21, f = i - nn*21;
        int n = nt*128 + nn;
        sm[nn][f] = (n < NN) ? base[(size_t)nn*21 + f] : 0.f;
    }
    __syncthreads();
    for (int o = threadIdx.x; o < 21*128; o += 256) {
        int f = o >> 7, nn = o & 127;
        inT[(size_t)((t*32 + b)*21 + f)*KP + nt*128 + nn] = f2bf(sm[nn][f]);
    }
}

// ---------------- one-shot Linp GEMM, persistent over the 8 m-tiles ----------------
// grid = 504 col-blocks. Each block loops all 8 m-tiles: its 128 KB B-slice is
// HBM-read once then L2-hot; A (L, 2 MB) is L2-resident across blocks.
__global__ __launch_bounds__(512)
void k_gemm(const u16* __restrict__ A, const u16* __restrict__ B,
            u16* __restrict__ Cout, int ncols) {
    __shared__ char sA[128*64];
    __shared__ char sB[64*64];
    const int n0 = blockIdx.x * 64;
    const int tid = threadIdx.x;
    const int w = tid >> 6, lane = tid & 63;
    const int l15 = lane & 15, l4 = lane >> 4;
    const int wm = w >> 1, wn = w & 1;

    int aoff[2], boff[2];
    #pragma unroll
    for (int mf = 0; mf < 2; ++mf) {
        int r = wm*32 + mf*16 + l15;
        aoff[mf] = (r*64 + l4*16) ^ ((r & 7) << 4);
    }
    #pragma unroll
    for (int nf = 0; nf < 2; ++nf) {
        int r = wn*32 + nf*16 + l15;
        boff[nf] = (r*64 + l4*16) ^ ((r & 7) << 4);
    }
    const int rA = tid >> 2, qA = tid & 3;
    const int dA = (rA*64 + qA*16) ^ ((rA & 7) << 4);
    const int rB = (tid & 255) >> 2, qB = tid & 3;
    const int dB = (rB*64 + qB*16) ^ ((rB & 7) << 4);
    const size_t gB = (size_t)(n0 + rB)*KP + qB*8;

    for (int mt8 = 0; mt8 < 8; ++mt8) {
        const int m0 = mt8 * 128;
        const size_t gA = (size_t)(m0 + rA)*KP + qA*8;
        float4v acc[2][2];
        #pragma unroll
        for (int i = 0; i < 2; ++i)
            #pragma unroll
            for (int j = 0; j < 2; ++j) acc[i][j] = (float4v){0.f,0.f,0.f,0.f};

        for (int kt = 0; kt < 32; ++kt) {
            const int k0 = kt*32;
            __syncthreads();
            *(uint4*)(sA + dA) = *(const uint4*)(A + gA + k0);
            if (tid < 256) *(uint4*)(sB + dB) = *(const uint4*)(B + gB + k0);
            __syncthreads();
            short8v a0 = *(const short8v*)(sA + aoff[0]);
            short8v a1 = *(const short8v*)(sA + aoff[1]);
            short8v b0 = *(const short8v*)(sB + boff[0]);
            short8v b1 = *(const short8v*)(sB + boff[1]);
            acc[0][0] = __builtin_amdgcn_mfma_f32_16x16x32_bf16(a0, b0, acc[0][0], 0, 0, 0);
            acc[0][1] = __builtin_amdgcn_mfma_f32_16x16x32_bf16(a0, b1, acc[0][1], 0, 0, 0);
            acc[1][0] = __builtin_amdgcn_mfma_f32_16x16x32_bf16(a1, b0, acc[1][0], 0, 0, 0);
            acc[1][1] = __builtin_amdgcn_mfma_f32_16x16x32_bf16(a1, b1, acc[1][1], 0, 0, 0);
        }
        #pragma unroll
        for (int mf = 0; mf < 2; ++mf)
            #pragma unroll
            for (int nf = 0; nf < 2; ++nf)
                #pragma unroll
                for (int i = 0; i < 4; ++i) {
                    int m = m0 + wm*32 + mf*16 + l4*4 + i;
                    int j = n0 + wn*32 + nf*16 + l15;
                    Cout[(size_t)m*ncols + j] = f2bf(acc[mf][nf][i]);
                }
        __syncthreads();
    }
}

// frag helper: offset (in u16) of fragment (grp, kb) for this lane
__device__ __forceinline__ size_t frag_off(int grp, int kb, int lane) {
    return (((size_t)grp*32 + kb)*64 + lane)*8;
}

// ---------------- G1 (512 thr / 8 waves, split-K): agh = L@hT + gate + r/u demux ----------------
__global__ __launch_bounds__(512)
void k_g1(const u16* __restrict__ Lf, const u16* __restrict__ hTf,
          const u16* __restrict__ agx, const u16* __restrict__ W1h,
          const float* __restrict__ b1, const float* __restrict__ h_lin,
          u16* __restrict__ rhf, float* __restrict__ u_lin) {
    const int b = blockIdx.x, mt = blockIdx.y;
    const int m0 = mt*64;
    const int tid = threadIdx.x;
    const int w = tid >> 6, lane = tid & 63, l15 = lane & 15, l4 = lane >> 4;
    const int kh = w >> 2, q = w & 3, qi = q >> 1, qj = q & 1;   // split-K waves
    const int c = tid & 63, ng = tid >> 6;    // ng in 0..7

    __shared__ char smem[49408];
    char* sF = smem;                        // 16384: feature tile [64][128] bf16 swizzled
    float* ru_s = (float*)(smem + 16384);   // 64*129*4 ; first 16 KB doubles as split-K red

    // K-loop: wave (kh, qi, qj): A-groups {2qi, 2qi+1}, B-groups {2qj, 2qj+1},
    // K-half kh. 4 loads / 4 MFMA per kb.
    float4v acc[2][2];
    #pragma unroll
    for (int i = 0; i < 2; ++i)
        #pragma unroll
        for (int j = 0; j < 2; ++j) acc[i][j] = (float4v){0.f,0.f,0.f,0.f};
    const u16* A0 = Lf  + frag_off(mt*4 + qi*2 + 0, kh*16, lane);
    const u16* A1 = Lf  + frag_off(mt*4 + qi*2 + 1, kh*16, lane);
    const u16* B0 = hTf + frag_off(b*4  + qj*2 + 0, kh*16, lane);
    const u16* B1 = hTf + frag_off(b*4  + qj*2 + 1, kh*16, lane);
    #pragma unroll 8
    for (int kb = 0; kb < 16; ++kb) {
        short8v a0 = *(const short8v*)(A0 + kb*512);
        short8v a1 = *(const short8v*)(A1 + kb*512);
        short8v b0 = *(const short8v*)(B0 + kb*512);
        short8v b1 = *(const short8v*)(B1 + kb*512);
        acc[0][0] = __builtin_amdgcn_mfma_f32_16x16x32_bf16(a0, b0, acc[0][0], 0, 0, 0);
        acc[0][1] = __builtin_amdgcn_mfma_f32_16x16x32_bf16(a0, b1, acc[0][1], 0, 0, 0);
        acc[1][0] = __builtin_amdgcn_mfma_f32_16x16x32_bf16(a1, b0, acc[1][0], 0, 0, 0);
        acc[1][1] = __builtin_amdgcn_mfma_f32_16x16x32_bf16(a1, b1, acc[1][1], 0, 0, 0);
    }

    // T14 prefetch: demux-phase h_lin reads (hide under gate MFMA)
    float hpre[2][8];
    #pragma unroll
    for (int it = 0; it < 2; ++it) {
        int nc = (it*8 + ng)*8;
        int n = 2*m0 + nc;
        if ((n >> 1) + 3 < 500) {
            #pragma unroll
            for (int d = 0; d < 8; ++d)
                hpre[it][d] = h_lin[((size_t)b*NN + n + d)*64 + c];
        }
    }

    // split-K dump (kh=1 -> red region, aliases ru_s which is dead here)
    float* red = ru_s;
    if (kh == 1) {
        #pragma unroll
        for (int fr = 0; fr < 4; ++fr)
            *(float4v*)(red + (((size_t)q*4 + fr)*64 + lane)*4) = acc[fr>>1][fr&1];
    }
    // independent sF writes (pad + agx) by all threads, overlaps dump
    if (tid < 192) {   // zero pad f 104..127
        int r = tid / 3, qq = tid - 3*(tid/3);
        *(uint4*)(sF + ((r*256 + (13 + qq)*16) ^ ((r & 7) << 4))) = (uint4){0,0,0,0};
    }
    if (tid < 320) {   // agx cols 0..39
        int r = tid / 5, qq = tid - 5*(tid/5);
        *(uint4*)(sF + ((r*256 + qq*16) ^ ((r & 7) << 4))) =
            *(const uint4*)(agx + (size_t)(m0 + r)*1280 + b*40 + qq*8);
    }
    __syncthreads();
    if (kh == 0) {
        #pragma unroll
        for (int fr = 0; fr < 4; ++fr)
            acc[fr>>1][fr&1] += *(const float4v*)(red + (((size_t)q*4 + fr)*64 + lane)*4);
        // agh cols 40..103 from combined regs
        #pragma unroll
        for (int mf = 0; mf < 2; ++mf)
            #pragma unroll
            for (int nf = 0; nf < 2; ++nf)
                #pragma unroll
                for (int i = 0; i < 4; ++i) {
                    int row = (qi*2 + mf)*16 + l4*4 + i;
                    int f = 40 + (qj*2 + nf)*16 + l15;
                    *(u16*)(sF + ((row*256 + f*2) ^ ((row & 7) << 4))) = f2bf(acc[mf][nf][i]);
                }
    }
    __syncthreads();

    // gate MFMA: 64 rows x 128 gate cols; 8 waves = 2m x 4g of 32x32
    const int gm = (w >> 2)*32, gn = (w & 3)*32;
    float4v acc2[2][2];
    #pragma unroll
    for (int i = 0; i < 2; ++i)
        #pragma unroll
        for (int j = 0; j < 2; ++j) acc2[i][j] = (float4v){0.f,0.f,0.f,0.f};
    for (int kt2 = 0; kt2 < 4; ++kt2) {
        #pragma unroll
        for (int mf = 0; mf < 2; ++mf) {
            int ar2 = gm + mf*16 + l15;
            short8v a = *(const short8v*)(sF + ((ar2*256 + kt2*64 + l4*16) ^ ((ar2 & 7) << 4)));
            #pragma unroll
            for (int nf = 0; nf < 2; ++nf) {
                short8v bb = *(const short8v*)(W1h + (gn + nf*16 + l15)*128 + kt2*32 + l4*8);
                acc2[mf][nf] = __builtin_amdgcn_mfma_f32_16x16x32_bf16(a, bb, acc2[mf][nf], 0, 0, 0);
            }
        }
    }
    __syncthreads();   // red region reads done; safe to overwrite ru_s
    #pragma unroll
    for (int mf = 0; mf < 2; ++mf)
        #pragma unroll
        for (int nf = 0; nf < 2; ++nf) {
            int col = gn + nf*16 + l15;
            float bias = b1[col];
            #pragma unroll
            for (int i = 0; i < 4; ++i) {
                int row = gm + mf*16 + l4*4 + i;
                ru_s[row*129 + col] = 1.f / (1.f + __expf(-(acc2[mf][nf][i] + bias)));
            }
        }
    __syncthreads();

    // demux. r: gate row m<500 -> r(2m), r(2m+1); write rh in fragment order.
    #pragma unroll
    for (int it = 0; it < 2; ++it) {
        int nc = (it*8 + ng)*8;            // local node offset 0..120
        int n = 2*m0 + nc;                 // global start node (even, mult of 8)
        if ((n >> 1) + 3 < 500) {
            ushort8v ov;
            #pragma unroll
            for (int d = 0; d < 8; ++d) {
                int nn = n + d;
                float r = ru_s[((nc + d) >> 1)*129 + (nn & 1)*64 + c];
                ov[d] = f2bf(r * hpre[it][d]);
            }
            *(ushort8v*)(rhf + frag_off(b*4 + (c >> 4), n >> 5, (c & 15) + 16*((n >> 3) & 3))) = ov;
        }
    }
    // u: gate row m>=500 -> u nodes 2(m-500), +1 (linear layout)
    #pragma unroll
    for (int lc = 0; lc < 8; lc += 4) {
        int lr = ng*8 + lc;
        int m = m0 + lr;
        if (m >= 500) {
            #pragma unroll
            for (int d = 0; d < 4; ++d) {
                int mm = m + d;
                if (mm < 1000) {
                    int n = 2*(mm - 500);
                    u_lin[((size_t)b*NN + n)*64 + c]     = ru_s[(lr+d)*129 + c];
                    u_lin[((size_t)b*NN + n + 1)*64 + c] = ru_s[(lr+d)*129 + 64 + c];
                }
            }
        }
    }
}

// ---------------- G2 (512 thr / 8 waves, split-K): agc = L@rh + update + h'/hT/out/next-agx ----------------
__global__ __launch_bounds__(512)
void k_g2(const u16* __restrict__ Lf, const u16* __restrict__ rhf,
          const u16* __restrict__ agx, const u16* __restrict__ W2h,
          const float* __restrict__ b2, const float* __restrict__ u_lin,
          float* __restrict__ h_lin, u16* __restrict__ hTf,
          const u16* __restrict__ LinpB, const float* __restrict__ Wp,
          const float* __restrict__ bp, const float* __restrict__ srl,
          u16* __restrict__ agx_next, int tnext,
          float* __restrict__ out, int write_out) {
    const int b = blockIdx.x, mt = blockIdx.y;
    const int m0 = mt*64;
    const int tid = threadIdx.x;
    const int w = tid >> 6, lane = tid & 63, l15 = lane & 15, l4 = lane >> 4;
    const int kh = w >> 2, q = w & 3, qi = q >> 1, qj = q & 1;
    const int c = tid & 63, ng = tid >> 6;

    __shared__ char smem[42016];
    char* sF = smem;                      // 16384
    float* cs  = (float*)(smem + 16384);  // 64*65*4 = 16640 ; doubles as split-K red
    float* sLp = (float*)(smem + 33024);  // 64*22*4 = 5632
    float* sWp = (float*)(smem + 38656);  // 21*40*4 = 3360
    __shared__ float sbp[40];
    __shared__ float ssr[64];

    float4v acc[2][2];
    #pragma unroll
    for (int i = 0; i < 2; ++i)
        #pragma unroll
        for (int j = 0; j < 2; ++j) acc[i][j] = (float4v){0.f,0.f,0.f,0.f};
    const u16* A0 = Lf  + frag_off(mt*4 + qi*2 + 0, kh*16, lane);
    const u16* A1 = Lf  + frag_off(mt*4 + qi*2 + 1, kh*16, lane);
    const u16* B0 = rhf + frag_off(b*4  + qj*2 + 0, kh*16, lane);
    const u16* B1 = rhf + frag_off(b*4  + qj*2 + 1, kh*16, lane);
    #pragma unroll 8
    for (int kb = 0; kb < 16; ++kb) {
        short8v a0 = *(const short8v*)(A0 + kb*512);
        short8v a1 = *(const short8v*)(A1 + kb*512);
        short8v b0 = *(const short8v*)(B0 + kb*512);
        short8v b1 = *(const short8v*)(B1 + kb*512);
        acc[0][0] = __builtin_amdgcn_mfma_f32_16x16x32_bf16(a0, b0, acc[0][0], 0, 0, 0);
        acc[0][1] = __builtin_amdgcn_mfma_f32_16x16x32_bf16(a0, b1, acc[0][1], 0, 0, 0);
        acc[1][0] = __builtin_amdgcn_mfma_f32_16x16x32_bf16(a1, b0, acc[1][0], 0, 0, 0);
        acc[1][1] = __builtin_amdgcn_mfma_f32_16x16x32_bf16(a1, b1, acc[1][1], 0, 0, 0);
    }

    // T14 prefetch: u/h for the update epilogue (hide under update MFMA)
    float upre[8], hpre[8];
    {
        int m = m0 + ng*8;
        #pragma unroll
        for (int d = 0; d < 8; ++d) {
            int mm = m + d;
            size_t idx = ((size_t)b*NN + mm)*64 + c;
            bool ok = mm < NN;
            upre[d] = ok ? u_lin[idx] : 0.f;
            hpre[d] = ok ? h_lin[idx] : 0.f;
        }
    }

    // split-K dump (kh=1 -> red region, aliases cs which is dead here)
    float* red = cs;
    if (kh == 1) {
        #pragma unroll
        for (int fr = 0; fr < 4; ++fr)
            *(float4v*)(red + (((size_t)q*4 + fr)*64 + lane)*4) = acc[fr>>1][fr&1];
    }
    if (tid < 192) {
        int r = tid / 3, qq = tid - 3*(tid/3);
        *(uint4*)(sF + ((r*256 + (13 + qq)*16) ^ ((r & 7) << 4))) = (uint4){0,0,0,0};
    }
    if (tid < 320) {
        int r = tid / 5, qq = tid - 5*(tid/5);
        *(uint4*)(sF + ((r*256 + qq*16) ^ ((r & 7) << 4))) =
            *(const uint4*)(agx + (size_t)(m0 + r)*1280 + b*40 + qq*8);
    }
    __syncthreads();
    if (kh == 0) {
        #pragma unroll
        for (int fr = 0; fr < 4; ++fr)
            acc[fr>>1][fr&1] += *(const float4v*)(red + (((size_t)q*4 + fr)*64 + lane)*4);
        #pragma unroll
        for (int mf = 0; mf < 2; ++mf)
            #pragma unroll
            for (int nf = 0; nf < 2; ++nf)
                #pragma unroll
                for (int i = 0; i < 4; ++i) {
                    int row = (qi*2 + mf)*16 + l4*4 + i;
                    int f = 40 + (qj*2 + nf)*16 + l15;
                    *(u16*)(sF + ((row*256 + f*2) ^ ((row & 7) << 4))) = f2bf(acc[mf][nf][i]);
                }
    }
    __syncthreads();

    // early sLp/sWp staging: independent of update MFMA; overlaps with it.
    if (tnext < SEQ) {
        for (int i = tid; i < 64*21; i += 512) {
            int r = i / 21, f = i - 21*(i/21);
            sLp[r*22 + f] = bf2f(LinpB[(size_t)(m0 + r)*LCOLS + tnext*672 + b*21 + f]);
        }
        for (int i = tid; i < 21*40; i += 512) sWp[i] = Wp[i];
        if (tid < 40) sbp[tid] = bp[tid];
        if (tid < 64) ssr[tid] = srl[m0 + tid];
    }

    // update MFMA: 64 rows x 64 cols; 8 waves = 2m x 4c of 32x16
    const int gm = (w >> 2)*32, gn = (w & 3)*16;
    float4v acc3[2];
    acc3[0] = (float4v){0.f,0.f,0.f,0.f};
    acc3[1] = (float4v){0.f,0.f,0.f,0.f};
    for (int kt2 = 0; kt2 < 4; ++kt2) {
        #pragma unroll
        for (int mf = 0; mf < 2; ++mf) {
            int ar2 = gm + mf*16 + l15;
            short8v a = *(const short8v*)(sF + ((ar2*256 + kt2*64 + l4*16) ^ ((ar2 & 7) << 4)));
            short8v bb = *(const short8v*)(W2h + (gn + l15)*128 + kt2*32 + l4*8);
            acc3[mf] = __builtin_amdgcn_mfma_f32_16x16x32_bf16(a, bb, acc3[mf], 0, 0, 0);
        }
    }
    __syncthreads();   // red reads done; safe to overwrite cs
    #pragma unroll
    for (int mf = 0; mf < 2; ++mf) {
        int col = gn + l15;
        float bias = b2[col];
        #pragma unroll
        for (int i = 0; i < 4; ++i) {
            int row = gm + mf*16 + l4*4 + i;
            cs[row*65 + col] = acc3[mf][i] + bias;
        }
    }
    __syncthreads();

    {
        int lr = ng*8;
        int m = m0 + lr;                     // node chunk m..m+7
        ushort8v hiv;
        #pragma unroll
        for (int d = 0; d < 8; ++d) {
            int mm = m + d;
            float hn = 0.f;
            if (mm < NN) {
                float x = cs[(lr+d)*65 + c];
                x = fminf(fmaxf(x, -15.f), 15.f);
                float e = __expf(2.f*x);
                float cand = (e - 1.f) / (e + 1.f);
                float u = upre[d], h = hpre[d];
                hn = u*h + (1.f - u)*cand;
                size_t idx = ((size_t)b*NN + mm)*64 + c;
                h_lin[idx] = hn;
                if (write_out) out[idx] = hn;
            }
            hiv[d] = f2bf(hn);
        }
        *(ushort8v*)(hTf + frag_off(b*4 + (c >> 4), m >> 5, (c & 15) + 16*((m >> 3) & 3))) = hiv;
    }

    if (tnext < SEQ) {
        __syncthreads();
        for (int o = tid; o < 64*40; o += 512) {
            int r = o / 40, a = o - 40*(o/40);
            float acc4 = ssr[r] * sbp[a];
            #pragma unroll
            for (int f = 0; f < 21; ++f) acc4 += sLp[r*22 + f] * sWp[f*40 + a];
            agx_next[(size_t)(m0 + r)*1280 + b*40 + a] = f2bf(acc4);
        }
    }
}

// ---------------- standalone agx producer (t=0) ----------------
__global__ __launch_bounds__(256)
void k_xproj2(const u16* __restrict__ LinpB, const float* __restrict__ Wp,
              const float* __restrict__ bp, const float* __restrict__ srl,
              u16* __restrict__ agx, int t) {
    const int b = blockIdx.x, mt = blockIdx.y;
    const int tid = threadIdx.x;
    __shared__ float sLp[64][22];
    __shared__ float sWp[21*40];
    __shared__ float sbp[40];
    __shared__ float ssr[64];
    for (int i = tid; i < 64*21; i += 256) {
        int r = i / 21, f = i - 21*(i/21);
        sLp[r][f] = bf2f(LinpB[(size_t)(mt*64 + r)*LCOLS + t*672 + b*21 + f]);
    }
    for (int i = tid; i < 21*40; i += 256) sWp[i] = Wp[i];
    if (tid < 40) sbp[tid] = bp[tid];
    if (tid < 64) ssr[tid] = srl[mt*64 + tid];
    __syncthreads();
    for (int o = tid; o < 64*40; o += 256) {
        int r = o / 40, a = o - 40*(o/40);
        float acc2 = ssr[r] * sbp[a];
        #pragma unroll
        for (int f = 0; f < 21; ++f) acc2 += sLp[r][f] * sWp[f*40 + a];
        agx[(size_t)(mt*64 + r)*1280 + b*40 + a] = f2bf(acc2);
    }
}

// ---------------- workspace layout (byte offsets, ~166 MB of ~516 MB ws) ----------------
#define O_LHI   0ull
#define O_LF    2097152ull
#define O_LINP  4194304ull
#define O_HLIN  70254592ull
#define O_ULIN  78446592ull
#define O_HTF   86638592ull
#define O_RHF   90832896ull
#define O_AGX0  95027200ull
#define O_AGX1  97648640ull
#define O_W1H   100270080ull
#define O_W2H   100302848ull
#define O_WP    100319232ull
#define O_BP    100323328ull
#define O_DINV  100323584ull
#define O_SRL   100327680ull
#define O_INT   100331776ull

extern "C" void kernel_launch(void* const* d_in, const int* in_sizes, int n_in,
                              void* d_out, int out_size, void* d_ws, size_t ws_size,
                              hipStream_t stream) {
    const float* inputs = (const float*)d_in[0];
    const float* adj    = (const float*)d_in[1];
    const float* Wo = (const float*)d_in[2];  const float* bo = (const float*)d_in[3];
    const float* Wd = (const float*)d_in[4];  const float* bd = (const float*)d_in[5];
    const float* We = (const float*)d_in[6];  const float* be = (const float*)d_in[7];
    const float* Wi = (const float*)d_in[8];  const float* bi = (const float*)d_in[9];
    const float* W1 = (const float*)d_in[10]; const float* b1 = (const float*)d_in[11];
    const float* W2 = (const float*)d_in[12]; const float* b2 = (const float*)d_in[13];
    float* out = (float*)d_out;

    char* ws = (char*)d_ws;
    u16*   Lhi   = (u16*)(ws + O_LHI);
    u16*   Lf    = (u16*)(ws + O_LF);
    u16*   LinpB = (u16*)(ws + O_LINP);
    float* h_lin = (float*)(ws + O_HLIN);
    float* u_lin = (float*)(ws + O_ULIN);
    u16*   hTf   = (u16*)(ws + O_HTF);
    u16*   rhf   = (u16*)(ws + O_RHF);
    u16*   agx0  = (u16*)(ws + O_AGX0);
    u16*   agx1  = (u16*)(ws + O_AGX1);
    u16*   W1h   = (u16*)(ws + O_W1H);
    u16*   W2h   = (u16*)(ws + O_W2H);
    float* Wp    = (float*)(ws + O_WP);
    float* bp    = (float*)(ws + O_BP);
    float* dinv  = (float*)(ws + O_DINV);
    float* srl   = (float*)(ws + O_SRL);
    u16*   inT   = (u16*)(ws + O_INT);

    k_rowsum<<<NN, 256, 0, stream>>>(adj, dinv);
    k_buildL<<<(KP*KP)/256, 256, 0, stream>>>(adj, dinv, Lhi);
    k_buildLf<<<(KP*KP)/256, 256, 0, stream>>>(adj, dinv, Lf);
    k_srow<<<KP, 256, 0, stream>>>(adj, dinv, srl);
    k_wconv<<<96, 256, 0, stream>>>(W1, W2, W1h, W2h);
    k_packW<<<1, 256, 0, stream>>>(Wo, bo, Wd, bd, We, be, Wi, bi, Wp, bp);
    k_transpose<<<dim3(BATCH*SEQ, 8), 256, 0, stream>>>(inputs, inT);
    k_gemm<<<dim3(LCOLS/64), 512, 0, stream>>>(Lhi, inT, LinpB, LCOLS);

    hipMemsetAsync(ws + O_HLIN, 0, 8192000ull, stream);   // h0 = 0
    hipMemsetAsync(ws + O_HTF,  0, 4194304ull, stream);   // hT frags = 0
    hipMemsetAsync(ws + O_RHF,  0, 4194304ull, stream);   // rh pad frags = 0
    k_xproj2<<<dim3(32,16), 256, 0, stream>>>(LinpB, Wp, bp, srl, agx0, 0);

    for (int t = 0; t < SEQ; ++t) {
        u16* agxc = (t & 1) ? agx1 : agx0;
        u16* agxn = (t & 1) ? agx0 : agx1;
        k_g1<<<dim3(32,16), 512, 0, stream>>>(Lf, hTf, agxc, W1h, b1, h_lin, rhf, u_lin);
        k_g2<<<dim3(32,16), 512, 0, stream>>>(Lf, rhf, agxc, W2h, b2, u_lin, h_lin, hTf,
                                              LinpB, Wp, bp, srl, agxn, t + 1,
                                              out, t == SEQ - 1);
    }
}